// Round 7
// baseline (114.873 us; speedup 1.0000x reference)
//
#include <hip/hip_runtime.h>
#include <hip/hip_bf16.h>

// Problem constants: B=2,C=32,N=4,V=32,W=32,E=256,H=8,D=32,K_H=K_W=7
// L=1024, Bn=8, M=8192.  Internal row ordering: m = bn*1024 + l  (bn-major)

typedef __attribute__((ext_vector_type(8))) short short8v;   // 8 bf16 (4 VGPR)
typedef __attribute__((ext_vector_type(4))) float f32x4;

__device__ __forceinline__ unsigned short f2bf(float x) {
    union { float f; unsigned u; } c; c.f = x;
    unsigned r = c.u + 0x7FFFu + ((c.u >> 16) & 1u);
    return (unsigned short)(r >> 16);
}
__device__ __forceinline__ float bf2f(short b) {
    union { unsigned u; float f; } c;
    c.u = ((unsigned)(unsigned short)b) << 16;
    return c.f;
}

// ---------------------------------------------------------------------------
// K1: blocks 0-255: fused gather + input proj (MFMA) + dual LN + QKV proj.
//     blocks 256-335: fp32->bf16 conversion of wop / wff1 / wff2.
// Embed block: 32 rows (m0 = blk*32).  Phase 2 waves: (p = wv>>1, rg = wv&1).
// Phase 3 waves: (rg = wv&1 rows, ch = wv>>1 col-half).
// ---------------------------------------------------------------------------
__global__ __launch_bounds__(256) void embed_qkv_kernel(
    const float* __restrict__ x_lf, const float* __restrict__ x_hf,
    const float* __restrict__ w_in, const float* __restrict__ w_qk,
    const float* __restrict__ ln_g, const float* __restrict__ ln_b,
    const float* __restrict__ in_proj_w,
    float* __restrict__ epi_tok, unsigned short* __restrict__ Qb,
    unsigned short* __restrict__ Kb, unsigned short* __restrict__ Vb,
    const float* __restrict__ wop, const float* __restrict__ wff1,
    const float* __restrict__ wff2,
    unsigned short* __restrict__ o2, unsigned short* __restrict__ o3,
    unsigned short* __restrict__ o4)
{
    int tid = threadIdx.x;

    if (blockIdx.x >= 256) {
        // ---- weight conversion: wop 65536 | wff1 131072 | wff2 131072 ----
        int gid = (blockIdx.x - 256) * 256 + tid;   // 0..20479
#pragma unroll
        for (int j = 0; j < 4; ++j) {
            int i4 = gid * 4 + j;                   // float4 index 0..81919
            const float* src; unsigned short* dst; int off;
            if (i4 < 16384)      { src = wop;  dst = o2; off = i4 * 4; }
            else if (i4 < 49152) { src = wff1; dst = o3; off = (i4 - 16384) * 4; }
            else                 { src = wff2; dst = o4; off = (i4 - 49152) * 4; }
            float4 v = *(const float4*)(src + off);
            ushort4 u;
            u.x = f2bf(v.x); u.y = f2bf(v.y); u.z = f2bf(v.z); u.w = f2bf(v.w);
            *(ushort4*)(dst + off) = u;
        }
        return;
    }

    // region U (16.4KB): phase1/2 xs[2][32][36] f32  |  phase3 W chunk [256][32] bf16
    __shared__ char smem_u[16384] __attribute__((aligned(16)));
    // A-buffers: 0=q_ln, 1=k_ln, 2=kv   [32][264] bf16 each
    __shared__ unsigned short abuf[3][32 * 264];

    float (*xs)[32][36] = (float (*)[32][36])smem_u;
    unsigned short* wc = (unsigned short*)smem_u;

    int m0 = blockIdx.x * 32;
    int bn = m0 >> 10, l0 = m0 & 1023;
    int bb = bn >> 2, nn = bn & 3;

    // Phase 1: coalesced gather.  Per tensor: 32 channels x 32 l's = 256
    // float4s = exactly one float4 per thread per tensor.
    {
        int c = tid >> 3, i0 = (tid & 7) * 4;
        size_t base = (size_t)bb * 131072 + (size_t)c * 4096 + nn * 1024 + l0 + i0;
        *(float4*)&xs[0][c][i0] = *(const float4*)(x_lf + base);
        *(float4*)&xs[1][c][i0] = *(const float4*)(x_hf + base);
    }
    __syncthreads();

    int lane = tid & 63, wv = tid >> 6;
    int rA = lane & 15, k8r = lane >> 4, g = lane >> 4;
    int k0 = k8r * 8;

    // Phase 2: input proj (K=32 MFMA) + LN.  wave: p = wv>>1, rg = wv&1
    {
        int p = wv >> 1, rg = wv & 1;
        const float* W = p ? w_qk : w_in;

        short8v afrag;
#pragma unroll
        for (int j = 0; j < 8; ++j)
            afrag[j] = (short)f2bf(xs[p][k0 + j][rg * 16 + rA]);

        f32x4 acc[16];
#pragma unroll
        for (int ct = 0; ct < 16; ++ct)
#pragma unroll
            for (int r = 0; r < 4; ++r) acc[ct][r] = 0.f;

#pragma unroll
        for (int ct = 0; ct < 16; ++ct) {
            const float* wp = W + (ct * 16 + rA) * 32 + k0;
            float4 w0 = *(const float4*)wp;
            float4 w1 = *(const float4*)(wp + 4);
            short8v bfrag;
            bfrag[0] = (short)f2bf(w0.x); bfrag[1] = (short)f2bf(w0.y);
            bfrag[2] = (short)f2bf(w0.z); bfrag[3] = (short)f2bf(w0.w);
            bfrag[4] = (short)f2bf(w1.x); bfrag[5] = (short)f2bf(w1.y);
            bfrag[6] = (short)f2bf(w1.z); bfrag[7] = (short)f2bf(w1.w);
            acc[ct] = __builtin_amdgcn_mfma_f32_16x16x32_bf16(afrag, bfrag, acc[ct], 0, 0, 0);
        }

        float s[4] = {0.f, 0.f, 0.f, 0.f}, q[4] = {0.f, 0.f, 0.f, 0.f};
#pragma unroll
        for (int ct = 0; ct < 16; ++ct)
#pragma unroll
            for (int r = 0; r < 4; ++r) {
                float v = acc[ct][r];
                s[r] += v; q[r] += v * v;
            }
#pragma unroll
        for (int off = 8; off; off >>= 1)
#pragma unroll
            for (int r = 0; r < 4; ++r) {
                s[r] += __shfl_xor(s[r], off);
                q[r] += __shfl_xor(q[r], off);
            }
        float mu[4], rs[4];
#pragma unroll
        for (int r = 0; r < 4; ++r) {
            mu[r] = s[r] * (1.f / 256.f);
            rs[r] = rsqrtf(q[r] * (1.f / 256.f) - mu[r] * mu[r] + 1e-5f);
        }

#pragma unroll
        for (int ct = 0; ct < 16; ++ct) {
            int col = ct * 16 + rA;
            float gg = ln_g[col], bv = ln_b[col];
#pragma unroll
            for (int r = 0; r < 4; ++r) {
                int lrow = rg * 16 + g * 4 + r;
                float v = acc[ct][r];
                float lnv = (v - mu[r]) * rs[r] * gg + bv;
                if (p == 0) {
                    epi_tok[(size_t)(m0 + lrow) * 256 + col] = v;
                    abuf[0][lrow * 264 + col] = f2bf(lnv);
                } else {
                    abuf[1][lrow * 264 + col] = f2bf(lnv);
                    abuf[2][lrow * 264 + col] = f2bf(v);
                }
            }
        }
    }
    __syncthreads();

    // Phase 3: QKV GEMMs (M=32, N=256, K=256), W streamed fp32->bf16.
    {
        int rg = wv & 1, ch = wv >> 1;
#pragma unroll
        for (int z = 0; z < 3; ++z) {
            f32x4 acc3[8];
#pragma unroll
            for (int nt = 0; nt < 8; ++nt)
#pragma unroll
                for (int r = 0; r < 4; ++r) acc3[nt][r] = 0.f;

            for (int kc = 0; kc < 8; ++kc) {
                // stage W chunk: rows n=0..255 of in_proj_w[z*256+n][kc*32..]
#pragma unroll
                for (int t = 0; t < 8; ++t) {
                    int idx = t * 256 + tid;          // 0..2047
                    int n = idx >> 3, i0 = (idx & 7) * 4;
                    float4 v4 = *(const float4*)(in_proj_w +
                        ((size_t)(z * 256 + n)) * 256 + kc * 32 + i0);
                    ushort4 u4;
                    u4.x = f2bf(v4.x); u4.y = f2bf(v4.y);
                    u4.z = f2bf(v4.z); u4.w = f2bf(v4.w);
                    *(ushort4*)&wc[n * 32 + i0] = u4;
                }
                __syncthreads();
                short8v a = *(const short8v*)&abuf[z][(rg * 16 + rA) * 264 + kc * 32 + k0];
#pragma unroll
                for (int nt = 0; nt < 8; ++nt) {
                    short8v b = *(const short8v*)&wc[(ch * 128 + nt * 16 + rA) * 32 + k0];
                    acc3[nt] = __builtin_amdgcn_mfma_f32_16x16x32_bf16(a, b, acc3[nt], 0, 0, 0);
                }
                __syncthreads();
            }

            unsigned short* dst = (z == 0) ? Qb : (z == 1) ? Kb : Vb;
#pragma unroll
            for (int nt = 0; nt < 8; ++nt) {
                int col = ch * 128 + nt * 16 + rA;
                int h = col >> 5, d = col & 31;
#pragma unroll
                for (int r = 0; r < 4; ++r) {
                    int l = l0 + rg * 16 + g * 4 + r;
                    dst[((size_t)(bn * 8 + h) * 1024 + l) * 32 + d] = f2bf(acc3[nt][r]);
                }
            }
        }
    }
}

// ---------------------------------------------------------------------------
// K3: local-window attention, bf16 Q/K/V, fp32 math.
// Block per (bh, qv): 32 queries, 7 K/V rows staged in LDS as bf16 (35 KB).
// ---------------------------------------------------------------------------
__global__ __launch_bounds__(256) void attn_kernel(
    const unsigned short* __restrict__ Qb, const unsigned short* __restrict__ Kb,
    const unsigned short* __restrict__ Vb, unsigned short* __restrict__ ctx)
{
    int bh = blockIdx.x >> 5;
    int qv = blockIdx.x & 31;
    int tid = threadIdx.x;

    __shared__ unsigned short Ks[7][32][40];
    __shared__ unsigned short Vs[7][32][40];

#pragma unroll
    for (int it = 0; it < 4; ++it) {
        int idx = it * 256 + tid;
        if (idx < 896) {
            int dv = idx >> 7, rem = idx & 127;
            int kw = rem >> 2, c8 = (rem & 3) * 8;
            int kvc = min(max(qv - 3 + dv, 0), 31);
            size_t base = ((size_t)bh * 1024 + kvc * 32 + kw) * 32 + c8;
            *(short8v*)&Ks[dv][kw][c8] = *(const short8v*)(Kb + base);
            *(short8v*)&Vs[dv][kw][c8] = *(const short8v*)(Vb + base);
        }
    }

    int qq = tid >> 3, t = tid & 7;
    int q = qv * 32 + qq;

    float qf[32];
    {
        const short8v* qp = (const short8v*)(Qb + ((size_t)bh * 1024 + q) * 32);
#pragma unroll
        for (int i = 0; i < 4; ++i) {
            short8v v = qp[i];
#pragma unroll
            for (int j = 0; j < 8; ++j) qf[i * 8 + j] = bf2f(v[j]);
        }
    }
    __syncthreads();

    float s[7];
    int kwj[7], dvj[7];
    bool val[7];
#pragma unroll
    for (int jj = 0; jj < 7; ++jj) {
        int j = t + 8 * jj;
        int dv = j / 7, dw = j % 7;
        int kvr = qv - 3 + dv, kwr = qq - 3 + dw;
        val[jj] = (j < 49) && (kvr >= 0) && (kvr < 32) && (kwr >= 0) && (kwr < 32);
        dvj[jj] = min(dv, 6);
        kwj[jj] = kwr & 31;
    }

#pragma unroll
    for (int jj = 0; jj < 7; ++jj) {
        const unsigned short* kr = &Ks[dvj[jj]][kwj[jj]][0];
        float acc = 0.f;
#pragma unroll
        for (int i = 0; i < 4; ++i) {
            short8v k8 = *(const short8v*)(kr + i * 8);
#pragma unroll
            for (int j = 0; j < 8; ++j) acc += qf[i * 8 + j] * bf2f(k8[j]);
        }
        s[jj] = acc;
    }

    const float scale = 0.17677669529663687f;
    float mx = -1e30f;
#pragma unroll
    for (int jj = 0; jj < 7; ++jj) {
        s[jj] = val[jj] ? s[jj] * scale : -1e30f;
        mx = fmaxf(mx, s[jj]);
    }
    mx = fmaxf(mx, __shfl_xor(mx, 4));
    mx = fmaxf(mx, __shfl_xor(mx, 2));
    mx = fmaxf(mx, __shfl_xor(mx, 1));

    float e[7], sum = 0.f;
#pragma unroll
    for (int jj = 0; jj < 7; ++jj) { e[jj] = __expf(s[jj] - mx); sum += e[jj]; }
    sum += __shfl_xor(sum, 4);
    sum += __shfl_xor(sum, 2);
    sum += __shfl_xor(sum, 1);
    float inv = 1.f / sum;

    float av[32];
#pragma unroll
    for (int i = 0; i < 32; ++i) av[i] = 0.f;

#pragma unroll
    for (int jj = 0; jj < 7; ++jj) {
        float p = e[jj] * inv;
        const unsigned short* vr = &Vs[dvj[jj]][kwj[jj]][0];
#pragma unroll
        for (int i = 0; i < 4; ++i) {
            short8v v8 = *(const short8v*)(vr + i * 8);
#pragma unroll
            for (int j = 0; j < 8; ++j) av[i * 8 + j] += p * bf2f(v8[j]);
        }
    }

#pragma unroll
    for (int off = 4; off; off >>= 1)
#pragma unroll
        for (int i = 0; i < 32; ++i) av[i] += __shfl_xor(av[i], off);

    {
        int bn = bh >> 3, h = bh & 7;
        unsigned short* dst = ctx + ((size_t)bn * 1024 + q) * 256 + h * 32 + t * 4;
        ushort4 u;
        u.x = f2bf(av[t * 4 + 0]); u.y = f2bf(av[t * 4 + 1]);
        u.z = f2bf(av[t * 4 + 2]); u.w = f2bf(av[t * 4 + 3]);
        *(ushort4*)dst = u;
    }
}

// ---------------------------------------------------------------------------
// K4: out_proj + residual + LN2 + FF1 + ReLU fused.  32-row tile, 4 waves.
// ---------------------------------------------------------------------------
__global__ __launch_bounds__(256) void outproj_ln_ff1_kernel(
    const unsigned short* __restrict__ ctx, const unsigned short* __restrict__ Wop,
    float* __restrict__ epi_tok, const float* __restrict__ g2,
    const float* __restrict__ b2, const unsigned short* __restrict__ W1,
    unsigned short* __restrict__ ffh)
{
    __shared__ unsigned short As[32 * 32];          // 2KB ctx chunk
    __shared__ unsigned short Wbuf[512 * 32];       // 32KB (GEMM1 uses first half)
    __shared__ unsigned short fbuf[32 * 264];       // 16.9KB LN'd tile
    __shared__ float part[2][2][4][4][2];

    int tid = threadIdx.x, lane = tid & 63, wv = tid >> 6;
    int m0 = blockIdx.x * 32;
    int rA = lane & 15, k8r = lane >> 4, g = lane >> 4;
    int rg = wv & 1, ch = wv >> 1;
    int k0 = k8r * 8;

    f32x4 acc[8];
#pragma unroll
    for (int ct = 0; ct < 8; ++ct)
#pragma unroll
        for (int r = 0; r < 4; ++r) acc[ct][r] = 0.f;

    for (int kc = 0; kc < 256; kc += 32) {
        if (tid < 128) {
            int row = tid >> 2, k8 = (tid & 3) * 8;
            *(short8v*)&As[row * 32 + k8] =
                *(const short8v*)(ctx + (size_t)(m0 + row) * 256 + kc + k8);
        }
#pragma unroll
        for (int c = 0; c < 4; ++c) {
            int i = c * 256 + tid;
            int row = i >> 2, k8 = (i & 3) * 8;
            *(short8v*)&Wbuf[row * 32 + k8] =
                *(const short8v*)(Wop + (size_t)row * 256 + kc + k8);
        }
        __syncthreads();
        short8v a = *(const short8v*)&As[(rg * 16 + rA) * 32 + k0];
#pragma unroll
        for (int ct = 0; ct < 8; ++ct) {
            short8v b = *(const short8v*)&Wbuf[(ch * 128 + ct * 16 + rA) * 32 + k0];
            acc[ct] = __builtin_amdgcn_mfma_f32_16x16x32_bf16(a, b, acc[ct], 0, 0, 0);
        }
        __syncthreads();
    }

    // residual + LN2 stats
    float s[4] = {0.f, 0.f, 0.f, 0.f}, q[4] = {0.f, 0.f, 0.f, 0.f};
#pragma unroll
    for (int ct = 0; ct < 8; ++ct) {
        int col = ch * 128 + ct * 16 + rA;
#pragma unroll
        for (int r = 0; r < 4; ++r) {
            int row = m0 + rg * 16 + g * 4 + r;
            float v = acc[ct][r] + epi_tok[(size_t)row * 256 + col];
            acc[ct][r] = v;
            s[r] += v; q[r] += v * v;
        }
    }
#pragma unroll
    for (int off = 8; off; off >>= 1)
#pragma unroll
        for (int r = 0; r < 4; ++r) {
            s[r] += __shfl_xor(s[r], off);
            q[r] += __shfl_xor(q[r], off);
        }
    if (rA == 0) {
#pragma unroll
        for (int r = 0; r < 4; ++r) {
            part[rg][ch][g][r][0] = s[r];
            part[rg][ch][g][r][1] = q[r];
        }
    }
    __syncthreads();
    float mu[4], rs[4];
#pragma unroll
    for (int r = 0; r < 4; ++r) {
        float S = part[rg][0][g][r][0] + part[rg][1][g][r][0];
        float Q = part[rg][0][g][r][1] + part[rg][1][g][r][1];
        mu[r] = S * (1.f / 256.f);
        rs[r] = rsqrtf(Q * (1.f / 256.f) - mu[r] * mu[r] + 1e-5f);
    }
    // write epi_tok (fp32 global) + LN'd tile -> fbuf (bf16)
#pragma unroll
    for (int ct = 0; ct < 8; ++ct) {
        int col = ch * 128 + ct * 16 + rA;
        float gg = g2[col], bv = b2[col];
#pragma unroll
        for (int r = 0; r < 4; ++r) {
            int lrow = rg * 16 + g * 4 + r;
            epi_tok[(size_t)(m0 + lrow) * 256 + col] = acc[ct][r];
            fbuf[lrow * 264 + col] = f2bf((acc[ct][r] - mu[r]) * rs[r] * gg + bv);
        }
    }

    // FF1: M=32, N=512, K=256.  wave = (rg rows, ch col-half of 512)
    f32x4 acc2[16];
#pragma unroll
    for (int nt = 0; nt < 16; ++nt)
#pragma unroll
        for (int r = 0; r < 4; ++r) acc2[nt][r] = 0.f;

    for (int kc = 0; kc < 8; ++kc) {
        // stage W1 chunk [512][32] bf16
#pragma unroll
        for (int t = 0; t < 8; ++t) {
            int idx = t * 256 + tid;          // 0..2047
            int n = idx >> 2, i0 = (idx & 3) * 8;
            *(short8v*)&Wbuf[n * 32 + i0] =
                *(const short8v*)(W1 + (size_t)n * 256 + kc * 32 + i0);
        }
        __syncthreads();
        short8v a = *(const short8v*)&fbuf[(rg * 16 + rA) * 264 + kc * 32 + k0];
#pragma unroll
        for (int nt = 0; nt < 16; ++nt) {
            short8v b = *(const short8v*)&Wbuf[(ch * 256 + nt * 16 + rA) * 32 + k0];
            acc2[nt] = __builtin_amdgcn_mfma_f32_16x16x32_bf16(a, b, acc2[nt], 0, 0, 0);
        }
        __syncthreads();
    }

#pragma unroll
    for (int nt = 0; nt < 16; ++nt) {
        int col = ch * 256 + nt * 16 + rA;
#pragma unroll
        for (int r = 0; r < 4; ++r) {
            int row = m0 + rg * 16 + g * 4 + r;
            ffh[(size_t)row * 512 + col] = f2bf(fmaxf(acc2[nt][r], 0.f));
        }
    }
}

// ---------------------------------------------------------------------------
// K6: FF2 + residual + final E->32 projection + transposed store, fused.
// ---------------------------------------------------------------------------
__global__ __launch_bounds__(256) void ff2_final_kernel(
    const unsigned short* __restrict__ ffh, const unsigned short* __restrict__ W2,
    const float* __restrict__ epi_tok, const float* __restrict__ w_out,
    float* __restrict__ out)
{
    __shared__ unsigned short As[32 * 32];
    __shared__ unsigned short Ws[256 * 32];
    __shared__ unsigned short Ts[32 * 264];

    int tid = threadIdx.x, lane = tid & 63, wv = tid >> 6;
    int m0 = blockIdx.x * 32;
    int rA = lane & 15, k8r = lane >> 4, g = lane >> 4;
    int rg = wv & 1, ch = wv >> 1;

    f32x4 acc[8];
#pragma unroll
    for (int ct = 0; ct < 8; ++ct)
#pragma unroll
        for (int r = 0; r < 4; ++r) acc[ct][r] = 0.f;

    for (int kc = 0; kc < 512; kc += 32) {
        if (tid < 128) {
            int row = tid >> 2, k8 = (tid & 3) * 8;
            *(short8v*)&As[row * 32 + k8] =
                *(const short8v*)(ffh + (size_t)(m0 + row) * 512 + kc + k8);
        }
#pragma unroll
        for (int c = 0; c < 4; ++c) {
            int i = c * 256 + tid;
            int row = i >> 2, k8 = (i & 3) * 8;
            *(short8v*)&Ws[row * 32 + k8] =
                *(const short8v*)(W2 + (size_t)row * 512 + kc + k8);
        }
        __syncthreads();
        short8v a = *(const short8v*)&As[(rg * 16 + rA) * 32 + k8r * 8];
#pragma unroll
        for (int ct = 0; ct < 8; ++ct) {
            short8v b = *(const short8v*)&Ws[(ch * 128 + ct * 16 + rA) * 32 + k8r * 8];
            acc[ct] = __builtin_amdgcn_mfma_f32_16x16x32_bf16(a, b, acc[ct], 0, 0, 0);
        }
        __syncthreads();
    }

    // residual add; write T = final epi_token tile to LDS (bf16)
#pragma unroll
    for (int ct = 0; ct < 8; ++ct) {
        int col = ch * 128 + ct * 16 + rA;
#pragma unroll
        for (int r = 0; r < 4; ++r) {
            int lrow = rg * 16 + g * 4 + r;
            float v = acc[ct][r] + epi_tok[(size_t)(m0 + lrow) * 256 + col];
            Ts[lrow * 264 + col] = f2bf(v);
        }
    }
    __syncthreads();

    int bn = m0 >> 10, l0 = m0 & 1023;
    int bb = bn >> 2, nn = bn & 3;

    // stage 2: wave w -> rows (w&1)*16, cols (w>>1)*16 of the 32x32 output
    {
        int rw = wv & 1, cw = wv >> 1;
        f32x4 a2;
#pragma unroll
        for (int r = 0; r < 4; ++r) a2[r] = 0.f;
#pragma unroll
        for (int ks = 0; ks < 8; ++ks) {
            short8v af = *(const short8v*)&Ts[(rw * 16 + rA) * 264 + ks * 32 + k8r * 8];
            const float* wp = w_out + (cw * 16 + rA) * 256 + ks * 32 + k8r * 8;
            float4 w0 = *(const float4*)wp;
            float4 w1 = *(const float4*)(wp + 4);
            short8v bf;
            bf[0] = (short)f2bf(w0.x); bf[1] = (short)f2bf(w0.y);
            bf[2] = (short)f2bf(w0.z); bf[3] = (short)f2bf(w0.w);
            bf[4] = (short)f2bf(w1.x); bf[5] = (short)f2bf(w1.y);
            bf[6] = (short)f2bf(w1.z); bf[7] = (short)f2bf(w1.w);
            a2 = __builtin_amdgcn_mfma_f32_16x16x32_bf16(af, bf, a2, 0, 0, 0);
        }
        int c = cw * 16 + rA;
        int l = l0 + rw * 16 + g * 4;
        float4 st; st.x = a2[0]; st.y = a2[1]; st.z = a2[2]; st.w = a2[3];
        *(float4*)(out + ((size_t)(bb * 32 + c) * 4 + nn) * 1024 + l) = st;
    }
}

// ---------------------------------------------------------------------------
extern "C" void kernel_launch(void* const* d_in, const int* in_sizes, int n_in,
                              void* d_out, int out_size, void* d_ws, size_t ws_size,
                              hipStream_t stream) {
    const float* x_lf       = (const float*)d_in[0];
    const float* x_hf       = (const float*)d_in[1];
    const float* w_in       = (const float*)d_in[2];
    const float* w_qk       = (const float*)d_in[3];
    const float* ln_g       = (const float*)d_in[4];
    const float* ln_b       = (const float*)d_in[5];
    const float* in_proj_w  = (const float*)d_in[6];
    const float* out_proj_w = (const float*)d_in[7];
    const float* ln2_g      = (const float*)d_in[8];
    const float* ln2_b      = (const float*)d_in[9];
    const float* ff_w1      = (const float*)d_in[10];
    const float* ff_w2      = (const float*)d_in[11];
    const float* w_out      = (const float*)d_in[12];
    float* out = (float*)d_out;

    char* w = (char*)d_ws;
    float* epi_tok         = (float*)(w);                         // 8 MB fp32
    unsigned short* Qb     = (unsigned short*)(w + (8u  << 20));  // 4 MB bf16
    unsigned short* Kb     = (unsigned short*)(w + (12u << 20));
    unsigned short* Vb     = (unsigned short*)(w + (16u << 20));
    unsigned short* ctx_b  = (unsigned short*)(w + (20u << 20));
    unsigned short* ffh_b  = (unsigned short*)(w + (24u << 20));  // 8 MB
    unsigned short* wop_b  = (unsigned short*)(w + (32u << 20));  // 128 KB
    unsigned short* wff1_b = (unsigned short*)(w + (33u << 20));  // 256 KB
    unsigned short* wff2_b = (unsigned short*)(w + (34u << 20));  // 256 KB

    // 1. gather + input proj + LN + QKV proj  ||  weight conversion
    embed_qkv_kernel<<<336, 256, 0, stream>>>(
        x_lf, x_hf, w_in, w_qk, ln_g, ln_b, in_proj_w,
        epi_tok, Qb, Kb, Vb,
        out_proj_w, ff_w1, ff_w2, wop_b, wff1_b, wff2_b);
    // 2. local-window attention -> ctx bf16
    attn_kernel<<<2048, 256, 0, stream>>>(Qb, Kb, Vb, ctx_b);
    // 3. out_proj + residual + LN2 + FF1 + ReLU (fused)
    outproj_ln_ff1_kernel<<<256, 256, 0, stream>>>(
        ctx_b, wop_b, epi_tok, ln2_g, ln2_b, wff1_b, ffh_b);
    // 4. FF2 + residual + final projection + transposed store (fused)
    ff2_final_kernel<<<256, 256, 0, stream>>>(ffh_b, wff2_b, epi_tok, w_out, out);
}

// Round 8
// 105.966 us; speedup vs baseline: 1.0840x; 1.0840x over previous
//
#include <hip/hip_runtime.h>
#include <hip/hip_bf16.h>

// Problem constants: B=2,C=32,N=4,V=32,W=32,E=256,H=8,D=32,K_H=K_W=7
// L=1024, Bn=8, M=8192.  Internal row ordering: m = bn*1024 + l  (bn-major)

typedef __attribute__((ext_vector_type(8))) short short8v;   // 8 bf16 (4 VGPR)
typedef __attribute__((ext_vector_type(4))) float f32x4;

__device__ __forceinline__ unsigned short f2bf(float x) {
    union { float f; unsigned u; } c; c.f = x;
    unsigned r = c.u + 0x7FFFu + ((c.u >> 16) & 1u);
    return (unsigned short)(r >> 16);
}
__device__ __forceinline__ float bf2f(short b) {
    union { unsigned u; float f; } c;
    c.u = ((unsigned)(unsigned short)b) << 16;
    return c.f;
}

// ---------------------------------------------------------------------------
// K1: blocks 0-127: fused gather + input projection (MFMA, 64-row tiles)
//     + dual LayerNorm.  blocks 128-255: fp32->bf16 weight conversion.
// ---------------------------------------------------------------------------
__global__ __launch_bounds__(256) void embed_conv_kernel(
    const float* __restrict__ x_lf, const float* __restrict__ x_hf,
    const float* __restrict__ w_in, const float* __restrict__ w_qk,
    const float* __restrict__ ln_g, const float* __restrict__ ln_b,
    float* __restrict__ epi_tok, unsigned short* __restrict__ kv_b,
    unsigned short* __restrict__ q_b, unsigned short* __restrict__ k_b,
    const float* __restrict__ wqkv, const float* __restrict__ wop,
    const float* __restrict__ wff1, const float* __restrict__ wff2,
    unsigned short* __restrict__ o1, unsigned short* __restrict__ o2,
    unsigned short* __restrict__ o3, unsigned short* __restrict__ o4)
{
    int tid = threadIdx.x;

    if (blockIdx.x >= 128) {
        // ---- weight conversion: 524288 floats total ----
        int gid = (blockIdx.x - 128) * 256 + tid;   // 0..32767
#pragma unroll
        for (int j = 0; j < 4; ++j) {
            int i = (gid + j * 32768) * 4;
            const float* src; unsigned short* dst; int off;
            if (i < 196608)      { src = wqkv; dst = o1; off = i; }
            else if (i < 262144) { src = wop;  dst = o2; off = i - 196608; }
            else if (i < 393216) { src = wff1; dst = o3; off = i - 262144; }
            else                 { src = wff2; dst = o4; off = i - 393216; }
            float4 v = *(const float4*)(src + off);
            ushort4 u;
            u.x = f2bf(v.x); u.y = f2bf(v.y); u.z = f2bf(v.z); u.w = f2bf(v.w);
            *(ushort4*)(dst + off) = u;
        }
        return;
    }

    __shared__ float xs[2][32][65];

    int m0 = blockIdx.x * 64;
    int bn = m0 >> 10, l0 = m0 & 1023;
    int bb = bn >> 2, nn = bn & 3;

    // coalesced gather of both input tensors (64 l's x 32 channels each)
    {
        int c = tid >> 3, i0 = (tid & 7) * 8;
        size_t base = (size_t)bb * 131072 + (size_t)c * 4096 + nn * 1024 + l0 + i0;
        float4 a0 = *(const float4*)(x_lf + base);
        float4 a1 = *(const float4*)(x_lf + base + 4);
        float4 b0 = *(const float4*)(x_hf + base);
        float4 b1 = *(const float4*)(x_hf + base + 4);
        *(float4*)&xs[0][c][i0] = a0; *(float4*)&xs[0][c][i0 + 4] = a1;
        *(float4*)&xs[1][c][i0] = b0; *(float4*)&xs[1][c][i0 + 4] = b1;
    }
    __syncthreads();

    int lane = tid & 63, wv = tid >> 6;
    int rloc = wv * 16 + (lane & 15);
    int k0 = (lane >> 4) * 8;
    int g = lane >> 4;
    const float* wts[2] = { w_in, w_qk };

#pragma unroll
    for (int p = 0; p < 2; ++p) {
        short8v afrag;
#pragma unroll
        for (int j = 0; j < 8; ++j)
            afrag[j] = (short)f2bf(xs[p][k0 + j][rloc]);

        f32x4 acc[16];
#pragma unroll
        for (int ct = 0; ct < 16; ++ct)
#pragma unroll
            for (int r = 0; r < 4; ++r) acc[ct][r] = 0.f;

        const float* W = wts[p];
#pragma unroll
        for (int ct = 0; ct < 16; ++ct) {
            const float* wp = W + (ct * 16 + (lane & 15)) * 32 + k0;
            float4 w0 = *(const float4*)wp;
            float4 w1 = *(const float4*)(wp + 4);
            short8v bfrag;
            bfrag[0] = (short)f2bf(w0.x); bfrag[1] = (short)f2bf(w0.y);
            bfrag[2] = (short)f2bf(w0.z); bfrag[3] = (short)f2bf(w0.w);
            bfrag[4] = (short)f2bf(w1.x); bfrag[5] = (short)f2bf(w1.y);
            bfrag[6] = (short)f2bf(w1.z); bfrag[7] = (short)f2bf(w1.w);
            acc[ct] = __builtin_amdgcn_mfma_f32_16x16x32_bf16(afrag, bfrag, acc[ct], 0, 0, 0);
        }

        float s[4] = {0.f, 0.f, 0.f, 0.f}, q[4] = {0.f, 0.f, 0.f, 0.f};
#pragma unroll
        for (int ct = 0; ct < 16; ++ct)
#pragma unroll
            for (int r = 0; r < 4; ++r) {
                float v = acc[ct][r];
                s[r] += v; q[r] += v * v;
            }
#pragma unroll
        for (int off = 8; off; off >>= 1)
#pragma unroll
            for (int r = 0; r < 4; ++r) {
                s[r] += __shfl_xor(s[r], off);
                q[r] += __shfl_xor(q[r], off);
            }
        float mu[4], rs[4];
#pragma unroll
        for (int r = 0; r < 4; ++r) {
            mu[r] = s[r] * (1.f / 256.f);
            rs[r] = rsqrtf(q[r] * (1.f / 256.f) - mu[r] * mu[r] + 1e-5f);
        }

#pragma unroll
        for (int ct = 0; ct < 16; ++ct) {
            int col = ct * 16 + (lane & 15);
            float gg = ln_g[col], bv = ln_b[col];
#pragma unroll
            for (int r = 0; r < 4; ++r) {
                int row = m0 + wv * 16 + g * 4 + r;
                float v = acc[ct][r];
                float lnv = (v - mu[r]) * rs[r] * gg + bv;
                size_t o = (size_t)row * 256 + col;
                if (p == 0) {
                    epi_tok[o] = v;
                    q_b[o] = f2bf(lnv);
                } else {
                    kv_b[o] = f2bf(v);
                    k_b[o] = f2bf(lnv);
                }
            }
        }
    }
}

// ---------------------------------------------------------------------------
// K2: bf16 MFMA GEMM, 128x128 tile, 4 waves, BK=32.
// OUTMAP 1: QKV head layout (bn,h,l,d), bf16 out; z selects A / W / OUT slice.
// ---------------------------------------------------------------------------
template <int OUTMAP, bool RELU, bool OBF16>
__global__ __launch_bounds__(256) void gemm_mfma(
    const unsigned short* __restrict__ A0, const unsigned short* __restrict__ A1,
    const unsigned short* __restrict__ A2, const unsigned short* __restrict__ Wb,
    void* __restrict__ OUTv, const float* __restrict__ RES,
    int K, int N)
{
    int z = blockIdx.z;
    const unsigned short* A = (z == 0) ? A0 : (z == 1) ? A1 : A2;
    const unsigned short* W = Wb + (size_t)z * 65536;

    __shared__ unsigned short As[128 * 32];
    __shared__ unsigned short Ws[128 * 32];

    int tid = threadIdx.x;
    int lane = tid & 63, wid = tid >> 6;
    int wm = wid >> 1, wn = wid & 1;
    int m0 = blockIdx.x * 128, n0 = blockIdx.y * 128;

    f32x4 acc[4][4];
#pragma unroll
    for (int i = 0; i < 4; ++i)
#pragma unroll
        for (int j = 0; j < 4; ++j)
#pragma unroll
            for (int r = 0; r < 4; ++r) acc[i][j][r] = 0.f;

    int rA = lane & 15, k8r = lane >> 4;

    for (int kc = 0; kc < K; kc += 32) {
#pragma unroll
        for (int c = 0; c < 2; ++c) {
            int i = c * 256 + tid;
            int row = i >> 2, k8 = i & 3;
            short8v va = *(const short8v*)(A + (size_t)(m0 + row) * K + kc + k8 * 8);
            short8v vw = *(const short8v*)(W + (size_t)(n0 + row) * K + kc + k8 * 8);
            *(short8v*)&As[i * 8] = va;
            *(short8v*)&Ws[i * 8] = vw;
        }
        __syncthreads();

        short8v a[4], b[4];
#pragma unroll
        for (int mi = 0; mi < 4; ++mi)
            a[mi] = *(const short8v*)&As[(wm * 64 + mi * 16 + rA) * 32 + k8r * 8];
#pragma unroll
        for (int ni = 0; ni < 4; ++ni)
            b[ni] = *(const short8v*)&Ws[(wn * 64 + ni * 16 + rA) * 32 + k8r * 8];
#pragma unroll
        for (int mi = 0; mi < 4; ++mi)
#pragma unroll
            for (int ni = 0; ni < 4; ++ni)
                acc[mi][ni] = __builtin_amdgcn_mfma_f32_16x16x32_bf16(
                    a[mi], b[ni], acc[mi][ni], 0, 0, 0);
        __syncthreads();
    }

#pragma unroll
    for (int mi = 0; mi < 4; ++mi) {
#pragma unroll
        for (int ni = 0; ni < 4; ++ni) {
#pragma unroll
            for (int r = 0; r < 4; ++r) {
                int row = m0 + wm * 64 + mi * 16 + (lane >> 4) * 4 + r;
                int col = n0 + wn * 64 + ni * 16 + (lane & 15);
                float v = acc[mi][ni][r];
                if (RES) v += RES[(size_t)row * N + col];
                if (RELU) v = fmaxf(v, 0.f);
                if (OUTMAP == 0) {
                    if (OBF16)
                        ((unsigned short*)OUTv)[(size_t)row * N + col] = f2bf(v);
                    else
                        ((float*)OUTv)[(size_t)row * N + col] = v;
                } else {
                    int l = row & 1023, bn = row >> 10;
                    int h = col >> 5, d = col & 31;
                    size_t o = (size_t)z * 2097152 + ((bn * 8 + h) * 1024 + l) * 32 + d;
                    if (OBF16) ((unsigned short*)OUTv)[o] = f2bf(v);
                    else       ((float*)OUTv)[o] = v;
                }
            }
        }
    }
}

// ---------------------------------------------------------------------------
// K3: local-window attention, bf16 Q/K/V, fp32 math.
// Block per (bh, qv): 32 queries, 7 K/V rows staged in LDS as bf16 (35 KB).
// ---------------------------------------------------------------------------
__global__ __launch_bounds__(256) void attn_kernel(
    const unsigned short* __restrict__ Qb, const unsigned short* __restrict__ Kb,
    const unsigned short* __restrict__ Vb, unsigned short* __restrict__ ctx)
{
    int bh = blockIdx.x >> 5;
    int qv = blockIdx.x & 31;
    int tid = threadIdx.x;

    __shared__ unsigned short Ks[7][32][40];
    __shared__ unsigned short Vs[7][32][40];

#pragma unroll
    for (int it = 0; it < 4; ++it) {
        int idx = it * 256 + tid;
        if (idx < 896) {
            int dv = idx >> 7, rem = idx & 127;
            int kw = rem >> 2, c8 = (rem & 3) * 8;
            int kvc = min(max(qv - 3 + dv, 0), 31);
            size_t base = ((size_t)bh * 1024 + kvc * 32 + kw) * 32 + c8;
            *(short8v*)&Ks[dv][kw][c8] = *(const short8v*)(Kb + base);
            *(short8v*)&Vs[dv][kw][c8] = *(const short8v*)(Vb + base);
        }
    }

    int qq = tid >> 3, t = tid & 7;
    int q = qv * 32 + qq;

    float qf[32];
    {
        const short8v* qp = (const short8v*)(Qb + ((size_t)bh * 1024 + q) * 32);
#pragma unroll
        for (int i = 0; i < 4; ++i) {
            short8v v = qp[i];
#pragma unroll
            for (int j = 0; j < 8; ++j) qf[i * 8 + j] = bf2f(v[j]);
        }
    }
    __syncthreads();

    float s[7];
    int kwj[7], dvj[7];
    bool val[7];
#pragma unroll
    for (int jj = 0; jj < 7; ++jj) {
        int j = t + 8 * jj;
        int dv = j / 7, dw = j % 7;
        int kvr = qv - 3 + dv, kwr = qq - 3 + dw;
        val[jj] = (j < 49) && (kvr >= 0) && (kvr < 32) && (kwr >= 0) && (kwr < 32);
        dvj[jj] = min(dv, 6);
        kwj[jj] = kwr & 31;
    }

#pragma unroll
    for (int jj = 0; jj < 7; ++jj) {
        const unsigned short* kr = &Ks[dvj[jj]][kwj[jj]][0];
        float acc = 0.f;
#pragma unroll
        for (int i = 0; i < 4; ++i) {
            short8v k8 = *(const short8v*)(kr + i * 8);
#pragma unroll
            for (int j = 0; j < 8; ++j) acc += qf[i * 8 + j] * bf2f(k8[j]);
        }
        s[jj] = acc;
    }

    const float scale = 0.17677669529663687f;
    float mx = -1e30f;
#pragma unroll
    for (int jj = 0; jj < 7; ++jj) {
        s[jj] = val[jj] ? s[jj] * scale : -1e30f;
        mx = fmaxf(mx, s[jj]);
    }
    mx = fmaxf(mx, __shfl_xor(mx, 4));
    mx = fmaxf(mx, __shfl_xor(mx, 2));
    mx = fmaxf(mx, __shfl_xor(mx, 1));

    float e[7], sum = 0.f;
#pragma unroll
    for (int jj = 0; jj < 7; ++jj) { e[jj] = __expf(s[jj] - mx); sum += e[jj]; }
    sum += __shfl_xor(sum, 4);
    sum += __shfl_xor(sum, 2);
    sum += __shfl_xor(sum, 1);
    float inv = 1.f / sum;

    float av[32];
#pragma unroll
    for (int i = 0; i < 32; ++i) av[i] = 0.f;

#pragma unroll
    for (int jj = 0; jj < 7; ++jj) {
        float p = e[jj] * inv;
        const unsigned short* vr = &Vs[dvj[jj]][kwj[jj]][0];
#pragma unroll
        for (int i = 0; i < 4; ++i) {
            short8v v8 = *(const short8v*)(vr + i * 8);
#pragma unroll
            for (int j = 0; j < 8; ++j) av[i * 8 + j] += p * bf2f(v8[j]);
        }
    }

#pragma unroll
    for (int off = 4; off; off >>= 1)
#pragma unroll
        for (int i = 0; i < 32; ++i) av[i] += __shfl_xor(av[i], off);

    {
        int bn = bh >> 3, h = bh & 7;
        unsigned short* dst = ctx + ((size_t)bn * 1024 + q) * 256 + h * 32 + t * 4;
        ushort4 u;
        u.x = f2bf(av[t * 4 + 0]); u.y = f2bf(av[t * 4 + 1]);
        u.z = f2bf(av[t * 4 + 2]); u.w = f2bf(av[t * 4 + 3]);
        *(ushort4*)dst = u;
    }
}

// ---------------------------------------------------------------------------
// K4: out_proj + residual + LN2 + FF1 + ReLU fused.  32-row tile, 4 waves.
// ---------------------------------------------------------------------------
__global__ __launch_bounds__(256) void outproj_ln_ff1_kernel(
    const unsigned short* __restrict__ ctx, const unsigned short* __restrict__ Wop,
    float* __restrict__ epi_tok, const float* __restrict__ g2,
    const float* __restrict__ b2, const unsigned short* __restrict__ W1,
    unsigned short* __restrict__ ffh)
{
    __shared__ unsigned short As[32 * 32];          // 2KB ctx chunk
    __shared__ unsigned short Wbuf[512 * 32];       // 32KB (GEMM1 uses first half)
    __shared__ unsigned short fbuf[32 * 264];       // 16.9KB LN'd tile
    __shared__ float part[2][2][4][4][2];

    int tid = threadIdx.x, lane = tid & 63, wv = tid >> 6;
    int m0 = blockIdx.x * 32;
    int rA = lane & 15, k8r = lane >> 4, g = lane >> 4;
    int rg = wv & 1, ch = wv >> 1;
    int k0 = k8r * 8;

    f32x4 acc[8];
#pragma unroll
    for (int ct = 0; ct < 8; ++ct)
#pragma unroll
        for (int r = 0; r < 4; ++r) acc[ct][r] = 0.f;

    for (int kc = 0; kc < 256; kc += 32) {
        if (tid < 128) {
            int row = tid >> 2, k8 = (tid & 3) * 8;
            *(short8v*)&As[row * 32 + k8] =
                *(const short8v*)(ctx + (size_t)(m0 + row) * 256 + kc + k8);
        }
#pragma unroll
        for (int c = 0; c < 4; ++c) {
            int i = c * 256 + tid;
            int row = i >> 2, k8 = (i & 3) * 8;
            *(short8v*)&Wbuf[row * 32 + k8] =
                *(const short8v*)(Wop + (size_t)row * 256 + kc + k8);
        }
        __syncthreads();
        short8v a = *(const short8v*)&As[(rg * 16 + rA) * 32 + k0];
#pragma unroll
        for (int ct = 0; ct < 8; ++ct) {
            short8v b = *(const short8v*)&Wbuf[(ch * 128 + ct * 16 + rA) * 32 + k0];
            acc[ct] = __builtin_amdgcn_mfma_f32_16x16x32_bf16(a, b, acc[ct], 0, 0, 0);
        }
        __syncthreads();
    }

    // residual + LN2 stats
    float s[4] = {0.f, 0.f, 0.f, 0.f}, q[4] = {0.f, 0.f, 0.f, 0.f};
#pragma unroll
    for (int ct = 0; ct < 8; ++ct) {
        int col = ch * 128 + ct * 16 + rA;
#pragma unroll
        for (int r = 0; r < 4; ++r) {
            int row = m0 + rg * 16 + g * 4 + r;
            float v = acc[ct][r] + epi_tok[(size_t)row * 256 + col];
            acc[ct][r] = v;
            s[r] += v; q[r] += v * v;
        }
    }
#pragma unroll
    for (int off = 8; off; off >>= 1)
#pragma unroll
        for (int r = 0; r < 4; ++r) {
            s[r] += __shfl_xor(s[r], off);
            q[r] += __shfl_xor(q[r], off);
        }
    if (rA == 0) {
#pragma unroll
        for (int r = 0; r < 4; ++r) {
            part[rg][ch][g][r][0] = s[r];
            part[rg][ch][g][r][1] = q[r];
        }
    }
    __syncthreads();
    float mu[4], rs[4];
#pragma unroll
    for (int r = 0; r < 4; ++r) {
        float S = part[rg][0][g][r][0] + part[rg][1][g][r][0];
        float Q = part[rg][0][g][r][1] + part[rg][1][g][r][1];
        mu[r] = S * (1.f / 256.f);
        rs[r] = rsqrtf(Q * (1.f / 256.f) - mu[r] * mu[r] + 1e-5f);
    }
    // write epi_tok (fp32 global) + LN'd tile -> fbuf (bf16)
#pragma unroll
    for (int ct = 0; ct < 8; ++ct) {
        int col = ch * 128 + ct * 16 + rA;
        float gg = g2[col], bv = b2[col];
#pragma unroll
        for (int r = 0; r < 4; ++r) {
            int lrow = rg * 16 + g * 4 + r;
            epi_tok[(size_t)(m0 + lrow) * 256 + col] = acc[ct][r];
            fbuf[lrow * 264 + col] = f2bf((acc[ct][r] - mu[r]) * rs[r] * gg + bv);
        }
    }

    // FF1: M=32, N=512, K=256.  wave = (rg rows, ch col-half of 512)
    f32x4 acc2[16];
#pragma unroll
    for (int nt = 0; nt < 16; ++nt)
#pragma unroll
        for (int r = 0; r < 4; ++r) acc2[nt][r] = 0.f;

    for (int kc = 0; kc < 8; ++kc) {
        // stage W1 chunk [512][32] bf16
#pragma unroll
        for (int t = 0; t < 8; ++t) {
            int idx = t * 256 + tid;          // 0..2047
            int n = idx >> 2, i0 = (idx & 3) * 8;
            *(short8v*)&Wbuf[n * 32 + i0] =
                *(const short8v*)(W1 + (size_t)n * 256 + kc * 32 + i0);
        }
        __syncthreads();
        short8v a = *(const short8v*)&fbuf[(rg * 16 + rA) * 264 + kc * 32 + k0];
#pragma unroll
        for (int nt = 0; nt < 16; ++nt) {
            short8v b = *(const short8v*)&Wbuf[(ch * 256 + nt * 16 + rA) * 32 + k0];
            acc2[nt] = __builtin_amdgcn_mfma_f32_16x16x32_bf16(a, b, acc2[nt], 0, 0, 0);
        }
        __syncthreads();
    }

#pragma unroll
    for (int nt = 0; nt < 16; ++nt) {
        int col = ch * 256 + nt * 16 + rA;
#pragma unroll
        for (int r = 0; r < 4; ++r) {
            int row = m0 + rg * 16 + g * 4 + r;
            ffh[(size_t)row * 512 + col] = f2bf(fmaxf(acc2[nt][r], 0.f));
        }
    }
}

// ---------------------------------------------------------------------------
// K6: FF2 + residual + final E->32 projection + transposed store, fused.
// ---------------------------------------------------------------------------
__global__ __launch_bounds__(256) void ff2_final_kernel(
    const unsigned short* __restrict__ ffh, const unsigned short* __restrict__ W2,
    const float* __restrict__ epi_tok, const float* __restrict__ w_out,
    float* __restrict__ out)
{
    __shared__ unsigned short As[32 * 32];
    __shared__ unsigned short Ws[256 * 32];
    __shared__ unsigned short Ts[32 * 264];

    int tid = threadIdx.x, lane = tid & 63, wv = tid >> 6;
    int m0 = blockIdx.x * 32;
    int rA = lane & 15, k8r = lane >> 4, g = lane >> 4;
    int rg = wv & 1, ch = wv >> 1;

    f32x4 acc[8];
#pragma unroll
    for (int ct = 0; ct < 8; ++ct)
#pragma unroll
        for (int r = 0; r < 4; ++r) acc[ct][r] = 0.f;

    for (int kc = 0; kc < 512; kc += 32) {
        if (tid < 128) {
            int row = tid >> 2, k8 = (tid & 3) * 8;
            *(short8v*)&As[row * 32 + k8] =
                *(const short8v*)(ffh + (size_t)(m0 + row) * 512 + kc + k8);
        }
#pragma unroll
        for (int c = 0; c < 4; ++c) {
            int i = c * 256 + tid;
            int row = i >> 2, k8 = (i & 3) * 8;
            *(short8v*)&Ws[row * 32 + k8] =
                *(const short8v*)(W2 + (size_t)row * 512 + kc + k8);
        }
        __syncthreads();
        short8v a = *(const short8v*)&As[(rg * 16 + rA) * 32 + k8r * 8];
#pragma unroll
        for (int ct = 0; ct < 8; ++ct) {
            short8v b = *(const short8v*)&Ws[(ch * 128 + ct * 16 + rA) * 32 + k8r * 8];
            acc[ct] = __builtin_amdgcn_mfma_f32_16x16x32_bf16(a, b, acc[ct], 0, 0, 0);
        }
        __syncthreads();
    }

    // residual add; write T = final epi_token tile to LDS (bf16)
#pragma unroll
    for (int ct = 0; ct < 8; ++ct) {
        int col = ch * 128 + ct * 16 + rA;
#pragma unroll
        for (int r = 0; r < 4; ++r) {
            int lrow = rg * 16 + g * 4 + r;
            float v = acc[ct][r] + epi_tok[(size_t)(m0 + lrow) * 256 + col];
            Ts[lrow * 264 + col] = f2bf(v);
        }
    }
    __syncthreads();

    int bn = m0 >> 10, l0 = m0 & 1023;
    int bb = bn >> 2, nn = bn & 3;

    // stage 2: wave w -> rows (w&1)*16, cols (w>>1)*16 of the 32x32 output
    {
        int rw = wv & 1, cw = wv >> 1;
        f32x4 a2;
#pragma unroll
        for (int r = 0; r < 4; ++r) a2[r] = 0.f;
#pragma unroll
        for (int ks = 0; ks < 8; ++ks) {
            short8v af = *(const short8v*)&Ts[(rw * 16 + rA) * 264 + ks * 32 + k8r * 8];
            const float* wp = w_out + (cw * 16 + rA) * 256 + ks * 32 + k8r * 8;
            float4 w0 = *(const float4*)wp;
            float4 w1 = *(const float4*)(wp + 4);
            short8v bf;
            bf[0] = (short)f2bf(w0.x); bf[1] = (short)f2bf(w0.y);
            bf[2] = (short)f2bf(w0.z); bf[3] = (short)f2bf(w0.w);
            bf[4] = (short)f2bf(w1.x); bf[5] = (short)f2bf(w1.y);
            bf[6] = (short)f2bf(w1.z); bf[7] = (short)f2bf(w1.w);
            a2 = __builtin_amdgcn_mfma_f32_16x16x32_bf16(af, bf, a2, 0, 0, 0);
        }
        int c = cw * 16 + rA;
        int l = l0 + rw * 16 + g * 4;
        float4 st; st.x = a2[0]; st.y = a2[1]; st.z = a2[2]; st.w = a2[3];
        *(float4*)(out + ((size_t)(bb * 32 + c) * 4 + nn) * 1024 + l) = st;
    }
}

// ---------------------------------------------------------------------------
extern "C" void kernel_launch(void* const* d_in, const int* in_sizes, int n_in,
                              void* d_out, int out_size, void* d_ws, size_t ws_size,
                              hipStream_t stream) {
    const float* x_lf       = (const float*)d_in[0];
    const float* x_hf       = (const float*)d_in[1];
    const float* w_in       = (const float*)d_in[2];
    const float* w_qk       = (const float*)d_in[3];
    const float* ln_g       = (const float*)d_in[4];
    const float* ln_b       = (const float*)d_in[5];
    const float* in_proj_w  = (const float*)d_in[6];
    const float* out_proj_w = (const float*)d_in[7];
    const float* ln2_g      = (const float*)d_in[8];
    const float* ln2_b      = (const float*)d_in[9];
    const float* ff_w1      = (const float*)d_in[10];
    const float* ff_w2      = (const float*)d_in[11];
    const float* w_out      = (const float*)d_in[12];
    float* out = (float*)d_out;

    char* w = (char*)d_ws;
    float* epi_tok         = (float*)(w);                         // 8 MB fp32
    unsigned short* Qb     = (unsigned short*)(w + (8u  << 20));  // 4 MB bf16
    unsigned short* Kb     = (unsigned short*)(w + (12u << 20));  // contiguous
    unsigned short* Vb     = (unsigned short*)(w + (16u << 20));  // with Qb
    unsigned short* q_b    = (unsigned short*)(w + (20u << 20));
    unsigned short* k_b    = (unsigned short*)(w + (24u << 20));
    unsigned short* kv_b   = (unsigned short*)(w + (28u << 20));
    unsigned short* ctx_b  = (unsigned short*)(w + (32u << 20));
    unsigned short* ffh_b  = (unsigned short*)(w + (36u << 20));  // 8 MB
    unsigned short* wqkv_b = (unsigned short*)(w + (44u << 20));  // 384 KB
    unsigned short* wop_b  = (unsigned short*)(w + (45u << 20));  // 128 KB
    unsigned short* wff1_b = (unsigned short*)(w + (46u << 20));  // 256 KB
    unsigned short* wff2_b = (unsigned short*)(w + (47u << 20));  // 256 KB

    // 1. gather + input proj + dual LN  ||  weight fp32->bf16 conversion
    embed_conv_kernel<<<256, 256, 0, stream>>>(
        x_lf, x_hf, w_in, w_qk, ln_g, ln_b, epi_tok, kv_b, q_b, k_b,
        in_proj_w, out_proj_w, ff_w1, ff_w2, wqkv_b, wop_b, wff1_b, wff2_b);
    // 2. QKV projection -> bf16 (bn,h,l,d)
    gemm_mfma<1, false, true><<<dim3(64, 2, 3), 256, 0, stream>>>(
        q_b, k_b, kv_b, wqkv_b, (void*)Qb, nullptr, 256, 256);
    // 3. local-window attention -> ctx bf16
    attn_kernel<<<2048, 256, 0, stream>>>(Qb, Kb, Vb, ctx_b);
    // 4. out_proj + residual + LN2 + FF1 + ReLU (fused)
    outproj_ln_ff1_kernel<<<256, 256, 0, stream>>>(
        ctx_b, wop_b, epi_tok, ln2_g, ln2_b, wff1_b, ffh_b);
    // 5. FF2 + residual + final projection + transposed store (fused)
    ff2_final_kernel<<<256, 256, 0, stream>>>(ffh_b, wff2_b, epi_tok, w_out, out);
}

// Round 9
// 103.341 us; speedup vs baseline: 1.1116x; 1.0254x over previous
//
#include <hip/hip_runtime.h>
#include <hip/hip_bf16.h>

// Problem constants: B=2,C=32,N=4,V=32,W=32,E=256,H=8,D=32,K_H=K_W=7
// L=1024, Bn=8, M=8192.  Internal row ordering: m = bn*1024 + l  (bn-major)

typedef __attribute__((ext_vector_type(8))) short short8v;   // 8 bf16 (4 VGPR)
typedef __attribute__((ext_vector_type(4))) float f32x4;

__device__ __forceinline__ unsigned short f2bf(float x) {
    union { float f; unsigned u; } c; c.f = x;
    unsigned r = c.u + 0x7FFFu + ((c.u >> 16) & 1u);
    return (unsigned short)(r >> 16);
}
__device__ __forceinline__ float bf2f(short b) {
    union { unsigned u; float f; } c;
    c.u = ((unsigned)(unsigned short)b) << 16;
    return c.f;
}

// ---------------------------------------------------------------------------
// K1: blocks 0-127: fused gather + input projection (MFMA, 64-row tiles)
//     + dual LayerNorm.  blocks 128-255: fp32->bf16 weight conversion.
// bf16 outputs (q_b, k_b, kv_b) go through an LDS bounce -> short8 stores.
// ---------------------------------------------------------------------------
__global__ __launch_bounds__(256) void embed_conv_kernel(
    const float* __restrict__ x_lf, const float* __restrict__ x_hf,
    const float* __restrict__ w_in, const float* __restrict__ w_qk,
    const float* __restrict__ ln_g, const float* __restrict__ ln_b,
    float* __restrict__ epi_tok, unsigned short* __restrict__ kv_b,
    unsigned short* __restrict__ q_b, unsigned short* __restrict__ k_b,
    const float* __restrict__ wqkv, const float* __restrict__ wop,
    const float* __restrict__ wff1, const float* __restrict__ wff2,
    unsigned short* __restrict__ o1, unsigned short* __restrict__ o2,
    unsigned short* __restrict__ o3, unsigned short* __restrict__ o4)
{
    int tid = threadIdx.x;

    if (blockIdx.x >= 128) {
        int gid = (blockIdx.x - 128) * 256 + tid;   // 0..32767
#pragma unroll
        for (int j = 0; j < 4; ++j) {
            int i = (gid + j * 32768) * 4;
            const float* src; unsigned short* dst; int off;
            if (i < 196608)      { src = wqkv; dst = o1; off = i; }
            else if (i < 262144) { src = wop;  dst = o2; off = i - 196608; }
            else if (i < 393216) { src = wff1; dst = o3; off = i - 262144; }
            else                 { src = wff2; dst = o4; off = i - 393216; }
            float4 v = *(const float4*)(src + off);
            ushort4 u;
            u.x = f2bf(v.x); u.y = f2bf(v.y); u.z = f2bf(v.z); u.w = f2bf(v.w);
            *(ushort4*)(dst + off) = u;
        }
        return;
    }

    __shared__ float xs[2][32][65];
    __shared__ unsigned short ob[64 * 272];   // 34.8 KB output bounce

    int m0 = blockIdx.x * 64;
    int bn = m0 >> 10, l0 = m0 & 1023;
    int bb = bn >> 2, nn = bn & 3;

    {
        int c = tid >> 3, i0 = (tid & 7) * 8;
        size_t base = (size_t)bb * 131072 + (size_t)c * 4096 + nn * 1024 + l0 + i0;
        float4 a0 = *(const float4*)(x_lf + base);
        float4 a1 = *(const float4*)(x_lf + base + 4);
        float4 b0 = *(const float4*)(x_hf + base);
        float4 b1 = *(const float4*)(x_hf + base + 4);
        *(float4*)&xs[0][c][i0] = a0; *(float4*)&xs[0][c][i0 + 4] = a1;
        *(float4*)&xs[1][c][i0] = b0; *(float4*)&xs[1][c][i0 + 4] = b1;
    }
    __syncthreads();

    int lane = tid & 63, wv = tid >> 6;
    int rloc = wv * 16 + (lane & 15);
    int k0 = (lane >> 4) * 8;
    int g = lane >> 4;
    const float* wts[2] = { w_in, w_qk };

    // vector-store geometry: thread -> (row = tid>>2, quarter = tid&3)
    int vrow = tid >> 2, vq = tid & 3;

#pragma unroll
    for (int p = 0; p < 2; ++p) {
        short8v afrag;
#pragma unroll
        for (int j = 0; j < 8; ++j)
            afrag[j] = (short)f2bf(xs[p][k0 + j][rloc]);

        f32x4 acc[16];
#pragma unroll
        for (int ct = 0; ct < 16; ++ct)
#pragma unroll
            for (int r = 0; r < 4; ++r) acc[ct][r] = 0.f;

        const float* W = wts[p];
#pragma unroll
        for (int ct = 0; ct < 16; ++ct) {
            const float* wp = W + (ct * 16 + (lane & 15)) * 32 + k0;
            float4 w0 = *(const float4*)wp;
            float4 w1 = *(const float4*)(wp + 4);
            short8v bfrag;
            bfrag[0] = (short)f2bf(w0.x); bfrag[1] = (short)f2bf(w0.y);
            bfrag[2] = (short)f2bf(w0.z); bfrag[3] = (short)f2bf(w0.w);
            bfrag[4] = (short)f2bf(w1.x); bfrag[5] = (short)f2bf(w1.y);
            bfrag[6] = (short)f2bf(w1.z); bfrag[7] = (short)f2bf(w1.w);
            acc[ct] = __builtin_amdgcn_mfma_f32_16x16x32_bf16(afrag, bfrag, acc[ct], 0, 0, 0);
        }

        float s[4] = {0.f, 0.f, 0.f, 0.f}, q[4] = {0.f, 0.f, 0.f, 0.f};
#pragma unroll
        for (int ct = 0; ct < 16; ++ct)
#pragma unroll
            for (int r = 0; r < 4; ++r) {
                float v = acc[ct][r];
                s[r] += v; q[r] += v * v;
            }
#pragma unroll
        for (int off = 8; off; off >>= 1)
#pragma unroll
            for (int r = 0; r < 4; ++r) {
                s[r] += __shfl_xor(s[r], off);
                q[r] += __shfl_xor(q[r], off);
            }
        float mu[4], rs[4];
#pragma unroll
        for (int r = 0; r < 4; ++r) {
            mu[r] = s[r] * (1.f / 256.f);
            rs[r] = rsqrtf(q[r] * (1.f / 256.f) - mu[r] * mu[r] + 1e-5f);
        }

        if (p == 0) {
            // epi_tok: scalar f32 stores (64B segments); q_ln -> bounce
#pragma unroll
            for (int ct = 0; ct < 16; ++ct) {
                int col = ct * 16 + (lane & 15);
                float gg = ln_g[col], bv = ln_b[col];
#pragma unroll
                for (int r = 0; r < 4; ++r) {
                    int lrow = wv * 16 + g * 4 + r;
                    float v = acc[ct][r];
                    epi_tok[(size_t)(m0 + lrow) * 256 + col] = v;
                    ob[lrow * 272 + col] = f2bf((v - mu[r]) * rs[r] * gg + bv);
                }
            }
            __syncthreads();
#pragma unroll
            for (int j = 0; j < 8; ++j)
                *(short8v*)(q_b + (size_t)(m0 + vrow) * 256 + vq * 64 + j * 8) =
                    *(const short8v*)&ob[vrow * 272 + vq * 64 + j * 8];
            __syncthreads();
        } else {
            // k_ln -> bounce -> k_b
#pragma unroll
            for (int ct = 0; ct < 16; ++ct) {
                int col = ct * 16 + (lane & 15);
                float gg = ln_g[col], bv = ln_b[col];
#pragma unroll
                for (int r = 0; r < 4; ++r) {
                    int lrow = wv * 16 + g * 4 + r;
                    ob[lrow * 272 + col] = f2bf((acc[ct][r] - mu[r]) * rs[r] * gg + bv);
                }
            }
            __syncthreads();
#pragma unroll
            for (int j = 0; j < 8; ++j)
                *(short8v*)(k_b + (size_t)(m0 + vrow) * 256 + vq * 64 + j * 8) =
                    *(const short8v*)&ob[vrow * 272 + vq * 64 + j * 8];
            __syncthreads();
            // kv -> bounce -> kv_b
#pragma unroll
            for (int ct = 0; ct < 16; ++ct) {
                int col = ct * 16 + (lane & 15);
#pragma unroll
                for (int r = 0; r < 4; ++r) {
                    int lrow = wv * 16 + g * 4 + r;
                    ob[lrow * 272 + col] = f2bf(acc[ct][r]);
                }
            }
            __syncthreads();
#pragma unroll
            for (int j = 0; j < 8; ++j)
                *(short8v*)(kv_b + (size_t)(m0 + vrow) * 256 + vq * 64 + j * 8) =
                    *(const short8v*)&ob[vrow * 272 + vq * 64 + j * 8];
        }
    }
}

// ---------------------------------------------------------------------------
// K2: bf16 MFMA GEMM, 128x128 tile, 4 waves, BK=32, LDS-bounced epilogue.
// OUTMAP 0: row-major bf16.  OUTMAP 1: QKV head layout (bn,h,l,d) bf16.
// (RES / f32-out unsupported in the bounce path; callers pass nullptr.)
// ---------------------------------------------------------------------------
template <int OUTMAP, bool RELU, bool OBF16>
__global__ __launch_bounds__(256) void gemm_mfma(
    const unsigned short* __restrict__ A0, const unsigned short* __restrict__ A1,
    const unsigned short* __restrict__ A2, const unsigned short* __restrict__ Wb,
    void* __restrict__ OUTv, const float* __restrict__ RES,
    int K, int N)
{
    int z = blockIdx.z;
    const unsigned short* A = (z == 0) ? A0 : (z == 1) ? A1 : A2;
    const unsigned short* W = Wb + (size_t)z * 65536;

    __shared__ unsigned short As[128 * 32];
    __shared__ unsigned short Ws[128 * 32];
    __shared__ unsigned short Ts[128 * 136];   // 34.8 KB C-tile bounce

    int tid = threadIdx.x;
    int lane = tid & 63, wid = tid >> 6;
    int wm = wid >> 1, wn = wid & 1;
    int m0 = blockIdx.x * 128, n0 = blockIdx.y * 128;

    f32x4 acc[4][4];
#pragma unroll
    for (int i = 0; i < 4; ++i)
#pragma unroll
        for (int j = 0; j < 4; ++j)
#pragma unroll
            for (int r = 0; r < 4; ++r) acc[i][j][r] = 0.f;

    int rA = lane & 15, k8r = lane >> 4, g = lane >> 4;

    for (int kc = 0; kc < K; kc += 32) {
#pragma unroll
        for (int c = 0; c < 2; ++c) {
            int i = c * 256 + tid;
            int row = i >> 2, k8 = i & 3;
            short8v va = *(const short8v*)(A + (size_t)(m0 + row) * K + kc + k8 * 8);
            short8v vw = *(const short8v*)(W + (size_t)(n0 + row) * K + kc + k8 * 8);
            *(short8v*)&As[i * 8] = va;
            *(short8v*)&Ws[i * 8] = vw;
        }
        __syncthreads();

        short8v a[4], b[4];
#pragma unroll
        for (int mi = 0; mi < 4; ++mi)
            a[mi] = *(const short8v*)&As[(wm * 64 + mi * 16 + rA) * 32 + k8r * 8];
#pragma unroll
        for (int ni = 0; ni < 4; ++ni)
            b[ni] = *(const short8v*)&Ws[(wn * 64 + ni * 16 + rA) * 32 + k8r * 8];
#pragma unroll
        for (int mi = 0; mi < 4; ++mi)
#pragma unroll
            for (int ni = 0; ni < 4; ++ni)
                acc[mi][ni] = __builtin_amdgcn_mfma_f32_16x16x32_bf16(
                    a[mi], b[ni], acc[mi][ni], 0, 0, 0);
        __syncthreads();
    }

    // C tile -> LDS (scalar), then vectorized global stores
#pragma unroll
    for (int mi = 0; mi < 4; ++mi) {
#pragma unroll
        for (int ni = 0; ni < 4; ++ni) {
#pragma unroll
            for (int r = 0; r < 4; ++r) {
                int row = wm * 64 + mi * 16 + g * 4 + r;
                int col = wn * 64 + ni * 16 + rA;
                float v = acc[mi][ni][r];
                if (RELU) v = fmaxf(v, 0.f);
                Ts[row * 136 + col] = f2bf(v);
            }
        }
    }
    __syncthreads();

    if (OUTMAP == 0) {
        int row = tid >> 1, half = tid & 1;
        unsigned short* OUT = (unsigned short*)OUTv;
#pragma unroll
        for (int j = 0; j < 8; ++j)
            *(short8v*)(OUT + (size_t)(m0 + row) * N + n0 + half * 64 + j * 8) =
                *(const short8v*)&Ts[row * 136 + half * 64 + j * 8];
    } else {
        int bn = m0 >> 10, l0 = m0 & 1023, h0 = n0 >> 5;
        unsigned short* OUT = (unsigned short*)OUTv + (size_t)z * 2097152;
#pragma unroll
        for (int i = 0; i < 8; ++i) {
            int lin = i * 256 + tid;          // 0..2047
            int dq = lin & 3;
            int l = (lin >> 2) & 127;
            int hl = lin >> 9;                // 0..3
            *(short8v*)(OUT + ((size_t)((bn * 8 + h0 + hl) * 1024 + l0 + l)) * 32 + dq * 8) =
                *(const short8v*)&Ts[l * 136 + hl * 32 + dq * 8];
        }
    }
}

// ---------------------------------------------------------------------------
// K3: local-window attention, bf16 Q/K/V, fp32 math.  (unchanged)
// ---------------------------------------------------------------------------
__global__ __launch_bounds__(256) void attn_kernel(
    const unsigned short* __restrict__ Qb, const unsigned short* __restrict__ Kb,
    const unsigned short* __restrict__ Vb, unsigned short* __restrict__ ctx)
{
    int bh = blockIdx.x >> 5;
    int qv = blockIdx.x & 31;
    int tid = threadIdx.x;

    __shared__ unsigned short Ks[7][32][40];
    __shared__ unsigned short Vs[7][32][40];

#pragma unroll
    for (int it = 0; it < 4; ++it) {
        int idx = it * 256 + tid;
        if (idx < 896) {
            int dv = idx >> 7, rem = idx & 127;
            int kw = rem >> 2, c8 = (rem & 3) * 8;
            int kvc = min(max(qv - 3 + dv, 0), 31);
            size_t base = ((size_t)bh * 1024 + kvc * 32 + kw) * 32 + c8;
            *(short8v*)&Ks[dv][kw][c8] = *(const short8v*)(Kb + base);
            *(short8v*)&Vs[dv][kw][c8] = *(const short8v*)(Vb + base);
        }
    }

    int qq = tid >> 3, t = tid & 7;
    int q = qv * 32 + qq;

    float qf[32];
    {
        const short8v* qp = (const short8v*)(Qb + ((size_t)bh * 1024 + q) * 32);
#pragma unroll
        for (int i = 0; i < 4; ++i) {
            short8v v = qp[i];
#pragma unroll
            for (int j = 0; j < 8; ++j) qf[i * 8 + j] = bf2f(v[j]);
        }
    }
    __syncthreads();

    float s[7];
    int kwj[7], dvj[7];
    bool val[7];
#pragma unroll
    for (int jj = 0; jj < 7; ++jj) {
        int j = t + 8 * jj;
        int dv = j / 7, dw = j % 7;
        int kvr = qv - 3 + dv, kwr = qq - 3 + dw;
        val[jj] = (j < 49) && (kvr >= 0) && (kvr < 32) && (kwr >= 0) && (kwr < 32);
        dvj[jj] = min(dv, 6);
        kwj[jj] = kwr & 31;
    }

#pragma unroll
    for (int jj = 0; jj < 7; ++jj) {
        const unsigned short* kr = &Ks[dvj[jj]][kwj[jj]][0];
        float acc = 0.f;
#pragma unroll
        for (int i = 0; i < 4; ++i) {
            short8v k8 = *(const short8v*)(kr + i * 8);
#pragma unroll
            for (int j = 0; j < 8; ++j) acc += qf[i * 8 + j] * bf2f(k8[j]);
        }
        s[jj] = acc;
    }

    const float scale = 0.17677669529663687f;
    float mx = -1e30f;
#pragma unroll
    for (int jj = 0; jj < 7; ++jj) {
        s[jj] = val[jj] ? s[jj] * scale : -1e30f;
        mx = fmaxf(mx, s[jj]);
    }
    mx = fmaxf(mx, __shfl_xor(mx, 4));
    mx = fmaxf(mx, __shfl_xor(mx, 2));
    mx = fmaxf(mx, __shfl_xor(mx, 1));

    float e[7], sum = 0.f;
#pragma unroll
    for (int jj = 0; jj < 7; ++jj) { e[jj] = __expf(s[jj] - mx); sum += e[jj]; }
    sum += __shfl_xor(sum, 4);
    sum += __shfl_xor(sum, 2);
    sum += __shfl_xor(sum, 1);
    float inv = 1.f / sum;

    float av[32];
#pragma unroll
    for (int i = 0; i < 32; ++i) av[i] = 0.f;

#pragma unroll
    for (int jj = 0; jj < 7; ++jj) {
        float p = e[jj] * inv;
        const unsigned short* vr = &Vs[dvj[jj]][kwj[jj]][0];
#pragma unroll
        for (int i = 0; i < 4; ++i) {
            short8v v8 = *(const short8v*)(vr + i * 8);
#pragma unroll
            for (int j = 0; j < 8; ++j) av[i * 8 + j] += p * bf2f(v8[j]);
        }
    }

#pragma unroll
    for (int off = 4; off; off >>= 1)
#pragma unroll
        for (int i = 0; i < 32; ++i) av[i] += __shfl_xor(av[i], off);

    {
        int bn = bh >> 3, h = bh & 7;
        unsigned short* dst = ctx + ((size_t)bn * 1024 + q) * 256 + h * 32 + t * 4;
        ushort4 u;
        u.x = f2bf(av[t * 4 + 0]); u.y = f2bf(av[t * 4 + 1]);
        u.z = f2bf(av[t * 4 + 2]); u.w = f2bf(av[t * 4 + 3]);
        *(ushort4*)dst = u;
    }
}

// ---------------------------------------------------------------------------
// K4: out_proj + residual + LN2 fused.  32-row tile, 4 waves, ffin bounced.
// ---------------------------------------------------------------------------
__global__ __launch_bounds__(256) void outproj_ln_kernel(
    const unsigned short* __restrict__ ctx, const unsigned short* __restrict__ Wop,
    float* __restrict__ epi_tok, const float* __restrict__ g2,
    const float* __restrict__ b2, unsigned short* __restrict__ ffin)
{
    __shared__ unsigned short As[32 * 32];
    __shared__ unsigned short Ws[256 * 32];
    __shared__ unsigned short fb[32 * 272];   // 17.4 KB ffin bounce
    __shared__ float part[2][2][4][4][2];

    int tid = threadIdx.x, lane = tid & 63, wv = tid >> 6;
    int m0 = blockIdx.x * 32;
    int rA = lane & 15, k8r = lane >> 4, g = lane >> 4;
    int rg = wv & 1, ch = wv >> 1;

    f32x4 acc[8];
#pragma unroll
    for (int ct = 0; ct < 8; ++ct)
#pragma unroll
        for (int r = 0; r < 4; ++r) acc[ct][r] = 0.f;

    for (int kc = 0; kc < 256; kc += 32) {
        if (tid < 128) {
            int row = tid >> 2, k8 = (tid & 3) * 8;
            *(short8v*)&As[row * 32 + k8] =
                *(const short8v*)(ctx + (size_t)(m0 + row) * 256 + kc + k8);
        }
#pragma unroll
        for (int c = 0; c < 4; ++c) {
            int i = c * 256 + tid;
            int row = i >> 2, k8 = (i & 3) * 8;
            *(short8v*)&Ws[row * 32 + k8] =
                *(const short8v*)(Wop + (size_t)row * 256 + kc + k8);
        }
        __syncthreads();
        short8v a = *(const short8v*)&As[(rg * 16 + rA) * 32 + k8r * 8];
#pragma unroll
        for (int ct = 0; ct < 8; ++ct) {
            short8v b = *(const short8v*)&Ws[(ch * 128 + ct * 16 + rA) * 32 + k8r * 8];
            acc[ct] = __builtin_amdgcn_mfma_f32_16x16x32_bf16(a, b, acc[ct], 0, 0, 0);
        }
        __syncthreads();
    }

    float s[4] = {0.f, 0.f, 0.f, 0.f}, q[4] = {0.f, 0.f, 0.f, 0.f};
#pragma unroll
    for (int ct = 0; ct < 8; ++ct) {
        int col = ch * 128 + ct * 16 + rA;
#pragma unroll
        for (int r = 0; r < 4; ++r) {
            int row = m0 + rg * 16 + g * 4 + r;
            float v = acc[ct][r] + epi_tok[(size_t)row * 256 + col];
            acc[ct][r] = v;
            s[r] += v; q[r] += v * v;
        }
    }
#pragma unroll
    for (int off = 8; off; off >>= 1)
#pragma unroll
        for (int r = 0; r < 4; ++r) {
            s[r] += __shfl_xor(s[r], off);
            q[r] += __shfl_xor(q[r], off);
        }
    if (rA == 0) {
#pragma unroll
        for (int r = 0; r < 4; ++r) {
            part[rg][ch][g][r][0] = s[r];
            part[rg][ch][g][r][1] = q[r];
        }
    }
    __syncthreads();
    float mu[4], rs[4];
#pragma unroll
    for (int r = 0; r < 4; ++r) {
        float S = part[rg][0][g][r][0] + part[rg][1][g][r][0];
        float Q = part[rg][0][g][r][1] + part[rg][1][g][r][1];
        mu[r] = S * (1.f / 256.f);
        rs[r] = rsqrtf(Q * (1.f / 256.f) - mu[r] * mu[r] + 1e-5f);
    }
#pragma unroll
    for (int ct = 0; ct < 8; ++ct) {
        int col = ch * 128 + ct * 16 + rA;
        float gg = g2[col], bv = b2[col];
#pragma unroll
        for (int r = 0; r < 4; ++r) {
            int lrow = rg * 16 + g * 4 + r;
            epi_tok[(size_t)(m0 + lrow) * 256 + col] = acc[ct][r];
            fb[lrow * 272 + col] = f2bf((acc[ct][r] - mu[r]) * rs[r] * gg + bv);
        }
    }
    __syncthreads();
    {
        int row = tid >> 3, vq = tid & 7;
#pragma unroll
        for (int j = 0; j < 4; ++j)
            *(short8v*)(ffin + (size_t)(m0 + row) * 256 + vq * 32 + j * 8) =
                *(const short8v*)&fb[row * 272 + vq * 32 + j * 8];
    }
}

// ---------------------------------------------------------------------------
// K6: FF2 + residual + final E->32 projection + transposed store, fused.
// ---------------------------------------------------------------------------
__global__ __launch_bounds__(256) void ff2_final_kernel(
    const unsigned short* __restrict__ ffh, const unsigned short* __restrict__ W2,
    const float* __restrict__ epi_tok, const float* __restrict__ w_out,
    float* __restrict__ out)
{
    __shared__ unsigned short As[32 * 32];
    __shared__ unsigned short Ws[256 * 32];
    __shared__ unsigned short Ts[32 * 264];

    int tid = threadIdx.x, lane = tid & 63, wv = tid >> 6;
    int m0 = blockIdx.x * 32;
    int rA = lane & 15, k8r = lane >> 4, g = lane >> 4;
    int rg = wv & 1, ch = wv >> 1;

    f32x4 acc[8];
#pragma unroll
    for (int ct = 0; ct < 8; ++ct)
#pragma unroll
        for (int r = 0; r < 4; ++r) acc[ct][r] = 0.f;

    for (int kc = 0; kc < 512; kc += 32) {
        if (tid < 128) {
            int row = tid >> 2, k8 = (tid & 3) * 8;
            *(short8v*)&As[row * 32 + k8] =
                *(const short8v*)(ffh + (size_t)(m0 + row) * 512 + kc + k8);
        }
#pragma unroll
        for (int c = 0; c < 4; ++c) {
            int i = c * 256 + tid;
            int row = i >> 2, k8 = (i & 3) * 8;
            *(short8v*)&Ws[row * 32 + k8] =
                *(const short8v*)(W2 + (size_t)row * 512 + kc + k8);
        }
        __syncthreads();
        short8v a = *(const short8v*)&As[(rg * 16 + rA) * 32 + k8r * 8];
#pragma unroll
        for (int ct = 0; ct < 8; ++ct) {
            short8v b = *(const short8v*)&Ws[(ch * 128 + ct * 16 + rA) * 32 + k8r * 8];
            acc[ct] = __builtin_amdgcn_mfma_f32_16x16x32_bf16(a, b, acc[ct], 0, 0, 0);
        }
        __syncthreads();
    }

#pragma unroll
    for (int ct = 0; ct < 8; ++ct) {
        int col = ch * 128 + ct * 16 + rA;
#pragma unroll
        for (int r = 0; r < 4; ++r) {
            int lrow = rg * 16 + g * 4 + r;
            float v = acc[ct][r] + epi_tok[(size_t)(m0 + lrow) * 256 + col];
            Ts[lrow * 264 + col] = f2bf(v);
        }
    }
    __syncthreads();

    int bn = m0 >> 10, l0 = m0 & 1023;
    int bb = bn >> 2, nn = bn & 3;

    {
        int rw = wv & 1, cw = wv >> 1;
        f32x4 a2;
#pragma unroll
        for (int r = 0; r < 4; ++r) a2[r] = 0.f;
#pragma unroll
        for (int ks = 0; ks < 8; ++ks) {
            short8v af = *(const short8v*)&Ts[(rw * 16 + rA) * 264 + ks * 32 + k8r * 8];
            const float* wp = w_out + (cw * 16 + rA) * 256 + ks * 32 + k8r * 8;
            float4 w0 = *(const float4*)wp;
            float4 w1 = *(const float4*)(wp + 4);
            short8v bf;
            bf[0] = (short)f2bf(w0.x); bf[1] = (short)f2bf(w0.y);
            bf[2] = (short)f2bf(w0.z); bf[3] = (short)f2bf(w0.w);
            bf[4] = (short)f2bf(w1.x); bf[5] = (short)f2bf(w1.y);
            bf[6] = (short)f2bf(w1.z); bf[7] = (short)f2bf(w1.w);
            a2 = __builtin_amdgcn_mfma_f32_16x16x32_bf16(af, bf, a2, 0, 0, 0);
        }
        int c = cw * 16 + rA;
        int l = l0 + rw * 16 + g * 4;
        float4 st; st.x = a2[0]; st.y = a2[1]; st.z = a2[2]; st.w = a2[3];
        *(float4*)(out + ((size_t)(bb * 32 + c) * 4 + nn) * 1024 + l) = st;
    }
}

// ---------------------------------------------------------------------------
extern "C" void kernel_launch(void* const* d_in, const int* in_sizes, int n_in,
                              void* d_out, int out_size, void* d_ws, size_t ws_size,
                              hipStream_t stream) {
    const float* x_lf       = (const float*)d_in[0];
    const float* x_hf       = (const float*)d_in[1];
    const float* w_in       = (const float*)d_in[2];
    const float* w_qk       = (const float*)d_in[3];
    const float* ln_g       = (const float*)d_in[4];
    const float* ln_b       = (const float*)d_in[5];
    const float* in_proj_w  = (const float*)d_in[6];
    const float* out_proj_w = (const float*)d_in[7];
    const float* ln2_g      = (const float*)d_in[8];
    const float* ln2_b      = (const float*)d_in[9];
    const float* ff_w1      = (const float*)d_in[10];
    const float* ff_w2      = (const float*)d_in[11];
    const float* w_out      = (const float*)d_in[12];
    float* out = (float*)d_out;

    char* w = (char*)d_ws;
    float* epi_tok         = (float*)(w);                         // 8 MB fp32
    unsigned short* Qb     = (unsigned short*)(w + (8u  << 20));  // 4 MB bf16
    unsigned short* Kb     = (unsigned short*)(w + (12u << 20));
    unsigned short* Vb     = (unsigned short*)(w + (16u << 20));
    unsigned short* q_b    = (unsigned short*)(w + (20u << 20));
    unsigned short* k_b    = (unsigned short*)(w + (24u << 20));
    unsigned short* kv_b   = (unsigned short*)(w + (28u << 20));
    unsigned short* ctx_b  = (unsigned short*)(w + (32u << 20));
    unsigned short* ffin_b = (unsigned short*)(w + (36u << 20));
    unsigned short* ffh_b  = (unsigned short*)(w + (40u << 20));  // 8 MB
    unsigned short* wqkv_b = (unsigned short*)(w + (48u << 20));
    unsigned short* wop_b  = (unsigned short*)(w + (49u << 20));
    unsigned short* wff1_b = (unsigned short*)(w + (50u << 20));
    unsigned short* wff2_b = (unsigned short*)(w + (51u << 20));

    // 1. gather + input proj + dual LN  ||  weight fp32->bf16 conversion
    embed_conv_kernel<<<256, 256, 0, stream>>>(
        x_lf, x_hf, w_in, w_qk, ln_g, ln_b, epi_tok, kv_b, q_b, k_b,
        in_proj_w, out_proj_w, ff_w1, ff_w2, wqkv_b, wop_b, wff1_b, wff2_b);
    // 2. QKV projection -> bf16 (bn,h,l,d)
    gemm_mfma<1, false, true><<<dim3(64, 2, 3), 256, 0, stream>>>(
        q_b, k_b, kv_b, wqkv_b, (void*)Qb, nullptr, 256, 256);
    // 3. local-window attention -> ctx bf16
    attn_kernel<<<2048, 256, 0, stream>>>(Qb, Kb, Vb, ctx_b);
    // 4. out_proj + residual + LN2 -> epi_tok fp32, ffin bf16
    outproj_ln_kernel<<<256, 256, 0, stream>>>(ctx_b, wop_b, epi_tok,
                                               ln2_g, ln2_b, ffin_b);
    // 5. FF1 + ReLU -> bf16 [8192,512]
    gemm_mfma<0, true, true><<<dim3(64, 4, 1), 256, 0, stream>>>(
        ffin_b, ffin_b, ffin_b, wff1_b, (void*)ffh_b, nullptr, 256, 512);
    // 6. FF2 + residual + final projection + transposed store (fused)
    ff2_final_kernel<<<256, 256, 0, stream>>>(ffh_b, wff2_b, epi_tok, w_out, out);
}

// Round 10
// 91.864 us; speedup vs baseline: 1.2505x; 1.1249x over previous
//
#include <hip/hip_runtime.h>
#include <hip/hip_bf16.h>

// Problem constants: B=2,C=32,N=4,V=32,W=32,E=256,H=8,D=32,K_H=K_W=7
// L=1024, Bn=8, M=8192.  Internal row ordering: m = bn*1024 + l  (bn-major)

typedef __attribute__((ext_vector_type(8))) short short8v;   // 8 bf16 (4 VGPR)
typedef __attribute__((ext_vector_type(4))) float f32x4;

__device__ __forceinline__ unsigned short f2bf(float x) {
    union { float f; unsigned u; } c; c.f = x;
    unsigned r = c.u + 0x7FFFu + ((c.u >> 16) & 1u);
    return (unsigned short)(r >> 16);
}
__device__ __forceinline__ float bf2f(short b) {
    union { unsigned u; float f; } c;
    c.u = ((unsigned)(unsigned short)b) << 16;
    return c.f;
}

// ---------------------------------------------------------------------------
// K1: blocks 0-127: fused gather + input projection (MFMA, 64-row tiles)
//     + dual LayerNorm.  blocks 128-255: fp32->bf16 weight conversion.
// ---------------------------------------------------------------------------
__global__ __launch_bounds__(256) void embed_conv_kernel(
    const float* __restrict__ x_lf, const float* __restrict__ x_hf,
    const float* __restrict__ w_in, const float* __restrict__ w_qk,
    const float* __restrict__ ln_g, const float* __restrict__ ln_b,
    float* __restrict__ epi_tok, unsigned short* __restrict__ kv_b,
    unsigned short* __restrict__ q_b, unsigned short* __restrict__ k_b,
    const float* __restrict__ wqkv, const float* __restrict__ wop,
    const float* __restrict__ wff1, const float* __restrict__ wff2,
    unsigned short* __restrict__ o1, unsigned short* __restrict__ o2,
    unsigned short* __restrict__ o3, unsigned short* __restrict__ o4)
{
    int tid = threadIdx.x;

    if (blockIdx.x >= 128) {
        int gid = (blockIdx.x - 128) * 256 + tid;   // 0..32767
#pragma unroll
        for (int j = 0; j < 4; ++j) {
            int i = (gid + j * 32768) * 4;
            const float* src; unsigned short* dst; int off;
            if (i < 196608)      { src = wqkv; dst = o1; off = i; }
            else if (i < 262144) { src = wop;  dst = o2; off = i - 196608; }
            else if (i < 393216) { src = wff1; dst = o3; off = i - 262144; }
            else                 { src = wff2; dst = o4; off = i - 393216; }
            float4 v = *(const float4*)(src + off);
            ushort4 u;
            u.x = f2bf(v.x); u.y = f2bf(v.y); u.z = f2bf(v.z); u.w = f2bf(v.w);
            *(ushort4*)(dst + off) = u;
        }
        return;
    }

    __shared__ float xs[2][32][65];

    int m0 = blockIdx.x * 64;
    int bn = m0 >> 10, l0 = m0 & 1023;
    int bb = bn >> 2, nn = bn & 3;

    {
        int c = tid >> 3, i0 = (tid & 7) * 8;
        size_t base = (size_t)bb * 131072 + (size_t)c * 4096 + nn * 1024 + l0 + i0;
        float4 a0 = *(const float4*)(x_lf + base);
        float4 a1 = *(const float4*)(x_lf + base + 4);
        float4 b0 = *(const float4*)(x_hf + base);
        float4 b1 = *(const float4*)(x_hf + base + 4);
        *(float4*)&xs[0][c][i0] = a0; *(float4*)&xs[0][c][i0 + 4] = a1;
        *(float4*)&xs[1][c][i0] = b0; *(float4*)&xs[1][c][i0 + 4] = b1;
    }
    __syncthreads();

    int lane = tid & 63, wv = tid >> 6;
    int rloc = wv * 16 + (lane & 15);
    int k0 = (lane >> 4) * 8;
    int g = lane >> 4;
    const float* wts[2] = { w_in, w_qk };

#pragma unroll
    for (int p = 0; p < 2; ++p) {
        short8v afrag;
#pragma unroll
        for (int j = 0; j < 8; ++j)
            afrag[j] = (short)f2bf(xs[p][k0 + j][rloc]);

        f32x4 acc[16];
#pragma unroll
        for (int ct = 0; ct < 16; ++ct)
#pragma unroll
            for (int r = 0; r < 4; ++r) acc[ct][r] = 0.f;

        const float* W = wts[p];
#pragma unroll
        for (int ct = 0; ct < 16; ++ct) {
            const float* wp = W + (ct * 16 + (lane & 15)) * 32 + k0;
            float4 w0 = *(const float4*)wp;
            float4 w1 = *(const float4*)(wp + 4);
            short8v bfrag;
            bfrag[0] = (short)f2bf(w0.x); bfrag[1] = (short)f2bf(w0.y);
            bfrag[2] = (short)f2bf(w0.z); bfrag[3] = (short)f2bf(w0.w);
            bfrag[4] = (short)f2bf(w1.x); bfrag[5] = (short)f2bf(w1.y);
            bfrag[6] = (short)f2bf(w1.z); bfrag[7] = (short)f2bf(w1.w);
            acc[ct] = __builtin_amdgcn_mfma_f32_16x16x32_bf16(afrag, bfrag, acc[ct], 0, 0, 0);
        }

        float s[4] = {0.f, 0.f, 0.f, 0.f}, q[4] = {0.f, 0.f, 0.f, 0.f};
#pragma unroll
        for (int ct = 0; ct < 16; ++ct)
#pragma unroll
            for (int r = 0; r < 4; ++r) {
                float v = acc[ct][r];
                s[r] += v; q[r] += v * v;
            }
#pragma unroll
        for (int off = 8; off; off >>= 1)
#pragma unroll
            for (int r = 0; r < 4; ++r) {
                s[r] += __shfl_xor(s[r], off);
                q[r] += __shfl_xor(q[r], off);
            }
        float mu[4], rs[4];
#pragma unroll
        for (int r = 0; r < 4; ++r) {
            mu[r] = s[r] * (1.f / 256.f);
            rs[r] = rsqrtf(q[r] * (1.f / 256.f) - mu[r] * mu[r] + 1e-5f);
        }

#pragma unroll
        for (int ct = 0; ct < 16; ++ct) {
            int col = ct * 16 + (lane & 15);
            float gg = ln_g[col], bv = ln_b[col];
#pragma unroll
            for (int r = 0; r < 4; ++r) {
                int row = m0 + wv * 16 + g * 4 + r;
                float v = acc[ct][r];
                float lnv = (v - mu[r]) * rs[r] * gg + bv;
                size_t o = (size_t)row * 256 + col;
                if (p == 0) {
                    epi_tok[o] = v;
                    q_b[o] = f2bf(lnv);
                } else {
                    kv_b[o] = f2bf(v);
                    k_b[o] = f2bf(lnv);
                }
            }
        }
    }
}

// ---------------------------------------------------------------------------
// K2: bf16 MFMA GEMM, 64x128 tile, 4 waves (each 32x64), BK=32.
// OUTMAP 0: row-major bf16.  OUTMAP 1: QKV head layout (bn,h,l,d) bf16.
// ---------------------------------------------------------------------------
template <int OUTMAP, bool RELU>
__global__ __launch_bounds__(256) void gemm_mfma64(
    const unsigned short* __restrict__ A0, const unsigned short* __restrict__ A1,
    const unsigned short* __restrict__ A2, const unsigned short* __restrict__ Wb,
    unsigned short* __restrict__ OUT, int K, int N)
{
    int z = blockIdx.z;
    const unsigned short* A = (z == 0) ? A0 : (z == 1) ? A1 : A2;
    const unsigned short* W = Wb + (size_t)z * 65536;

    __shared__ unsigned short As[64 * 32];
    __shared__ unsigned short Ws[128 * 32];

    int tid = threadIdx.x;
    int lane = tid & 63, wid = tid >> 6;
    int wm = wid >> 1, wn = wid & 1;         // wave: rows wm*32, cols wn*64
    int m0 = blockIdx.x * 64, n0 = blockIdx.y * 128;

    f32x4 acc[2][4];
#pragma unroll
    for (int i = 0; i < 2; ++i)
#pragma unroll
        for (int j = 0; j < 4; ++j)
#pragma unroll
            for (int r = 0; r < 4; ++r) acc[i][j][r] = 0.f;

    int rA = lane & 15, k8r = lane >> 4, g = lane >> 4;

    for (int kc = 0; kc < K; kc += 32) {
        {
            int row = tid >> 2, k8 = tid & 3;
            *(short8v*)&As[row * 32 + k8 * 8] =
                *(const short8v*)(A + (size_t)(m0 + row) * K + kc + k8 * 8);
        }
#pragma unroll
        for (int c = 0; c < 2; ++c) {
            int i = c * 256 + tid;
            int row = i >> 2, k8 = i & 3;
            *(short8v*)&Ws[row * 32 + k8 * 8] =
                *(const short8v*)(W + (size_t)(n0 + row) * K + kc + k8 * 8);
        }
        __syncthreads();

        short8v a[2], b[4];
#pragma unroll
        for (int mi = 0; mi < 2; ++mi)
            a[mi] = *(const short8v*)&As[(wm * 32 + mi * 16 + rA) * 32 + k8r * 8];
#pragma unroll
        for (int ni = 0; ni < 4; ++ni)
            b[ni] = *(const short8v*)&Ws[(wn * 64 + ni * 16 + rA) * 32 + k8r * 8];
#pragma unroll
        for (int mi = 0; mi < 2; ++mi)
#pragma unroll
            for (int ni = 0; ni < 4; ++ni)
                acc[mi][ni] = __builtin_amdgcn_mfma_f32_16x16x32_bf16(
                    a[mi], b[ni], acc[mi][ni], 0, 0, 0);
        __syncthreads();
    }

#pragma unroll
    for (int mi = 0; mi < 2; ++mi) {
#pragma unroll
        for (int ni = 0; ni < 4; ++ni) {
#pragma unroll
            for (int r = 0; r < 4; ++r) {
                int row = m0 + wm * 32 + mi * 16 + g * 4 + r;
                int col = n0 + wn * 64 + ni * 16 + rA;
                float v = acc[mi][ni][r];
                if (RELU) v = fmaxf(v, 0.f);
                if (OUTMAP == 0) {
                    OUT[(size_t)row * N + col] = f2bf(v);
                } else {
                    int l = row & 1023, bn = row >> 10;
                    int h = col >> 5, d = col & 31;
                    OUT[(size_t)z * 2097152 + ((bn * 8 + h) * 1024 + l) * 32 + d] = f2bf(v);
                }
            }
        }
    }
}

// ---------------------------------------------------------------------------
// K3: local-window attention, bf16 Q/K/V, fp32 math.  (unchanged)
// ---------------------------------------------------------------------------
__global__ __launch_bounds__(256) void attn_kernel(
    const unsigned short* __restrict__ Qb, const unsigned short* __restrict__ Kb,
    const unsigned short* __restrict__ Vb, unsigned short* __restrict__ ctx)
{
    int bh = blockIdx.x >> 5;
    int qv = blockIdx.x & 31;
    int tid = threadIdx.x;

    __shared__ unsigned short Ks[7][32][40];
    __shared__ unsigned short Vs[7][32][40];

#pragma unroll
    for (int it = 0; it < 4; ++it) {
        int idx = it * 256 + tid;
        if (idx < 896) {
            int dv = idx >> 7, rem = idx & 127;
            int kw = rem >> 2, c8 = (rem & 3) * 8;
            int kvc = min(max(qv - 3 + dv, 0), 31);
            size_t base = ((size_t)bh * 1024 + kvc * 32 + kw) * 32 + c8;
            *(short8v*)&Ks[dv][kw][c8] = *(const short8v*)(Kb + base);
            *(short8v*)&Vs[dv][kw][c8] = *(const short8v*)(Vb + base);
        }
    }

    int qq = tid >> 3, t = tid & 7;
    int q = qv * 32 + qq;

    float qf[32];
    {
        const short8v* qp = (const short8v*)(Qb + ((size_t)bh * 1024 + q) * 32);
#pragma unroll
        for (int i = 0; i < 4; ++i) {
            short8v v = qp[i];
#pragma unroll
            for (int j = 0; j < 8; ++j) qf[i * 8 + j] = bf2f(v[j]);
        }
    }
    __syncthreads();

    float s[7];
    int kwj[7], dvj[7];
    bool val[7];
#pragma unroll
    for (int jj = 0; jj < 7; ++jj) {
        int j = t + 8 * jj;
        int dv = j / 7, dw = j % 7;
        int kvr = qv - 3 + dv, kwr = qq - 3 + dw;
        val[jj] = (j < 49) && (kvr >= 0) && (kvr < 32) && (kwr >= 0) && (kwr < 32);
        dvj[jj] = min(dv, 6);
        kwj[jj] = kwr & 31;
    }

#pragma unroll
    for (int jj = 0; jj < 7; ++jj) {
        const unsigned short* kr = &Ks[dvj[jj]][kwj[jj]][0];
        float acc = 0.f;
#pragma unroll
        for (int i = 0; i < 4; ++i) {
            short8v k8 = *(const short8v*)(kr + i * 8);
#pragma unroll
            for (int j = 0; j < 8; ++j) acc += qf[i * 8 + j] * bf2f(k8[j]);
        }
        s[jj] = acc;
    }

    const float scale = 0.17677669529663687f;
    float mx = -1e30f;
#pragma unroll
    for (int jj = 0; jj < 7; ++jj) {
        s[jj] = val[jj] ? s[jj] * scale : -1e30f;
        mx = fmaxf(mx, s[jj]);
    }
    mx = fmaxf(mx, __shfl_xor(mx, 4));
    mx = fmaxf(mx, __shfl_xor(mx, 2));
    mx = fmaxf(mx, __shfl_xor(mx, 1));

    float e[7], sum = 0.f;
#pragma unroll
    for (int jj = 0; jj < 7; ++jj) { e[jj] = __expf(s[jj] - mx); sum += e[jj]; }
    sum += __shfl_xor(sum, 4);
    sum += __shfl_xor(sum, 2);
    sum += __shfl_xor(sum, 1);
    float inv = 1.f / sum;

    float av[32];
#pragma unroll
    for (int i = 0; i < 32; ++i) av[i] = 0.f;

#pragma unroll
    for (int jj = 0; jj < 7; ++jj) {
        float p = e[jj] * inv;
        const unsigned short* vr = &Vs[dvj[jj]][kwj[jj]][0];
#pragma unroll
        for (int i = 0; i < 4; ++i) {
            short8v v8 = *(const short8v*)(vr + i * 8);
#pragma unroll
            for (int j = 0; j < 8; ++j) av[i * 8 + j] += p * bf2f(v8[j]);
        }
    }

#pragma unroll
    for (int off = 4; off; off >>= 1)
#pragma unroll
        for (int i = 0; i < 32; ++i) av[i] += __shfl_xor(av[i], off);

    {
        int bn = bh >> 3, h = bh & 7;
        unsigned short* dst = ctx + ((size_t)bn * 1024 + q) * 256 + h * 32 + t * 4;
        ushort4 u;
        u.x = f2bf(av[t * 4 + 0]); u.y = f2bf(av[t * 4 + 1]);
        u.z = f2bf(av[t * 4 + 2]); u.w = f2bf(av[t * 4 + 3]);
        *(ushort4*)dst = u;
    }
}

// ---------------------------------------------------------------------------
// K4: out_proj + residual + LN2.  32-row tile, 512 threads / 8 waves.
// Wave: rg = wv&1 (16 rows), ch = wv>>2? no: ch = wv>>1 in 0..3 (64 cols).
// ---------------------------------------------------------------------------
__global__ __launch_bounds__(512) void outproj_ln_kernel(
    const unsigned short* __restrict__ ctx, const unsigned short* __restrict__ Wop,
    float* __restrict__ epi_tok, const float* __restrict__ g2,
    const float* __restrict__ b2, unsigned short* __restrict__ ffin)
{
    __shared__ unsigned short As[32 * 32];
    __shared__ unsigned short Ws[256 * 32];
    __shared__ float part[2][4][4][4][2];   // [rg][ch][g][r][{s,q}]

    int tid = threadIdx.x, lane = tid & 63, wv = tid >> 6;
    int m0 = blockIdx.x * 32;
    int rA = lane & 15, k8r = lane >> 4, g = lane >> 4;
    int rg = wv & 1, ch = wv >> 1;          // ch in 0..3

    f32x4 acc[4];
#pragma unroll
    for (int ct = 0; ct < 4; ++ct)
#pragma unroll
        for (int r = 0; r < 4; ++r) acc[ct][r] = 0.f;

    for (int kc = 0; kc < 256; kc += 32) {
        if (tid < 128) {
            int row = tid >> 2, k8 = (tid & 3) * 8;
            *(short8v*)&As[row * 32 + k8] =
                *(const short8v*)(ctx + (size_t)(m0 + row) * 256 + kc + k8);
        }
#pragma unroll
        for (int c = 0; c < 2; ++c) {
            int i = c * 512 + tid;
            int row = i >> 2, k8 = (i & 3) * 8;
            *(short8v*)&Ws[row * 32 + k8] =
                *(const short8v*)(Wop + (size_t)row * 256 + kc + k8);
        }
        __syncthreads();
        short8v a = *(const short8v*)&As[(rg * 16 + rA) * 32 + k8r * 8];
#pragma unroll
        for (int ct = 0; ct < 4; ++ct) {
            short8v b = *(const short8v*)&Ws[(ch * 64 + ct * 16 + rA) * 32 + k8r * 8];
            acc[ct] = __builtin_amdgcn_mfma_f32_16x16x32_bf16(a, b, acc[ct], 0, 0, 0);
        }
        __syncthreads();
    }

    float s[4] = {0.f, 0.f, 0.f, 0.f}, q[4] = {0.f, 0.f, 0.f, 0.f};
#pragma unroll
    for (int ct = 0; ct < 4; ++ct) {
        int col = ch * 64 + ct * 16 + rA;
#pragma unroll
        for (int r = 0; r < 4; ++r) {
            int row = m0 + rg * 16 + g * 4 + r;
            float v = acc[ct][r] + epi_tok[(size_t)row * 256 + col];
            acc[ct][r] = v;
            s[r] += v; q[r] += v * v;
        }
    }
#pragma unroll
    for (int off = 8; off; off >>= 1)
#pragma unroll
        for (int r = 0; r < 4; ++r) {
            s[r] += __shfl_xor(s[r], off);
            q[r] += __shfl_xor(q[r], off);
        }
    if (rA == 0) {
#pragma unroll
        for (int r = 0; r < 4; ++r) {
            part[rg][ch][g][r][0] = s[r];
            part[rg][ch][g][r][1] = q[r];
        }
    }
    __syncthreads();
    float mu[4], rs[4];
#pragma unroll
    for (int r = 0; r < 4; ++r) {
        float S = part[rg][0][g][r][0] + part[rg][1][g][r][0]
                + part[rg][2][g][r][0] + part[rg][3][g][r][0];
        float Q = part[rg][0][g][r][1] + part[rg][1][g][r][1]
                + part[rg][2][g][r][1] + part[rg][3][g][r][1];
        mu[r] = S * (1.f / 256.f);
        rs[r] = rsqrtf(Q * (1.f / 256.f) - mu[r] * mu[r] + 1e-5f);
    }
#pragma unroll
    for (int ct = 0; ct < 4; ++ct) {
        int col = ch * 64 + ct * 16 + rA;
        float gg = g2[col], bv = b2[col];
#pragma unroll
        for (int r = 0; r < 4; ++r) {
            int row = m0 + rg * 16 + g * 4 + r;
            size_t o = (size_t)row * 256 + col;
            epi_tok[o] = acc[ct][r];
            ffin[o] = f2bf((acc[ct][r] - mu[r]) * rs[r] * gg + bv);
        }
    }
}

// ---------------------------------------------------------------------------
// K6: FF2 + residual + final E->32 projection + transposed store, fused.
// 32-row tile, 512 threads / 8 waves (stage 1); stage 2 uses waves 0-3.
// ---------------------------------------------------------------------------
__global__ __launch_bounds__(512) void ff2_final_kernel(
    const unsigned short* __restrict__ ffh, const unsigned short* __restrict__ W2,
    const float* __restrict__ epi_tok, const float* __restrict__ w_out,
    float* __restrict__ out)
{
    __shared__ unsigned short As[32 * 32];
    __shared__ unsigned short Ws[256 * 32];
    __shared__ unsigned short Ts[32 * 264];

    int tid = threadIdx.x, lane = tid & 63, wv = tid >> 6;
    int m0 = blockIdx.x * 32;
    int rA = lane & 15, k8r = lane >> 4, g = lane >> 4;
    int rg = wv & 1, ch = wv >> 1;          // ch in 0..3

    f32x4 acc[4];
#pragma unroll
    for (int ct = 0; ct < 4; ++ct)
#pragma unroll
        for (int r = 0; r < 4; ++r) acc[ct][r] = 0.f;

    for (int kc = 0; kc < 512; kc += 32) {
        if (tid < 128) {
            int row = tid >> 2, k8 = (tid & 3) * 8;
            *(short8v*)&As[row * 32 + k8] =
                *(const short8v*)(ffh + (size_t)(m0 + row) * 512 + kc + k8);
        }
#pragma unroll
        for (int c = 0; c < 2; ++c) {
            int i = c * 512 + tid;
            int row = i >> 2, k8 = (i & 3) * 8;
            *(short8v*)&Ws[row * 32 + k8] =
                *(const short8v*)(W2 + (size_t)row * 512 + kc + k8);
        }
        __syncthreads();
        short8v a = *(const short8v*)&As[(rg * 16 + rA) * 32 + k8r * 8];
#pragma unroll
        for (int ct = 0; ct < 4; ++ct) {
            short8v b = *(const short8v*)&Ws[(ch * 64 + ct * 16 + rA) * 32 + k8r * 8];
            acc[ct] = __builtin_amdgcn_mfma_f32_16x16x32_bf16(a, b, acc[ct], 0, 0, 0);
        }
        __syncthreads();
    }

    // residual add; write T = final epi_token tile to LDS (bf16)
#pragma unroll
    for (int ct = 0; ct < 4; ++ct) {
        int col = ch * 64 + ct * 16 + rA;
#pragma unroll
        for (int r = 0; r < 4; ++r) {
            int lrow = rg * 16 + g * 4 + r;
            float v = acc[ct][r] + epi_tok[(size_t)(m0 + lrow) * 256 + col];
            Ts[lrow * 264 + col] = f2bf(v);
        }
    }
    __syncthreads();

    int bn = m0 >> 10, l0 = m0 & 1023;
    int bb = bn >> 2, nn = bn & 3;

    // stage 2: waves 0-3 -> rows (w&1)*16, cols (w>>1)*16 of the 32x32 output
    if (wv < 4) {
        int rw = wv & 1, cw = wv >> 1;
        f32x4 a2;
#pragma unroll
        for (int r = 0; r < 4; ++r) a2[r] = 0.f;
#pragma unroll
        for (int ks = 0; ks < 8; ++ks) {
            short8v af = *(const short8v*)&Ts[(rw * 16 + rA) * 264 + ks * 32 + k8r * 8];
            const float* wp = w_out + (cw * 16 + rA) * 256 + ks * 32 + k8r * 8;
            float4 w0 = *(const float4*)wp;
            float4 w1 = *(const float4*)(wp + 4);
            short8v bf;
            bf[0] = (short)f2bf(w0.x); bf[1] = (short)f2bf(w0.y);
            bf[2] = (short)f2bf(w0.z); bf[3] = (short)f2bf(w0.w);
            bf[4] = (short)f2bf(w1.x); bf[5] = (short)f2bf(w1.y);
            bf[6] = (short)f2bf(w1.z); bf[7] = (short)f2bf(w1.w);
            a2 = __builtin_amdgcn_mfma_f32_16x16x32_bf16(af, bf, a2, 0, 0, 0);
        }
        int c = cw * 16 + rA;
        int l = l0 + rw * 16 + g * 4;
        float4 st; st.x = a2[0]; st.y = a2[1]; st.z = a2[2]; st.w = a2[3];
        *(float4*)(out + ((size_t)(bb * 32 + c) * 4 + nn) * 1024 + l) = st;
    }
}

// ---------------------------------------------------------------------------
extern "C" void kernel_launch(void* const* d_in, const int* in_sizes, int n_in,
                              void* d_out, int out_size, void* d_ws, size_t ws_size,
                              hipStream_t stream) {
    const float* x_lf       = (const float*)d_in[0];
    const float* x_hf       = (const float*)d_in[1];
    const float* w_in       = (const float*)d_in[2];
    const float* w_qk       = (const float*)d_in[3];
    const float* ln_g       = (const float*)d_in[4];
    const float* ln_b       = (const float*)d_in[5];
    const float* in_proj_w  = (const float*)d_in[6];
    const float* out_proj_w = (const float*)d_in[7];
    const float* ln2_g      = (const float*)d_in[8];
    const float* ln2_b      = (const float*)d_in[9];
    const float* ff_w1      = (const float*)d_in[10];
    const float* ff_w2      = (const float*)d_in[11];
    const float* w_out      = (const float*)d_in[12];
    float* out = (float*)d_out;

    char* w = (char*)d_ws;
    float* epi_tok         = (float*)(w);                         // 8 MB fp32
    unsigned short* Qb     = (unsigned short*)(w + (8u  << 20));  // 4 MB bf16
    unsigned short* Kb     = (unsigned short*)(w + (12u << 20));
    unsigned short* Vb     = (unsigned short*)(w + (16u << 20));
    unsigned short* q_b    = (unsigned short*)(w + (20u << 20));
    unsigned short* k_b    = (unsigned short*)(w + (24u << 20));
    unsigned short* kv_b   = (unsigned short*)(w + (28u << 20));
    unsigned short* ctx_b  = (unsigned short*)(w + (32u << 20));
    unsigned short* ffin_b = (unsigned short*)(w + (36u << 20));
    unsigned short* ffh_b  = (unsigned short*)(w + (40u << 20));  // 8 MB
    unsigned short* wqkv_b = (unsigned short*)(w + (48u << 20));
    unsigned short* wop_b  = (unsigned short*)(w + (49u << 20));
    unsigned short* wff1_b = (unsigned short*)(w + (50u << 20));
    unsigned short* wff2_b = (unsigned short*)(w + (51u << 20));

    // 1. gather + input proj + dual LN  ||  weight fp32->bf16 conversion
    embed_conv_kernel<<<256, 256, 0, stream>>>(
        x_lf, x_hf, w_in, w_qk, ln_g, ln_b, epi_tok, kv_b, q_b, k_b,
        in_proj_w, out_proj_w, ff_w1, ff_w2, wqkv_b, wop_b, wff1_b, wff2_b);
    // 2. QKV projection -> bf16 (bn,h,l,d)   [768 blocks = 3/CU]
    gemm_mfma64<1, false><<<dim3(128, 2, 3), 256, 0, stream>>>(
        q_b, k_b, kv_b, wqkv_b, Qb, 256, 256);
    // 3. local-window attention -> ctx bf16
    attn_kernel<<<2048, 256, 0, stream>>>(Qb, Kb, Vb, ctx_b);
    // 4. out_proj + residual + LN2 -> epi_tok fp32, ffin bf16  [512 thr]
    outproj_ln_kernel<<<256, 512, 0, stream>>>(ctx_b, wop_b, epi_tok,
                                               ln2_g, ln2_b, ffin_b);
    // 5. FF1 + ReLU -> bf16 [8192,512]   [512 blocks = 2/CU]
    gemm_mfma64<0, true><<<dim3(128, 4, 1), 256, 0, stream>>>(
        ffin_b, ffin_b, ffin_b, wff1_b, ffh_b, 256, 512);
    // 6. FF2 + residual + final projection + transposed store  [512 thr]
    ff2_final_kernel<<<256, 512, 0, stream>>>(ffh_b, wff2_b, epi_tok, w_out, out);
}

// Round 11
// 85.630 us; speedup vs baseline: 1.3415x; 1.0728x over previous
//
#include <hip/hip_runtime.h>
#include <hip/hip_bf16.h>

// Problem constants: B=2,C=32,N=4,V=32,W=32,E=256,H=8,D=32,K_H=K_W=7
// L=1024, Bn=8, M=8192.  Internal row ordering: m = bn*1024 + l  (bn-major)

typedef __attribute__((ext_vector_type(8))) short short8v;   // 8 bf16 (4 VGPR)
typedef __attribute__((ext_vector_type(4))) float f32x4;

__device__ __forceinline__ unsigned short f2bf(float x) {
    union { float f; unsigned u; } c; c.f = x;
    unsigned r = c.u + 0x7FFFu + ((c.u >> 16) & 1u);
    return (unsigned short)(r >> 16);
}
__device__ __forceinline__ float bf2f(short b) {
    union { unsigned u; float f; } c;
    c.u = ((unsigned)(unsigned short)b) << 16;
    return c.f;
}

// ---------------------------------------------------------------------------
// K1: blocks 0-127: fused gather + input projection (MFMA, 64-row tiles)
//     + dual LayerNorm.  blocks 128-255: fp32->bf16 weight conversion.
// ---------------------------------------------------------------------------
__global__ __launch_bounds__(256) void embed_conv_kernel(
    const float* __restrict__ x_lf, const float* __restrict__ x_hf,
    const float* __restrict__ w_in, const float* __restrict__ w_qk,
    const float* __restrict__ ln_g, const float* __restrict__ ln_b,
    float* __restrict__ epi_tok, unsigned short* __restrict__ kv_b,
    unsigned short* __restrict__ q_b, unsigned short* __restrict__ k_b,
    const float* __restrict__ wqkv, const float* __restrict__ wop,
    const float* __restrict__ wff1, const float* __restrict__ wff2,
    unsigned short* __restrict__ o1, unsigned short* __restrict__ o2,
    unsigned short* __restrict__ o3, unsigned short* __restrict__ o4)
{
    int tid = threadIdx.x;

    if (blockIdx.x >= 128) {
        int gid = (blockIdx.x - 128) * 256 + tid;   // 0..32767
#pragma unroll
        for (int j = 0; j < 4; ++j) {
            int i = (gid + j * 32768) * 4;
            const float* src; unsigned short* dst; int off;
            if (i < 196608)      { src = wqkv; dst = o1; off = i; }
            else if (i < 262144) { src = wop;  dst = o2; off = i - 196608; }
            else if (i < 393216) { src = wff1; dst = o3; off = i - 262144; }
            else                 { src = wff2; dst = o4; off = i - 393216; }
            float4 v = *(const float4*)(src + off);
            ushort4 u;
            u.x = f2bf(v.x); u.y = f2bf(v.y); u.z = f2bf(v.z); u.w = f2bf(v.w);
            *(ushort4*)(dst + off) = u;
        }
        return;
    }

    __shared__ float xs[2][32][65];

    int m0 = blockIdx.x * 64;
    int bn = m0 >> 10, l0 = m0 & 1023;
    int bb = bn >> 2, nn = bn & 3;

    {
        int c = tid >> 3, i0 = (tid & 7) * 8;
        size_t base = (size_t)bb * 131072 + (size_t)c * 4096 + nn * 1024 + l0 + i0;
        float4 a0 = *(const float4*)(x_lf + base);
        float4 a1 = *(const float4*)(x_lf + base + 4);
        float4 b0 = *(const float4*)(x_hf + base);
        float4 b1 = *(const float4*)(x_hf + base + 4);
        *(float4*)&xs[0][c][i0] = a0; *(float4*)&xs[0][c][i0 + 4] = a1;
        *(float4*)&xs[1][c][i0] = b0; *(float4*)&xs[1][c][i0 + 4] = b1;
    }
    __syncthreads();

    int lane = tid & 63, wv = tid >> 6;
    int rloc = wv * 16 + (lane & 15);
    int k0 = (lane >> 4) * 8;
    int g = lane >> 4;
    const float* wts[2] = { w_in, w_qk };

#pragma unroll
    for (int p = 0; p < 2; ++p) {
        short8v afrag;
#pragma unroll
        for (int j = 0; j < 8; ++j)
            afrag[j] = (short)f2bf(xs[p][k0 + j][rloc]);

        f32x4 acc[16];
#pragma unroll
        for (int ct = 0; ct < 16; ++ct)
#pragma unroll
            for (int r = 0; r < 4; ++r) acc[ct][r] = 0.f;

        const float* W = wts[p];
#pragma unroll
        for (int ct = 0; ct < 16; ++ct) {
            const float* wp = W + (ct * 16 + (lane & 15)) * 32 + k0;
            float4 w0 = *(const float4*)wp;
            float4 w1 = *(const float4*)(wp + 4);
            short8v bfrag;
            bfrag[0] = (short)f2bf(w0.x); bfrag[1] = (short)f2bf(w0.y);
            bfrag[2] = (short)f2bf(w0.z); bfrag[3] = (short)f2bf(w0.w);
            bfrag[4] = (short)f2bf(w1.x); bfrag[5] = (short)f2bf(w1.y);
            bfrag[6] = (short)f2bf(w1.z); bfrag[7] = (short)f2bf(w1.w);
            acc[ct] = __builtin_amdgcn_mfma_f32_16x16x32_bf16(afrag, bfrag, acc[ct], 0, 0, 0);
        }

        float s[4] = {0.f, 0.f, 0.f, 0.f}, q[4] = {0.f, 0.f, 0.f, 0.f};
#pragma unroll
        for (int ct = 0; ct < 16; ++ct)
#pragma unroll
            for (int r = 0; r < 4; ++r) {
                float v = acc[ct][r];
                s[r] += v; q[r] += v * v;
            }
#pragma unroll
        for (int off = 8; off; off >>= 1)
#pragma unroll
            for (int r = 0; r < 4; ++r) {
                s[r] += __shfl_xor(s[r], off);
                q[r] += __shfl_xor(q[r], off);
            }
        float mu[4], rs[4];
#pragma unroll
        for (int r = 0; r < 4; ++r) {
            mu[r] = s[r] * (1.f / 256.f);
            rs[r] = rsqrtf(q[r] * (1.f / 256.f) - mu[r] * mu[r] + 1e-5f);
        }

#pragma unroll
        for (int ct = 0; ct < 16; ++ct) {
            int col = ct * 16 + (lane & 15);
            float gg = ln_g[col], bv = ln_b[col];
#pragma unroll
            for (int r = 0; r < 4; ++r) {
                int row = m0 + wv * 16 + g * 4 + r;
                float v = acc[ct][r];
                float lnv = (v - mu[r]) * rs[r] * gg + bv;
                size_t o = (size_t)row * 256 + col;
                if (p == 0) {
                    epi_tok[o] = v;
                    q_b[o] = f2bf(lnv);
                } else {
                    kv_b[o] = f2bf(v);
                    k_b[o] = f2bf(lnv);
                }
            }
        }
    }
}

// ---------------------------------------------------------------------------
// K2: bf16 MFMA GEMM, 64x128 tile, 4 waves (each 32x64), BK=32.
// OUTMAP 0: row-major bf16.  OUTMAP 1: QKV head layout (bn,h,l,d) bf16.
// ---------------------------------------------------------------------------
template <int OUTMAP, bool RELU>
__global__ __launch_bounds__(256) void gemm_mfma64(
    const unsigned short* __restrict__ A0, const unsigned short* __restrict__ A1,
    const unsigned short* __restrict__ A2, const unsigned short* __restrict__ Wb,
    unsigned short* __restrict__ OUT, int K, int N)
{
    int z = blockIdx.z;
    const unsigned short* A = (z == 0) ? A0 : (z == 1) ? A1 : A2;
    const unsigned short* W = Wb + (size_t)z * 65536;

    __shared__ unsigned short As[64 * 32];
    __shared__ unsigned short Ws[128 * 32];

    int tid = threadIdx.x;
    int lane = tid & 63, wid = tid >> 6;
    int wm = wid >> 1, wn = wid & 1;
    int m0 = blockIdx.x * 64, n0 = blockIdx.y * 128;

    f32x4 acc[2][4];
#pragma unroll
    for (int i = 0; i < 2; ++i)
#pragma unroll
        for (int j = 0; j < 4; ++j)
#pragma unroll
            for (int r = 0; r < 4; ++r) acc[i][j][r] = 0.f;

    int rA = lane & 15, k8r = lane >> 4, g = lane >> 4;

    for (int kc = 0; kc < K; kc += 32) {
        {
            int row = tid >> 2, k8 = tid & 3;
            *(short8v*)&As[row * 32 + k8 * 8] =
                *(const short8v*)(A + (size_t)(m0 + row) * K + kc + k8 * 8);
        }
#pragma unroll
        for (int c = 0; c < 2; ++c) {
            int i = c * 256 + tid;
            int row = i >> 2, k8 = i & 3;
            *(short8v*)&Ws[row * 32 + k8 * 8] =
                *(const short8v*)(W + (size_t)(n0 + row) * K + kc + k8 * 8);
        }
        __syncthreads();

        short8v a[2], b[4];
#pragma unroll
        for (int mi = 0; mi < 2; ++mi)
            a[mi] = *(const short8v*)&As[(wm * 32 + mi * 16 + rA) * 32 + k8r * 8];
#pragma unroll
        for (int ni = 0; ni < 4; ++ni)
            b[ni] = *(const short8v*)&Ws[(wn * 64 + ni * 16 + rA) * 32 + k8r * 8];
#pragma unroll
        for (int mi = 0; mi < 2; ++mi)
#pragma unroll
            for (int ni = 0; ni < 4; ++ni)
                acc[mi][ni] = __builtin_amdgcn_mfma_f32_16x16x32_bf16(
                    a[mi], b[ni], acc[mi][ni], 0, 0, 0);
        __syncthreads();
    }

#pragma unroll
    for (int mi = 0; mi < 2; ++mi) {
#pragma unroll
        for (int ni = 0; ni < 4; ++ni) {
#pragma unroll
            for (int r = 0; r < 4; ++r) {
                int row = m0 + wm * 32 + mi * 16 + g * 4 + r;
                int col = n0 + wn * 64 + ni * 16 + rA;
                float v = acc[mi][ni][r];
                if (RELU) v = fmaxf(v, 0.f);
                if (OUTMAP == 0) {
                    OUT[(size_t)row * N + col] = f2bf(v);
                } else {
                    int l = row & 1023, bn = row >> 10;
                    int h = col >> 5, d = col & 31;
                    OUT[(size_t)z * 2097152 + ((bn * 8 + h) * 1024 + l) * 32 + d] = f2bf(v);
                }
            }
        }
    }
}

// ---------------------------------------------------------------------------
// K3: local-window attention, MFMA version.
// Block per (bh, qv): 32 queries x 224 candidate keys (7 kv-rows x 32 kw).
// QK^T: 28 MFMAs (2 m-tiles x 14 n-tiles).  Window mask in C-fragments.
// Wave-parallel softmax (16-lane shfl + cross-wave LDS).  P -> bf16 LDS.
// PV: 28 MFMAs against transposed-staged V.  ctx out (bn-major, L,Bn,E).
// ---------------------------------------------------------------------------
__global__ __launch_bounds__(256) void attn_mfma_kernel(
    const unsigned short* __restrict__ Qb, const unsigned short* __restrict__ Kb,
    const unsigned short* __restrict__ Vb, unsigned short* __restrict__ ctx)
{
    int bh = blockIdx.x >> 5;       // bn*8 + h
    int qv = blockIdx.x & 31;
    int tid = threadIdx.x, lane = tid & 63, wv = tid >> 6;
    int rA = lane & 15, k8r = lane >> 4, g = lane >> 4;

    __shared__ unsigned short Ks[7 * 32 * 40];   // [key n][d], pitch 40
    __shared__ unsigned short Vt[32 * 232];      // [d][key n], pitch 232
    __shared__ unsigned short Ps[32 * 232];      // [q][key n], pitch 232
    __shared__ float redm[2][2][4][4];           // [mt][nh][g][r] row max
    __shared__ float reds[2][2][4][4];           // [mt][nh][g][r] row sum

    int mt = wv & 1, nh = wv >> 1;   // m-tile (16 q), n-half (112 keys / d-tile)

    // Q A-fragment straight from global (L2-hot)
    short8v qfrag = *(const short8v*)(
        Qb + ((size_t)bh * 1024 + qv * 32 + mt * 16 + rA) * 32 + k8r * 8);

    // stage K (row-major, pitch 40) and V transposed (Vt[d][n], pitch 232)
#pragma unroll
    for (int it = 0; it < 4; ++it) {
        int idx = it * 256 + tid;
        if (idx < 896) {
            int dv = idx >> 7, rem = idx & 127;
            int kw = rem >> 2, c8 = (rem & 3) * 8;
            int kvc = min(max(qv - 3 + dv, 0), 31);
            size_t base = ((size_t)bh * 1024 + kvc * 32 + kw) * 32 + c8;
            int n = dv * 32 + kw;
            *(short8v*)&Ks[n * 40 + c8] = *(const short8v*)(Kb + base);
            short8v v8 = *(const short8v*)(Vb + base);
#pragma unroll
            for (int j = 0; j < 8; ++j)
                Vt[(c8 + j) * 232 + n] = (unsigned short)v8[j];
        }
    }
    __syncthreads();

    // QK^T: wave (mt, nh) -> 7 n-tiles of 16 keys
    f32x4 sc[7];
#pragma unroll
    for (int ct = 0; ct < 7; ++ct)
#pragma unroll
        for (int r = 0; r < 4; ++r) sc[ct][r] = 0.f;
#pragma unroll
    for (int ct = 0; ct < 7; ++ct) {
        short8v b = *(const short8v*)&Ks[(nh * 112 + ct * 16 + rA) * 40 + k8r * 8];
        sc[ct] = __builtin_amdgcn_mfma_f32_16x16x32_bf16(qfrag, b, sc[ct], 0, 0, 0);
    }

    // mask + scale + row max.  C layout: col(key)=rA, row(q)=g*4+r
    const float scale = 0.17677669529663687f;
    float mx[4] = {-1e30f, -1e30f, -1e30f, -1e30f};
#pragma unroll
    for (int ct = 0; ct < 7; ++ct) {
        int n = nh * 112 + ct * 16 + rA;
        int dv = n >> 5, kw = n & 31;
        int kv = qv - 3 + dv;
        bool vv = (kv >= 0) && (kv < 32);
#pragma unroll
        for (int r = 0; r < 4; ++r) {
            int qw = mt * 16 + g * 4 + r;
            int dj = kw - qw;
            bool ok = vv && (dj >= -3) && (dj <= 3);
            float s = ok ? sc[ct][r] * scale : -1e30f;
            sc[ct][r] = s;
            mx[r] = fmaxf(mx[r], s);
        }
    }
#pragma unroll
    for (int off = 8; off; off >>= 1)
#pragma unroll
        for (int r = 0; r < 4; ++r) mx[r] = fmaxf(mx[r], __shfl_xor(mx[r], off));
    if (rA == 0) {
#pragma unroll
        for (int r = 0; r < 4; ++r) redm[mt][nh][g][r] = mx[r];
    }
    __syncthreads();
#pragma unroll
    for (int r = 0; r < 4; ++r)
        mx[r] = fmaxf(redm[mt][0][g][r], redm[mt][1][g][r]);

    // exp + row sum
    float sm[4] = {0.f, 0.f, 0.f, 0.f};
#pragma unroll
    for (int ct = 0; ct < 7; ++ct)
#pragma unroll
        for (int r = 0; r < 4; ++r) {
            float e = __expf(sc[ct][r] - mx[r]);
            sc[ct][r] = e;
            sm[r] += e;
        }
#pragma unroll
    for (int off = 8; off; off >>= 1)
#pragma unroll
        for (int r = 0; r < 4; ++r) sm[r] += __shfl_xor(sm[r], off);
    if (rA == 0) {
#pragma unroll
        for (int r = 0; r < 4; ++r) reds[mt][nh][g][r] = sm[r];
    }
    __syncthreads();
    float inv[4];
#pragma unroll
    for (int r = 0; r < 4; ++r)
        inv[r] = 1.f / (reds[mt][0][g][r] + reds[mt][1][g][r]);

    // P -> bf16 LDS [q][n]
#pragma unroll
    for (int ct = 0; ct < 7; ++ct) {
        int n = nh * 112 + ct * 16 + rA;
#pragma unroll
        for (int r = 0; r < 4; ++r) {
            int q = mt * 16 + g * 4 + r;
            Ps[q * 232 + n] = f2bf(sc[ct][r] * inv[r]);
        }
    }
    __syncthreads();

    // PV: wave (mt, nt=nh) -> 16q x 16d, 7 k-steps over 224 keys
    f32x4 o;
#pragma unroll
    for (int r = 0; r < 4; ++r) o[r] = 0.f;
#pragma unroll
    for (int kb = 0; kb < 7; ++kb) {
        short8v pa = *(const short8v*)&Ps[(mt * 16 + rA) * 232 + kb * 32 + k8r * 8];
        short8v vb = *(const short8v*)&Vt[(nh * 16 + rA) * 232 + kb * 32 + k8r * 8];
        o = __builtin_amdgcn_mfma_f32_16x16x32_bf16(pa, vb, o, 0, 0, 0);
    }

    {
        int bn = bh >> 3, h = bh & 7;
        int d = nh * 16 + rA;
#pragma unroll
        for (int r = 0; r < 4; ++r) {
            int q = qv * 32 + mt * 16 + g * 4 + r;
            ctx[((size_t)bn * 1024 + q) * 256 + h * 32 + d] = f2bf(o[r]);
        }
    }
}

// ---------------------------------------------------------------------------
// K4: out_proj + residual + LN2.  32-row tile, 512 threads / 8 waves.
// ---------------------------------------------------------------------------
__global__ __launch_bounds__(512) void outproj_ln_kernel(
    const unsigned short* __restrict__ ctx, const unsigned short* __restrict__ Wop,
    float* __restrict__ epi_tok, const float* __restrict__ g2,
    const float* __restrict__ b2, unsigned short* __restrict__ ffin)
{
    __shared__ unsigned short As[32 * 32];
    __shared__ unsigned short Ws[256 * 32];
    __shared__ float part[2][4][4][4][2];   // [rg][ch][g][r][{s,q}]

    int tid = threadIdx.x, lane = tid & 63, wv = tid >> 6;
    int m0 = blockIdx.x * 32;
    int rA = lane & 15, k8r = lane >> 4, g = lane >> 4;
    int rg = wv & 1, ch = wv >> 1;          // ch in 0..3

    f32x4 acc[4];
#pragma unroll
    for (int ct = 0; ct < 4; ++ct)
#pragma unroll
        for (int r = 0; r < 4; ++r) acc[ct][r] = 0.f;

    for (int kc = 0; kc < 256; kc += 32) {
        if (tid < 128) {
            int row = tid >> 2, k8 = (tid & 3) * 8;
            *(short8v*)&As[row * 32 + k8] =
                *(const short8v*)(ctx + (size_t)(m0 + row) * 256 + kc + k8);
        }
#pragma unroll
        for (int c = 0; c < 2; ++c) {
            int i = c * 512 + tid;
            int row = i >> 2, k8 = (i & 3) * 8;
            *(short8v*)&Ws[row * 32 + k8] =
                *(const short8v*)(Wop + (size_t)row * 256 + kc + k8);
        }
        __syncthreads();
        short8v a = *(const short8v*)&As[(rg * 16 + rA) * 32 + k8r * 8];
#pragma unroll
        for (int ct = 0; ct < 4; ++ct) {
            short8v b = *(const short8v*)&Ws[(ch * 64 + ct * 16 + rA) * 32 + k8r * 8];
            acc[ct] = __builtin_amdgcn_mfma_f32_16x16x32_bf16(a, b, acc[ct], 0, 0, 0);
        }
        __syncthreads();
    }

    float s[4] = {0.f, 0.f, 0.f, 0.f}, q[4] = {0.f, 0.f, 0.f, 0.f};
#pragma unroll
    for (int ct = 0; ct < 4; ++ct) {
        int col = ch * 64 + ct * 16 + rA;
#pragma unroll
        for (int r = 0; r < 4; ++r) {
            int row = m0 + rg * 16 + g * 4 + r;
            float v = acc[ct][r] + epi_tok[(size_t)row * 256 + col];
            acc[ct][r] = v;
            s[r] += v; q[r] += v * v;
        }
    }
#pragma unroll
    for (int off = 8; off; off >>= 1)
#pragma unroll
        for (int r = 0; r < 4; ++r) {
            s[r] += __shfl_xor(s[r], off);
            q[r] += __shfl_xor(q[r], off);
        }
    if (rA == 0) {
#pragma unroll
        for (int r = 0; r < 4; ++r) {
            part[rg][ch][g][r][0] = s[r];
            part[rg][ch][g][r][1] = q[r];
        }
    }
    __syncthreads();
    float mu[4], rs[4];
#pragma unroll
    for (int r = 0; r < 4; ++r) {
        float S = part[rg][0][g][r][0] + part[rg][1][g][r][0]
                + part[rg][2][g][r][0] + part[rg][3][g][r][0];
        float Q = part[rg][0][g][r][1] + part[rg][1][g][r][1]
                + part[rg][2][g][r][1] + part[rg][3][g][r][1];
        mu[r] = S * (1.f / 256.f);
        rs[r] = rsqrtf(Q * (1.f / 256.f) - mu[r] * mu[r] + 1e-5f);
    }
#pragma unroll
    for (int ct = 0; ct < 4; ++ct) {
        int col = ch * 64 + ct * 16 + rA;
        float gg = g2[col], bv = b2[col];
#pragma unroll
        for (int r = 0; r < 4; ++r) {
            int row = m0 + rg * 16 + g * 4 + r;
            size_t o = (size_t)row * 256 + col;
            epi_tok[o] = acc[ct][r];
            ffin[o] = f2bf((acc[ct][r] - mu[r]) * rs[r] * gg + bv);
        }
    }
}

// ---------------------------------------------------------------------------
// K6: FF2 + residual + final E->32 projection + transposed store, fused.
// 32-row tile, 512 threads / 8 waves (stage 1); stage 2 uses waves 0-3.
// ---------------------------------------------------------------------------
__global__ __launch_bounds__(512) void ff2_final_kernel(
    const unsigned short* __restrict__ ffh, const unsigned short* __restrict__ W2,
    const float* __restrict__ epi_tok, const float* __restrict__ w_out,
    float* __restrict__ out)
{
    __shared__ unsigned short As[32 * 32];
    __shared__ unsigned short Ws[256 * 32];
    __shared__ unsigned short Ts[32 * 264];

    int tid = threadIdx.x, lane = tid & 63, wv = tid >> 6;
    int m0 = blockIdx.x * 32;
    int rA = lane & 15, k8r = lane >> 4, g = lane >> 4;
    int rg = wv & 1, ch = wv >> 1;          // ch in 0..3

    f32x4 acc[4];
#pragma unroll
    for (int ct = 0; ct < 4; ++ct)
#pragma unroll
        for (int r = 0; r < 4; ++r) acc[ct][r] = 0.f;

    for (int kc = 0; kc < 512; kc += 32) {
        if (tid < 128) {
            int row = tid >> 2, k8 = (tid & 3) * 8;
            *(short8v*)&As[row * 32 + k8] =
                *(const short8v*)(ffh + (size_t)(m0 + row) * 512 + kc + k8);
        }
#pragma unroll
        for (int c = 0; c < 2; ++c) {
            int i = c * 512 + tid;
            int row = i >> 2, k8 = (i & 3) * 8;
            *(short8v*)&Ws[row * 32 + k8] =
                *(const short8v*)(W2 + (size_t)row * 512 + kc + k8);
        }
        __syncthreads();
        short8v a = *(const short8v*)&As[(rg * 16 + rA) * 32 + k8r * 8];
#pragma unroll
        for (int ct = 0; ct < 4; ++ct) {
            short8v b = *(const short8v*)&Ws[(ch * 64 + ct * 16 + rA) * 32 + k8r * 8];
            acc[ct] = __builtin_amdgcn_mfma_f32_16x16x32_bf16(a, b, acc[ct], 0, 0, 0);
        }
        __syncthreads();
    }

    // residual add; write T = final epi_token tile to LDS (bf16)
#pragma unroll
    for (int ct = 0; ct < 4; ++ct) {
        int col = ch * 64 + ct * 16 + rA;
#pragma unroll
        for (int r = 0; r < 4; ++r) {
            int lrow = rg * 16 + g * 4 + r;
            float v = acc[ct][r] + epi_tok[(size_t)(m0 + lrow) * 256 + col];
            Ts[lrow * 264 + col] = f2bf(v);
        }
    }
    __syncthreads();

    int bn = m0 >> 10, l0 = m0 & 1023;
    int bb = bn >> 2, nn = bn & 3;

    // stage 2: waves 0-3 -> rows (w&1)*16, cols (w>>1)*16 of the 32x32 output
    if (wv < 4) {
        int rw = wv & 1, cw = wv >> 1;
        f32x4 a2;
#pragma unroll
        for (int r = 0; r < 4; ++r) a2[r] = 0.f;
#pragma unroll
        for (int ks = 0; ks < 8; ++ks) {
            short8v af = *(const short8v*)&Ts[(rw * 16 + rA) * 264 + ks * 32 + k8r * 8];
            const float* wp = w_out + (cw * 16 + rA) * 256 + ks * 32 + k8r * 8;
            float4 w0 = *(const float4*)wp;
            float4 w1 = *(const float4*)(wp + 4);
            short8v bf;
            bf[0] = (short)f2bf(w0.x); bf[1] = (short)f2bf(w0.y);
            bf[2] = (short)f2bf(w0.z); bf[3] = (short)f2bf(w0.w);
            bf[4] = (short)f2bf(w1.x); bf[5] = (short)f2bf(w1.y);
            bf[6] = (short)f2bf(w1.z); bf[7] = (short)f2bf(w1.w);
            a2 = __builtin_amdgcn_mfma_f32_16x16x32_bf16(af, bf, a2, 0, 0, 0);
        }
        int c = cw * 16 + rA;
        int l = l0 + rw * 16 + g * 4;
        float4 st; st.x = a2[0]; st.y = a2[1]; st.z = a2[2]; st.w = a2[3];
        *(float4*)(out + ((size_t)(bb * 32 + c) * 4 + nn) * 1024 + l) = st;
    }
}

// ---------------------------------------------------------------------------
extern "C" void kernel_launch(void* const* d_in, const int* in_sizes, int n_in,
                              void* d_out, int out_size, void* d_ws, size_t ws_size,
                              hipStream_t stream) {
    const float* x_lf       = (const float*)d_in[0];
    const float* x_hf       = (const float*)d_in[1];
    const float* w_in       = (const float*)d_in[2];
    const float* w_qk       = (const float*)d_in[3];
    const float* ln_g       = (const float*)d_in[4];
    const float* ln_b       = (const float*)d_in[5];
    const float* in_proj_w  = (const float*)d_in[6];
    const float* out_proj_w = (const float*)d_in[7];
    const float* ln2_g      = (const float*)d_in[8];
    const float* ln2_b      = (const float*)d_in[9];
    const float* ff_w1      = (const float*)d_in[10];
    const float* ff_w2      = (const float*)d_in[11];
    const float* w_out      = (const float*)d_in[12];
    float* out = (float*)d_out;

    char* w = (char*)d_ws;
    float* epi_tok         = (float*)(w);                         // 8 MB fp32
    unsigned short* Qb     = (unsigned short*)(w + (8u  << 20));  // 4 MB bf16
    unsigned short* Kb     = (unsigned short*)(w + (12u << 20));
    unsigned short* Vb     = (unsigned short*)(w + (16u << 20));
    unsigned short* q_b    = (unsigned short*)(w + (20u << 20));
    unsigned short* k_b    = (unsigned short*)(w + (24u << 20));
    unsigned short* kv_b   = (unsigned short*)(w + (28u << 20));
    unsigned short* ctx_b  = (unsigned short*)(w + (32u << 20));
    unsigned short* ffin_b = (unsigned short*)(w + (36u << 20));
    unsigned short* ffh_b  = (unsigned short*)(w + (40u << 20));  // 8 MB
    unsigned short* wqkv_b = (unsigned short*)(w + (48u << 20));
    unsigned short* wop_b  = (unsigned short*)(w + (49u << 20));
    unsigned short* wff1_b = (unsigned short*)(w + (50u << 20));
    unsigned short* wff2_b = (unsigned short*)(w + (51u << 20));

    // 1. gather + input proj + dual LN  ||  weight fp32->bf16 conversion
    embed_conv_kernel<<<256, 256, 0, stream>>>(
        x_lf, x_hf, w_in, w_qk, ln_g, ln_b, epi_tok, kv_b, q_b, k_b,
        in_proj_w, out_proj_w, ff_w1, ff_w2, wqkv_b, wop_b, wff1_b, wff2_b);
    // 2. QKV projection -> bf16 (bn,h,l,d)   [768 blocks = 3/CU]
    gemm_mfma64<1, false><<<dim3(128, 2, 3), 256, 0, stream>>>(
        q_b, k_b, kv_b, wqkv_b, Qb, 256, 256);
    // 3. local-window attention (MFMA) -> ctx bf16
    attn_mfma_kernel<<<2048, 256, 0, stream>>>(Qb, Kb, Vb, ctx_b);
    // 4. out_proj + residual + LN2 -> epi_tok fp32, ffin bf16  [512 thr]
    outproj_ln_kernel<<<256, 512, 0, stream>>>(ctx_b, wop_b, epi_tok,
                                               ln2_g, ln2_b, ffin_b);
    // 5. FF1 + ReLU -> bf16 [8192,512]   [512 blocks = 2/CU]
    gemm_mfma64<0, true><<<dim3(128, 4, 1), 256, 0, stream>>>(
        ffin_b, ffin_b, ffin_b, wff1_b, ffh_b, 256, 512);
    // 6. FF2 + residual + final projection + transposed store  [512 thr]
    ff2_final_kernel<<<256, 512, 0, stream>>>(ffh_b, wff2_b, epi_tok, w_out, out);
}

// Round 12
// 82.390 us; speedup vs baseline: 1.3943x; 1.0393x over previous
//
#include <hip/hip_runtime.h>
#include <hip/hip_bf16.h>

// Problem constants: B=2,C=32,N=4,V=32,W=32,E=256,H=8,D=32,K_H=K_W=7
// L=1024, Bn=8, M=8192.  Internal row ordering: m = bn*1024 + l  (bn-major)

typedef __attribute__((ext_vector_type(8))) short short8v;   // 8 bf16 (4 VGPR)
typedef __attribute__((ext_vector_type(4))) float f32x4;

__device__ __forceinline__ unsigned short f2bf(float x) {
    union { float f; unsigned u; } c; c.f = x;
    unsigned r = c.u + 0x7FFFu + ((c.u >> 16) & 1u);
    return (unsigned short)(r >> 16);
}
__device__ __forceinline__ float bf2f(short b) {
    union { unsigned u; float f; } c;
    c.u = ((unsigned)(unsigned short)b) << 16;
    return c.f;
}

// ---------------------------------------------------------------------------
// K1: 256 uniform blocks.  Each: 32-row gather + input proj (MFMA) + dual LN,
// then a small weight-conversion tail (2 float4s/thread covers all W's).
// ---------------------------------------------------------------------------
__global__ __launch_bounds__(256) void embed_conv_kernel(
    const float* __restrict__ x_lf, const float* __restrict__ x_hf,
    const float* __restrict__ w_in, const float* __restrict__ w_qk,
    const float* __restrict__ ln_g, const float* __restrict__ ln_b,
    float* __restrict__ epi_tok, unsigned short* __restrict__ kv_b,
    unsigned short* __restrict__ q_b, unsigned short* __restrict__ k_b,
    const float* __restrict__ wqkv, const float* __restrict__ wop,
    const float* __restrict__ wff1, const float* __restrict__ wff2,
    unsigned short* __restrict__ o1, unsigned short* __restrict__ o2,
    unsigned short* __restrict__ o3, unsigned short* __restrict__ o4)
{
    __shared__ float xs[2][32][36];

    int tid = threadIdx.x;
    int m0 = blockIdx.x * 32;
    int bn = m0 >> 10, l0 = m0 & 1023;
    int bb = bn >> 2, nn = bn & 3;

    // gather: per tensor 32c x 32l = 256 float4s = 1 per thread
    {
        int c = tid >> 3, i0 = (tid & 7) * 4;
        size_t base = (size_t)bb * 131072 + (size_t)c * 4096 + nn * 1024 + l0 + i0;
        *(float4*)&xs[0][c][i0] = *(const float4*)(x_lf + base);
        *(float4*)&xs[1][c][i0] = *(const float4*)(x_hf + base);
    }
    __syncthreads();

    int lane = tid & 63, wv = tid >> 6;
    int rA = lane & 15, k8r = lane >> 4, g = k8r, k0 = k8r * 8;
    int p = wv >> 1, rg = wv & 1;          // wave: tensor p, row-group rg
    const float* W = p ? w_qk : w_in;

    short8v afrag;
#pragma unroll
    for (int j = 0; j < 8; ++j)
        afrag[j] = (short)f2bf(xs[p][k0 + j][rg * 16 + rA]);

    f32x4 acc[16];
#pragma unroll
    for (int ct = 0; ct < 16; ++ct)
#pragma unroll
        for (int r = 0; r < 4; ++r) acc[ct][r] = 0.f;

#pragma unroll
    for (int ct = 0; ct < 16; ++ct) {
        const float* wp = W + (ct * 16 + rA) * 32 + k0;
        float4 w0 = *(const float4*)wp;
        float4 w1 = *(const float4*)(wp + 4);
        short8v bfrag;
        bfrag[0] = (short)f2bf(w0.x); bfrag[1] = (short)f2bf(w0.y);
        bfrag[2] = (short)f2bf(w0.z); bfrag[3] = (short)f2bf(w0.w);
        bfrag[4] = (short)f2bf(w1.x); bfrag[5] = (short)f2bf(w1.y);
        bfrag[6] = (short)f2bf(w1.z); bfrag[7] = (short)f2bf(w1.w);
        acc[ct] = __builtin_amdgcn_mfma_f32_16x16x32_bf16(afrag, bfrag, acc[ct], 0, 0, 0);
    }

    float s[4] = {0.f, 0.f, 0.f, 0.f}, q[4] = {0.f, 0.f, 0.f, 0.f};
#pragma unroll
    for (int ct = 0; ct < 16; ++ct)
#pragma unroll
        for (int r = 0; r < 4; ++r) {
            float v = acc[ct][r];
            s[r] += v; q[r] += v * v;
        }
#pragma unroll
    for (int off = 8; off; off >>= 1)
#pragma unroll
        for (int r = 0; r < 4; ++r) {
            s[r] += __shfl_xor(s[r], off);
            q[r] += __shfl_xor(q[r], off);
        }
    float mu[4], rs[4];
#pragma unroll
    for (int r = 0; r < 4; ++r) {
        mu[r] = s[r] * (1.f / 256.f);
        rs[r] = rsqrtf(q[r] * (1.f / 256.f) - mu[r] * mu[r] + 1e-5f);
    }

#pragma unroll
    for (int ct = 0; ct < 16; ++ct) {
        int col = ct * 16 + rA;
        float gg = ln_g[col], bv = ln_b[col];
#pragma unroll
        for (int r = 0; r < 4; ++r) {
            int row = m0 + rg * 16 + g * 4 + r;
            float v = acc[ct][r];
            float lnv = (v - mu[r]) * rs[r] * gg + bv;
            size_t o = (size_t)row * 256 + col;
            if (p == 0) {
                epi_tok[o] = v;
                q_b[o] = f2bf(lnv);
            } else {
                kv_b[o] = f2bf(v);
                k_b[o] = f2bf(lnv);
            }
        }
    }

    // ---- weight conversion tail: 131072 float4s over 65536 threads ----
    {
        int gid = blockIdx.x * 256 + tid;
#pragma unroll
        for (int j = 0; j < 2; ++j) {
            int i4 = gid * 2 + j;
            const float* src; unsigned short* dst; int off;
            if (i4 < 49152)      { src = wqkv; dst = o1; off = i4 * 4; }
            else if (i4 < 65536) { src = wop;  dst = o2; off = (i4 - 49152) * 4; }
            else if (i4 < 98304) { src = wff1; dst = o3; off = (i4 - 65536) * 4; }
            else                 { src = wff2; dst = o4; off = (i4 - 98304) * 4; }
            float4 v = *(const float4*)(src + off);
            ushort4 u;
            u.x = f2bf(v.x); u.y = f2bf(v.y); u.z = f2bf(v.z); u.w = f2bf(v.w);
            *(ushort4*)(dst + off) = u;
        }
    }
}

// ---------------------------------------------------------------------------
// K2: bf16 MFMA GEMM, 64x128 tile, 4 waves (each 32x64), BK=64, pitch-72 LDS
// (conflict-spread fragment reads).  OUTMAP 0: row-major bf16.
// OUTMAP 1: QKV head layout (bn,h,l,d) bf16.
// ---------------------------------------------------------------------------
template <int OUTMAP, bool RELU>
__global__ __launch_bounds__(256) void gemm_mfma64(
    const unsigned short* __restrict__ A0, const unsigned short* __restrict__ A1,
    const unsigned short* __restrict__ A2, const unsigned short* __restrict__ Wb,
    unsigned short* __restrict__ OUT, int K, int N)
{
    int z = blockIdx.z;
    const unsigned short* A = (z == 0) ? A0 : (z == 1) ? A1 : A2;
    const unsigned short* W = Wb + (size_t)z * 65536;

    __shared__ unsigned short As[64 * 72];
    __shared__ unsigned short Ws[128 * 72];

    int tid = threadIdx.x;
    int lane = tid & 63, wid = tid >> 6;
    int wm = wid >> 1, wn = wid & 1;
    int m0 = blockIdx.x * 64, n0 = blockIdx.y * 128;

    f32x4 acc[2][4];
#pragma unroll
    for (int i = 0; i < 2; ++i)
#pragma unroll
        for (int j = 0; j < 4; ++j)
#pragma unroll
            for (int r = 0; r < 4; ++r) acc[i][j][r] = 0.f;

    int rA = lane & 15, k8r = lane >> 4, g = lane >> 4;

    for (int kc = 0; kc < K; kc += 64) {
#pragma unroll
        for (int t = 0; t < 2; ++t) {
            int idx = t * 256 + tid;          // 512 chunks = 64 rows x 8
            int row = idx >> 3, k8 = idx & 7;
            *(short8v*)&As[row * 72 + k8 * 8] =
                *(const short8v*)(A + (size_t)(m0 + row) * K + kc + k8 * 8);
        }
#pragma unroll
        for (int t = 0; t < 4; ++t) {
            int idx = t * 256 + tid;          // 1024 chunks = 128 rows x 8
            int row = idx >> 3, k8 = idx & 7;
            *(short8v*)&Ws[row * 72 + k8 * 8] =
                *(const short8v*)(W + (size_t)(n0 + row) * K + kc + k8 * 8);
        }
        __syncthreads();

        short8v a[2][2], b[2][4];
#pragma unroll
        for (int ks = 0; ks < 2; ++ks) {
#pragma unroll
            for (int mi = 0; mi < 2; ++mi)
                a[ks][mi] = *(const short8v*)&As[(wm * 32 + mi * 16 + rA) * 72 + ks * 32 + k8r * 8];
#pragma unroll
            for (int ni = 0; ni < 4; ++ni)
                b[ks][ni] = *(const short8v*)&Ws[(wn * 64 + ni * 16 + rA) * 72 + ks * 32 + k8r * 8];
        }
#pragma unroll
        for (int ks = 0; ks < 2; ++ks)
#pragma unroll
            for (int mi = 0; mi < 2; ++mi)
#pragma unroll
                for (int ni = 0; ni < 4; ++ni)
                    acc[mi][ni] = __builtin_amdgcn_mfma_f32_16x16x32_bf16(
                        a[ks][mi], b[ks][ni], acc[mi][ni], 0, 0, 0);
        __syncthreads();
    }

#pragma unroll
    for (int mi = 0; mi < 2; ++mi) {
#pragma unroll
        for (int ni = 0; ni < 4; ++ni) {
#pragma unroll
            for (int r = 0; r < 4; ++r) {
                int row = m0 + wm * 32 + mi * 16 + g * 4 + r;
                int col = n0 + wn * 64 + ni * 16 + rA;
                float v = acc[mi][ni][r];
                if (RELU) v = fmaxf(v, 0.f);
                if (OUTMAP == 0) {
                    OUT[(size_t)row * N + col] = f2bf(v);
                } else {
                    int l = row & 1023, bn = row >> 10;
                    int h = col >> 5, d = col & 31;
                    OUT[(size_t)z * 2097152 + ((bn * 8 + h) * 1024 + l) * 32 + d] = f2bf(v);
                }
            }
        }
    }
}

// ---------------------------------------------------------------------------
// K3: local-window attention, MFMA version.  (unchanged from R11, passing)
// ---------------------------------------------------------------------------
__global__ __launch_bounds__(256) void attn_mfma_kernel(
    const unsigned short* __restrict__ Qb, const unsigned short* __restrict__ Kb,
    const unsigned short* __restrict__ Vb, unsigned short* __restrict__ ctx)
{
    int bh = blockIdx.x >> 5;       // bn*8 + h
    int qv = blockIdx.x & 31;
    int tid = threadIdx.x, lane = tid & 63, wv = tid >> 6;
    int rA = lane & 15, k8r = lane >> 4, g = lane >> 4;

    __shared__ unsigned short Ks[7 * 32 * 40];   // [key n][d], pitch 40
    __shared__ unsigned short Vt[32 * 232];      // [d][key n], pitch 232
    __shared__ unsigned short Ps[32 * 232];      // [q][key n], pitch 232
    __shared__ float redm[2][2][4][4];
    __shared__ float reds[2][2][4][4];

    int mt = wv & 1, nh = wv >> 1;

    short8v qfrag = *(const short8v*)(
        Qb + ((size_t)bh * 1024 + qv * 32 + mt * 16 + rA) * 32 + k8r * 8);

#pragma unroll
    for (int it = 0; it < 4; ++it) {
        int idx = it * 256 + tid;
        if (idx < 896) {
            int dv = idx >> 7, rem = idx & 127;
            int kw = rem >> 2, c8 = (rem & 3) * 8;
            int kvc = min(max(qv - 3 + dv, 0), 31);
            size_t base = ((size_t)bh * 1024 + kvc * 32 + kw) * 32 + c8;
            int n = dv * 32 + kw;
            *(short8v*)&Ks[n * 40 + c8] = *(const short8v*)(Kb + base);
            short8v v8 = *(const short8v*)(Vb + base);
#pragma unroll
            for (int j = 0; j < 8; ++j)
                Vt[(c8 + j) * 232 + n] = (unsigned short)v8[j];
        }
    }
    __syncthreads();

    f32x4 sc[7];
#pragma unroll
    for (int ct = 0; ct < 7; ++ct)
#pragma unroll
        for (int r = 0; r < 4; ++r) sc[ct][r] = 0.f;
#pragma unroll
    for (int ct = 0; ct < 7; ++ct) {
        short8v b = *(const short8v*)&Ks[(nh * 112 + ct * 16 + rA) * 40 + k8r * 8];
        sc[ct] = __builtin_amdgcn_mfma_f32_16x16x32_bf16(qfrag, b, sc[ct], 0, 0, 0);
    }

    const float scale = 0.17677669529663687f;
    float mx[4] = {-1e30f, -1e30f, -1e30f, -1e30f};
#pragma unroll
    for (int ct = 0; ct < 7; ++ct) {
        int n = nh * 112 + ct * 16 + rA;
        int dv = n >> 5, kw = n & 31;
        int kv = qv - 3 + dv;
        bool vv = (kv >= 0) && (kv < 32);
#pragma unroll
        for (int r = 0; r < 4; ++r) {
            int qw = mt * 16 + g * 4 + r;
            int dj = kw - qw;
            bool ok = vv && (dj >= -3) && (dj <= 3);
            float s = ok ? sc[ct][r] * scale : -1e30f;
            sc[ct][r] = s;
            mx[r] = fmaxf(mx[r], s);
        }
    }
#pragma unroll
    for (int off = 8; off; off >>= 1)
#pragma unroll
        for (int r = 0; r < 4; ++r) mx[r] = fmaxf(mx[r], __shfl_xor(mx[r], off));
    if (rA == 0) {
#pragma unroll
        for (int r = 0; r < 4; ++r) redm[mt][nh][g][r] = mx[r];
    }
    __syncthreads();
#pragma unroll
    for (int r = 0; r < 4; ++r)
        mx[r] = fmaxf(redm[mt][0][g][r], redm[mt][1][g][r]);

    float sm[4] = {0.f, 0.f, 0.f, 0.f};
#pragma unroll
    for (int ct = 0; ct < 7; ++ct)
#pragma unroll
        for (int r = 0; r < 4; ++r) {
            float e = __expf(sc[ct][r] - mx[r]);
            sc[ct][r] = e;
            sm[r] += e;
        }
#pragma unroll
    for (int off = 8; off; off >>= 1)
#pragma unroll
        for (int r = 0; r < 4; ++r) sm[r] += __shfl_xor(sm[r], off);
    if (rA == 0) {
#pragma unroll
        for (int r = 0; r < 4; ++r) reds[mt][nh][g][r] = sm[r];
    }
    __syncthreads();
    float inv[4];
#pragma unroll
    for (int r = 0; r < 4; ++r)
        inv[r] = 1.f / (reds[mt][0][g][r] + reds[mt][1][g][r]);

#pragma unroll
    for (int ct = 0; ct < 7; ++ct) {
        int n = nh * 112 + ct * 16 + rA;
#pragma unroll
        for (int r = 0; r < 4; ++r) {
            int q = mt * 16 + g * 4 + r;
            Ps[q * 232 + n] = f2bf(sc[ct][r] * inv[r]);
        }
    }
    __syncthreads();

    f32x4 o;
#pragma unroll
    for (int r = 0; r < 4; ++r) o[r] = 0.f;
#pragma unroll
    for (int kb = 0; kb < 7; ++kb) {
        short8v pa = *(const short8v*)&Ps[(mt * 16 + rA) * 232 + kb * 32 + k8r * 8];
        short8v vb = *(const short8v*)&Vt[(nh * 16 + rA) * 232 + kb * 32 + k8r * 8];
        o = __builtin_amdgcn_mfma_f32_16x16x32_bf16(pa, vb, o, 0, 0, 0);
    }

    {
        int bn = bh >> 3, h = bh & 7;
        int d = nh * 16 + rA;
#pragma unroll
        for (int r = 0; r < 4; ++r) {
            int q = qv * 32 + mt * 16 + g * 4 + r;
            ctx[((size_t)bn * 1024 + q) * 256 + h * 32 + d] = f2bf(o[r]);
        }
    }
}

// ---------------------------------------------------------------------------
// K4: out_proj + residual + LN2.  32-row tile, 512 threads / 8 waves.
// (unchanged from R11, passing)
// ---------------------------------------------------------------------------
__global__ __launch_bounds__(512) void outproj_ln_kernel(
    const unsigned short* __restrict__ ctx, const unsigned short* __restrict__ Wop,
    float* __restrict__ epi_tok, const float* __restrict__ g2,
    const float* __restrict__ b2, unsigned short* __restrict__ ffin)
{
    __shared__ unsigned short As[32 * 32];
    __shared__ unsigned short Ws[256 * 32];
    __shared__ float part[2][4][4][4][2];

    int tid = threadIdx.x, lane = tid & 63, wv = tid >> 6;
    int m0 = blockIdx.x * 32;
    int rA = lane & 15, k8r = lane >> 4, g = lane >> 4;
    int rg = wv & 1, ch = wv >> 1;

    f32x4 acc[4];
#pragma unroll
    for (int ct = 0; ct < 4; ++ct)
#pragma unroll
        for (int r = 0; r < 4; ++r) acc[ct][r] = 0.f;

    for (int kc = 0; kc < 256; kc += 32) {
        if (tid < 128) {
            int row = tid >> 2, k8 = (tid & 3) * 8;
            *(short8v*)&As[row * 32 + k8] =
                *(const short8v*)(ctx + (size_t)(m0 + row) * 256 + kc + k8);
        }
#pragma unroll
        for (int c = 0; c < 2; ++c) {
            int i = c * 512 + tid;
            int row = i >> 2, k8 = (i & 3) * 8;
            *(short8v*)&Ws[row * 32 + k8] =
                *(const short8v*)(Wop + (size_t)row * 256 + kc + k8);
        }
        __syncthreads();
        short8v a = *(const short8v*)&As[(rg * 16 + rA) * 32 + k8r * 8];
#pragma unroll
        for (int ct = 0; ct < 4; ++ct) {
            short8v b = *(const short8v*)&Ws[(ch * 64 + ct * 16 + rA) * 32 + k8r * 8];
            acc[ct] = __builtin_amdgcn_mfma_f32_16x16x32_bf16(a, b, acc[ct], 0, 0, 0);
        }
        __syncthreads();
    }

    float s[4] = {0.f, 0.f, 0.f, 0.f}, q[4] = {0.f, 0.f, 0.f, 0.f};
#pragma unroll
    for (int ct = 0; ct < 4; ++ct) {
        int col = ch * 64 + ct * 16 + rA;
#pragma unroll
        for (int r = 0; r < 4; ++r) {
            int row = m0 + rg * 16 + g * 4 + r;
            float v = acc[ct][r] + epi_tok[(size_t)row * 256 + col];
            acc[ct][r] = v;
            s[r] += v; q[r] += v * v;
        }
    }
#pragma unroll
    for (int off = 8; off; off >>= 1)
#pragma unroll
        for (int r = 0; r < 4; ++r) {
            s[r] += __shfl_xor(s[r], off);
            q[r] += __shfl_xor(q[r], off);
        }
    if (rA == 0) {
#pragma unroll
        for (int r = 0; r < 4; ++r) {
            part[rg][ch][g][r][0] = s[r];
            part[rg][ch][g][r][1] = q[r];
        }
    }
    __syncthreads();
    float mu[4], rs[4];
#pragma unroll
    for (int r = 0; r < 4; ++r) {
        float S = part[rg][0][g][r][0] + part[rg][1][g][r][0]
                + part[rg][2][g][r][0] + part[rg][3][g][r][0];
        float Q = part[rg][0][g][r][1] + part[rg][1][g][r][1]
                + part[rg][2][g][r][1] + part[rg][3][g][r][1];
        mu[r] = S * (1.f / 256.f);
        rs[r] = rsqrtf(Q * (1.f / 256.f) - mu[r] * mu[r] + 1e-5f);
    }
#pragma unroll
    for (int ct = 0; ct < 4; ++ct) {
        int col = ch * 64 + ct * 16 + rA;
        float gg = g2[col], bv = b2[col];
#pragma unroll
        for (int r = 0; r < 4; ++r) {
            int row = m0 + rg * 16 + g * 4 + r;
            size_t o = (size_t)row * 256 + col;
            epi_tok[o] = acc[ct][r];
            ffin[o] = f2bf((acc[ct][r] - mu[r]) * rs[r] * gg + bv);
        }
    }
}

// ---------------------------------------------------------------------------
// K6: FF2 + residual + final E->32 projection + transposed store, fused.
// 32-row tile, 512 threads / 8 waves.  (unchanged from R11, passing)
// ---------------------------------------------------------------------------
__global__ __launch_bounds__(512) void ff2_final_kernel(
    const unsigned short* __restrict__ ffh, const unsigned short* __restrict__ W2,
    const float* __restrict__ epi_tok, const float* __restrict__ w_out,
    float* __restrict__ out)
{
    __shared__ unsigned short As[32 * 32];
    __shared__ unsigned short Ws[256 * 32];
    __shared__ unsigned short Ts[32 * 264];

    int tid = threadIdx.x, lane = tid & 63, wv = tid >> 6;
    int m0 = blockIdx.x * 32;
    int rA = lane & 15, k8r = lane >> 4, g = lane >> 4;
    int rg = wv & 1, ch = wv >> 1;

    f32x4 acc[4];
#pragma unroll
    for (int ct = 0; ct < 4; ++ct)
#pragma unroll
        for (int r = 0; r < 4; ++r) acc[ct][r] = 0.f;

    for (int kc = 0; kc < 512; kc += 32) {
        if (tid < 128) {
            int row = tid >> 2, k8 = (tid & 3) * 8;
            *(short8v*)&As[row * 32 + k8] =
                *(const short8v*)(ffh + (size_t)(m0 + row) * 512 + kc + k8);
        }
#pragma unroll
        for (int c = 0; c < 2; ++c) {
            int i = c * 512 + tid;
            int row = i >> 2, k8 = (i & 3) * 8;
            *(short8v*)&Ws[row * 32 + k8] =
                *(const short8v*)(W2 + (size_t)row * 512 + kc + k8);
        }
        __syncthreads();
        short8v a = *(const short8v*)&As[(rg * 16 + rA) * 32 + k8r * 8];
#pragma unroll
        for (int ct = 0; ct < 4; ++ct) {
            short8v b = *(const short8v*)&Ws[(ch * 64 + ct * 16 + rA) * 32 + k8r * 8];
            acc[ct] = __builtin_amdgcn_mfma_f32_16x16x32_bf16(a, b, acc[ct], 0, 0, 0);
        }
        __syncthreads();
    }

#pragma unroll
    for (int ct = 0; ct < 4; ++ct) {
        int col = ch * 64 + ct * 16 + rA;
#pragma unroll
        for (int r = 0; r < 4; ++r) {
            int lrow = rg * 16 + g * 4 + r;
            float v = acc[ct][r] + epi_tok[(size_t)(m0 + lrow) * 256 + col];
            Ts[lrow * 264 + col] = f2bf(v);
        }
    }
    __syncthreads();

    int bn = m0 >> 10, l0 = m0 & 1023;
    int bb = bn >> 2, nn = bn & 3;

    if (wv < 4) {
        int rw = wv & 1, cw = wv >> 1;
        f32x4 a2;
#pragma unroll
        for (int r = 0; r < 4; ++r) a2[r] = 0.f;
#pragma unroll
        for (int ks = 0; ks < 8; ++ks) {
            short8v af = *(const short8v*)&Ts[(rw * 16 + rA) * 264 + ks * 32 + k8r * 8];
            const float* wp = w_out + (cw * 16 + rA) * 256 + ks * 32 + k8r * 8;
            float4 w0 = *(const float4*)wp;
            float4 w1 = *(const float4*)(wp + 4);
            short8v bf;
            bf[0] = (short)f2bf(w0.x); bf[1] = (short)f2bf(w0.y);
            bf[2] = (short)f2bf(w0.z); bf[3] = (short)f2bf(w0.w);
            bf[4] = (short)f2bf(w1.x); bf[5] = (short)f2bf(w1.y);
            bf[6] = (short)f2bf(w1.z); bf[7] = (short)f2bf(w1.w);
            a2 = __builtin_amdgcn_mfma_f32_16x16x32_bf16(af, bf, a2, 0, 0, 0);
        }
        int c = cw * 16 + rA;
        int l = l0 + rw * 16 + g * 4;
        float4 st; st.x = a2[0]; st.y = a2[1]; st.z = a2[2]; st.w = a2[3];
        *(float4*)(out + ((size_t)(bb * 32 + c) * 4 + nn) * 1024 + l) = st;
    }
}

// ---------------------------------------------------------------------------
extern "C" void kernel_launch(void* const* d_in, const int* in_sizes, int n_in,
                              void* d_out, int out_size, void* d_ws, size_t ws_size,
                              hipStream_t stream) {
    const float* x_lf       = (const float*)d_in[0];
    const float* x_hf       = (const float*)d_in[1];
    const float* w_in       = (const float*)d_in[2];
    const float* w_qk       = (const float*)d_in[3];
    const float* ln_g       = (const float*)d_in[4];
    const float* ln_b       = (const float*)d_in[5];
    const float* in_proj_w  = (const float*)d_in[6];
    const float* out_proj_w = (const float*)d_in[7];
    const float* ln2_g      = (const float*)d_in[8];
    const float* ln2_b      = (const float*)d_in[9];
    const float* ff_w1      = (const float*)d_in[10];
    const float* ff_w2      = (const float*)d_in[11];
    const float* w_out      = (const float*)d_in[12];
    float* out = (float*)d_out;

    char* w = (char*)d_ws;
    float* epi_tok         = (float*)(w);                         // 8 MB fp32
    unsigned short* Qb     = (unsigned short*)(w + (8u  << 20));  // 4 MB bf16
    unsigned short* Kb     = (unsigned short*)(w + (12u << 20));
    unsigned short* Vb     = (unsigned short*)(w + (16u << 20));
    unsigned short* q_b    = (unsigned short*)(w + (20u << 20));
    unsigned short* k_b    = (unsigned short*)(w + (24u << 20));
    unsigned short* kv_b   = (unsigned short*)(w + (28u << 20));
    unsigned short* ctx_b  = (unsigned short*)(w + (32u << 20));
    unsigned short* ffin_b = (unsigned short*)(w + (36u << 20));
    unsigned short* ffh_b  = (unsigned short*)(w + (40u << 20));  // 8 MB
    unsigned short* wqkv_b = (unsigned short*)(w + (48u << 20));
    unsigned short* wop_b  = (unsigned short*)(w + (49u << 20));
    unsigned short* wff1_b = (unsigned short*)(w + (50u << 20));
    unsigned short* wff2_b = (unsigned short*)(w + (51u << 20));

    // 1. gather + input proj + dual LN + weight conversion  [256 blocks]
    embed_conv_kernel<<<256, 256, 0, stream>>>(
        x_lf, x_hf, w_in, w_qk, ln_g, ln_b, epi_tok, kv_b, q_b, k_b,
        in_proj_w, out_proj_w, ff_w1, ff_w2, wqkv_b, wop_b, wff1_b, wff2_b);
    // 2. QKV projection -> bf16 (bn,h,l,d)   [768 blocks = 3/CU, BK=64]
    gemm_mfma64<1, false><<<dim3(128, 2, 3), 256, 0, stream>>>(
        q_b, k_b, kv_b, wqkv_b, Qb, 256, 256);
    // 3. local-window attention (MFMA) -> ctx bf16
    attn_mfma_kernel<<<2048, 256, 0, stream>>>(Qb, Kb, Vb, ctx_b);
    // 4. out_proj + residual + LN2 -> epi_tok fp32, ffin bf16  [512 thr]
    outproj_ln_kernel<<<256, 512, 0, stream>>>(ctx_b, wop_b, epi_tok,
                                               ln2_g, ln2_b, ffin_b);
    // 5. FF1 + ReLU -> bf16 [8192,512]   [512 blocks = 2/CU, BK=64]
    gemm_mfma64<0, true><<<dim3(128, 4, 1), 256, 0, stream>>>(
        ffin_b, ffin_b, ffin_b, wff1_b, ffh_b, 256, 512);
    // 6. FF2 + residual + final projection + transposed store  [512 thr]
    ff2_final_kernel<<<256, 512, 0, stream>>>(ffh_b, wff2_b, epi_tok, w_out, out);
}

// Round 13
// 78.320 us; speedup vs baseline: 1.4667x; 1.0520x over previous
//
#include <hip/hip_runtime.h>
#include <hip/hip_bf16.h>

// Problem constants: B=2,C=32,N=4,V=32,W=32,E=256,H=8,D=32,K_H=K_W=7
// L=1024, Bn=8, M=8192.  Internal row ordering: m = bn*1024 + l  (bn-major)

typedef __attribute__((ext_vector_type(8))) short short8v;   // 8 bf16 (4 VGPR)
typedef __attribute__((ext_vector_type(4))) float f32x4;

__device__ __forceinline__ unsigned short f2bf(float x) {
    union { float f; unsigned u; } c; c.f = x;
    unsigned r = c.u + 0x7FFFu + ((c.u >> 16) & 1u);
    return (unsigned short)(r >> 16);
}
__device__ __forceinline__ float bf2f(short b) {
    union { unsigned u; float f; } c;
    c.u = ((unsigned)(unsigned short)b) << 16;
    return c.f;
}

// ---------------------------------------------------------------------------
// K1: 256 uniform blocks.  Each: 32-row gather + input proj (MFMA) + dual LN,
// then a small weight-conversion tail (2 float4s/thread covers all W's).
// ---------------------------------------------------------------------------
__global__ __launch_bounds__(256) void embed_conv_kernel(
    const float* __restrict__ x_lf, const float* __restrict__ x_hf,
    const float* __restrict__ w_in, const float* __restrict__ w_qk,
    const float* __restrict__ ln_g, const float* __restrict__ ln_b,
    float* __restrict__ epi_tok, unsigned short* __restrict__ kv_b,
    unsigned short* __restrict__ q_b, unsigned short* __restrict__ k_b,
    const float* __restrict__ wqkv, const float* __restrict__ wop,
    const float* __restrict__ wff1, const float* __restrict__ wff2,
    unsigned short* __restrict__ o1, unsigned short* __restrict__ o2,
    unsigned short* __restrict__ o3, unsigned short* __restrict__ o4)
{
    __shared__ float xs[2][32][36];

    int tid = threadIdx.x;
    int m0 = blockIdx.x * 32;
    int bn = m0 >> 10, l0 = m0 & 1023;
    int bb = bn >> 2, nn = bn & 3;

    {
        int c = tid >> 3, i0 = (tid & 7) * 4;
        size_t base = (size_t)bb * 131072 + (size_t)c * 4096 + nn * 1024 + l0 + i0;
        *(float4*)&xs[0][c][i0] = *(const float4*)(x_lf + base);
        *(float4*)&xs[1][c][i0] = *(const float4*)(x_hf + base);
    }
    __syncthreads();

    int lane = tid & 63, wv = tid >> 6;
    int rA = lane & 15, k8r = lane >> 4, g = k8r, k0 = k8r * 8;
    int p = wv >> 1, rg = wv & 1;
    const float* W = p ? w_qk : w_in;

    short8v afrag;
#pragma unroll
    for (int j = 0; j < 8; ++j)
        afrag[j] = (short)f2bf(xs[p][k0 + j][rg * 16 + rA]);

    f32x4 acc[16];
#pragma unroll
    for (int ct = 0; ct < 16; ++ct)
#pragma unroll
        for (int r = 0; r < 4; ++r) acc[ct][r] = 0.f;

#pragma unroll
    for (int ct = 0; ct < 16; ++ct) {
        const float* wp = W + (ct * 16 + rA) * 32 + k0;
        float4 w0 = *(const float4*)wp;
        float4 w1 = *(const float4*)(wp + 4);
        short8v bfrag;
        bfrag[0] = (short)f2bf(w0.x); bfrag[1] = (short)f2bf(w0.y);
        bfrag[2] = (short)f2bf(w0.z); bfrag[3] = (short)f2bf(w0.w);
        bfrag[4] = (short)f2bf(w1.x); bfrag[5] = (short)f2bf(w1.y);
        bfrag[6] = (short)f2bf(w1.z); bfrag[7] = (short)f2bf(w1.w);
        acc[ct] = __builtin_amdgcn_mfma_f32_16x16x32_bf16(afrag, bfrag, acc[ct], 0, 0, 0);
    }

    float s[4] = {0.f, 0.f, 0.f, 0.f}, q[4] = {0.f, 0.f, 0.f, 0.f};
#pragma unroll
    for (int ct = 0; ct < 16; ++ct)
#pragma unroll
        for (int r = 0; r < 4; ++r) {
            float v = acc[ct][r];
            s[r] += v; q[r] += v * v;
        }
#pragma unroll
    for (int off = 8; off; off >>= 1)
#pragma unroll
        for (int r = 0; r < 4; ++r) {
            s[r] += __shfl_xor(s[r], off);
            q[r] += __shfl_xor(q[r], off);
        }
    float mu[4], rs[4];
#pragma unroll
    for (int r = 0; r < 4; ++r) {
        mu[r] = s[r] * (1.f / 256.f);
        rs[r] = rsqrtf(q[r] * (1.f / 256.f) - mu[r] * mu[r] + 1e-5f);
    }

#pragma unroll
    for (int ct = 0; ct < 16; ++ct) {
        int col = ct * 16 + rA;
        float gg = ln_g[col], bv = ln_b[col];
#pragma unroll
        for (int r = 0; r < 4; ++r) {
            int row = m0 + rg * 16 + g * 4 + r;
            float v = acc[ct][r];
            float lnv = (v - mu[r]) * rs[r] * gg + bv;
            size_t o = (size_t)row * 256 + col;
            if (p == 0) {
                epi_tok[o] = v;
                q_b[o] = f2bf(lnv);
            } else {
                kv_b[o] = f2bf(v);
                k_b[o] = f2bf(lnv);
            }
        }
    }

    // ---- weight conversion tail ----
    {
        int gid = blockIdx.x * 256 + tid;
#pragma unroll
        for (int j = 0; j < 2; ++j) {
            int i4 = gid * 2 + j;
            const float* src; unsigned short* dst; int off;
            if (i4 < 49152)      { src = wqkv; dst = o1; off = i4 * 4; }
            else if (i4 < 65536) { src = wop;  dst = o2; off = (i4 - 49152) * 4; }
            else if (i4 < 98304) { src = wff1; dst = o3; off = (i4 - 65536) * 4; }
            else                 { src = wff2; dst = o4; off = (i4 - 98304) * 4; }
            float4 v = *(const float4*)(src + off);
            ushort4 u;
            u.x = f2bf(v.x); u.y = f2bf(v.y); u.z = f2bf(v.z); u.w = f2bf(v.w);
            *(ushort4*)(dst + off) = u;
        }
    }
}

// ---------------------------------------------------------------------------
// K2: bf16 MFMA GEMM, 64x128 tile, 4 waves, BK=64, pitch-72 LDS.
// ---------------------------------------------------------------------------
template <int OUTMAP, bool RELU>
__global__ __launch_bounds__(256) void gemm_mfma64(
    const unsigned short* __restrict__ A0, const unsigned short* __restrict__ A1,
    const unsigned short* __restrict__ A2, const unsigned short* __restrict__ Wb,
    unsigned short* __restrict__ OUT, int K, int N)
{
    int z = blockIdx.z;
    const unsigned short* A = (z == 0) ? A0 : (z == 1) ? A1 : A2;
    const unsigned short* W = Wb + (size_t)z * 65536;

    __shared__ unsigned short As[64 * 72];
    __shared__ unsigned short Ws[128 * 72];

    int tid = threadIdx.x;
    int lane = tid & 63, wid = tid >> 6;
    int wm = wid >> 1, wn = wid & 1;
    int m0 = blockIdx.x * 64, n0 = blockIdx.y * 128;

    f32x4 acc[2][4];
#pragma unroll
    for (int i = 0; i < 2; ++i)
#pragma unroll
        for (int j = 0; j < 4; ++j)
#pragma unroll
            for (int r = 0; r < 4; ++r) acc[i][j][r] = 0.f;

    int rA = lane & 15, k8r = lane >> 4, g = lane >> 4;

    for (int kc = 0; kc < K; kc += 64) {
#pragma unroll
        for (int t = 0; t < 2; ++t) {
            int idx = t * 256 + tid;
            int row = idx >> 3, k8 = idx & 7;
            *(short8v*)&As[row * 72 + k8 * 8] =
                *(const short8v*)(A + (size_t)(m0 + row) * K + kc + k8 * 8);
        }
#pragma unroll
        for (int t = 0; t < 4; ++t) {
            int idx = t * 256 + tid;
            int row = idx >> 3, k8 = idx & 7;
            *(short8v*)&Ws[row * 72 + k8 * 8] =
                *(const short8v*)(W + (size_t)(n0 + row) * K + kc + k8 * 8);
        }
        __syncthreads();

        short8v a[2][2], b[2][4];
#pragma unroll
        for (int ks = 0; ks < 2; ++ks) {
#pragma unroll
            for (int mi = 0; mi < 2; ++mi)
                a[ks][mi] = *(const short8v*)&As[(wm * 32 + mi * 16 + rA) * 72 + ks * 32 + k8r * 8];
#pragma unroll
            for (int ni = 0; ni < 4; ++ni)
                b[ks][ni] = *(const short8v*)&Ws[(wn * 64 + ni * 16 + rA) * 72 + ks * 32 + k8r * 8];
        }
#pragma unroll
        for (int ks = 0; ks < 2; ++ks)
#pragma unroll
            for (int mi = 0; mi < 2; ++mi)
#pragma unroll
                for (int ni = 0; ni < 4; ++ni)
                    acc[mi][ni] = __builtin_amdgcn_mfma_f32_16x16x32_bf16(
                        a[ks][mi], b[ks][ni], acc[mi][ni], 0, 0, 0);
        __syncthreads();
    }

#pragma unroll
    for (int mi = 0; mi < 2; ++mi) {
#pragma unroll
        for (int ni = 0; ni < 4; ++ni) {
#pragma unroll
            for (int r = 0; r < 4; ++r) {
                int row = m0 + wm * 32 + mi * 16 + g * 4 + r;
                int col = n0 + wn * 64 + ni * 16 + rA;
                float v = acc[mi][ni][r];
                if (RELU) v = fmaxf(v, 0.f);
                if (OUTMAP == 0) {
                    OUT[(size_t)row * N + col] = f2bf(v);
                } else {
                    int l = row & 1023, bn = row >> 10;
                    int h = col >> 5, d = col & 31;
                    OUT[(size_t)z * 2097152 + ((bn * 8 + h) * 1024 + l) * 32 + d] = f2bf(v);
                }
            }
        }
    }
}

// ---------------------------------------------------------------------------
// K3: local-window attention, MFMA version.  (unchanged, passing)
// ---------------------------------------------------------------------------
__global__ __launch_bounds__(256) void attn_mfma_kernel(
    const unsigned short* __restrict__ Qb, const unsigned short* __restrict__ Kb,
    const unsigned short* __restrict__ Vb, unsigned short* __restrict__ ctx)
{
    int bh = blockIdx.x >> 5;
    int qv = blockIdx.x & 31;
    int tid = threadIdx.x, lane = tid & 63, wv = tid >> 6;
    int rA = lane & 15, k8r = lane >> 4, g = lane >> 4;

    __shared__ unsigned short Ks[7 * 32 * 40];
    __shared__ unsigned short Vt[32 * 232];
    __shared__ unsigned short Ps[32 * 232];
    __shared__ float redm[2][2][4][4];
    __shared__ float reds[2][2][4][4];

    int mt = wv & 1, nh = wv >> 1;

    short8v qfrag = *(const short8v*)(
        Qb + ((size_t)bh * 1024 + qv * 32 + mt * 16 + rA) * 32 + k8r * 8);

#pragma unroll
    for (int it = 0; it < 4; ++it) {
        int idx = it * 256 + tid;
        if (idx < 896) {
            int dv = idx >> 7, rem = idx & 127;
            int kw = rem >> 2, c8 = (rem & 3) * 8;
            int kvc = min(max(qv - 3 + dv, 0), 31);
            size_t base = ((size_t)bh * 1024 + kvc * 32 + kw) * 32 + c8;
            int n = dv * 32 + kw;
            *(short8v*)&Ks[n * 40 + c8] = *(const short8v*)(Kb + base);
            short8v v8 = *(const short8v*)(Vb + base);
#pragma unroll
            for (int j = 0; j < 8; ++j)
                Vt[(c8 + j) * 232 + n] = (unsigned short)v8[j];
        }
    }
    __syncthreads();

    f32x4 sc[7];
#pragma unroll
    for (int ct = 0; ct < 7; ++ct)
#pragma unroll
        for (int r = 0; r < 4; ++r) sc[ct][r] = 0.f;
#pragma unroll
    for (int ct = 0; ct < 7; ++ct) {
        short8v b = *(const short8v*)&Ks[(nh * 112 + ct * 16 + rA) * 40 + k8r * 8];
        sc[ct] = __builtin_amdgcn_mfma_f32_16x16x32_bf16(qfrag, b, sc[ct], 0, 0, 0);
    }

    const float scale = 0.17677669529663687f;
    float mx[4] = {-1e30f, -1e30f, -1e30f, -1e30f};
#pragma unroll
    for (int ct = 0; ct < 7; ++ct) {
        int n = nh * 112 + ct * 16 + rA;
        int dv = n >> 5, kw = n & 31;
        int kv = qv - 3 + dv;
        bool vv = (kv >= 0) && (kv < 32);
#pragma unroll
        for (int r = 0; r < 4; ++r) {
            int qw = mt * 16 + g * 4 + r;
            int dj = kw - qw;
            bool ok = vv && (dj >= -3) && (dj <= 3);
            float s = ok ? sc[ct][r] * scale : -1e30f;
            sc[ct][r] = s;
            mx[r] = fmaxf(mx[r], s);
        }
    }
#pragma unroll
    for (int off = 8; off; off >>= 1)
#pragma unroll
        for (int r = 0; r < 4; ++r) mx[r] = fmaxf(mx[r], __shfl_xor(mx[r], off));
    if (rA == 0) {
#pragma unroll
        for (int r = 0; r < 4; ++r) redm[mt][nh][g][r] = mx[r];
    }
    __syncthreads();
#pragma unroll
    for (int r = 0; r < 4; ++r)
        mx[r] = fmaxf(redm[mt][0][g][r], redm[mt][1][g][r]);

    float sm[4] = {0.f, 0.f, 0.f, 0.f};
#pragma unroll
    for (int ct = 0; ct < 7; ++ct)
#pragma unroll
        for (int r = 0; r < 4; ++r) {
            float e = __expf(sc[ct][r] - mx[r]);
            sc[ct][r] = e;
            sm[r] += e;
        }
#pragma unroll
    for (int off = 8; off; off >>= 1)
#pragma unroll
        for (int r = 0; r < 4; ++r) sm[r] += __shfl_xor(sm[r], off);
    if (rA == 0) {
#pragma unroll
        for (int r = 0; r < 4; ++r) reds[mt][nh][g][r] = sm[r];
    }
    __syncthreads();
    float inv[4];
#pragma unroll
    for (int r = 0; r < 4; ++r)
        inv[r] = 1.f / (reds[mt][0][g][r] + reds[mt][1][g][r]);

#pragma unroll
    for (int ct = 0; ct < 7; ++ct) {
        int n = nh * 112 + ct * 16 + rA;
#pragma unroll
        for (int r = 0; r < 4; ++r) {
            int q = mt * 16 + g * 4 + r;
            Ps[q * 232 + n] = f2bf(sc[ct][r] * inv[r]);
        }
    }
    __syncthreads();

    f32x4 o;
#pragma unroll
    for (int r = 0; r < 4; ++r) o[r] = 0.f;
#pragma unroll
    for (int kb = 0; kb < 7; ++kb) {
        short8v pa = *(const short8v*)&Ps[(mt * 16 + rA) * 232 + kb * 32 + k8r * 8];
        short8v vb = *(const short8v*)&Vt[(nh * 16 + rA) * 232 + kb * 32 + k8r * 8];
        o = __builtin_amdgcn_mfma_f32_16x16x32_bf16(pa, vb, o, 0, 0, 0);
    }

    {
        int bn = bh >> 3, h = bh & 7;
        int d = nh * 16 + rA;
#pragma unroll
        for (int r = 0; r < 4; ++r) {
            int q = qv * 32 + mt * 16 + g * 4 + r;
            ctx[((size_t)bn * 1024 + q) * 256 + h * 32 + d] = f2bf(o[r]);
        }
    }
}

// ---------------------------------------------------------------------------
// K4: out_proj + residual + LN2.  32-row tile, 512 threads / 8 waves,
// BK=64, pitch-72 LDS (conflict-free fragment reads, 4 barrier rounds).
// ---------------------------------------------------------------------------
__global__ __launch_bounds__(512) void outproj_ln_kernel(
    const unsigned short* __restrict__ ctx, const unsigned short* __restrict__ Wop,
    float* __restrict__ epi_tok, const float* __restrict__ g2,
    const float* __restrict__ b2, unsigned short* __restrict__ ffin)
{
    __shared__ unsigned short As[32 * 72];
    __shared__ unsigned short Ws[256 * 72];
    __shared__ float part[2][4][4][4][2];

    int tid = threadIdx.x, lane = tid & 63, wv = tid >> 6;
    int m0 = blockIdx.x * 32;
    int rA = lane & 15, k8r = lane >> 4, g = lane >> 4;
    int rg = wv & 1, ch = wv >> 1;

    f32x4 acc[4];
#pragma unroll
    for (int ct = 0; ct < 4; ++ct)
#pragma unroll
        for (int r = 0; r < 4; ++r) acc[ct][r] = 0.f;

    for (int kc = 0; kc < 256; kc += 64) {
        if (tid < 256) {
            int row = tid >> 3, k8 = tid & 7;
            *(short8v*)&As[row * 72 + k8 * 8] =
                *(const short8v*)(ctx + (size_t)(m0 + row) * 256 + kc + k8 * 8);
        }
#pragma unroll
        for (int t = 0; t < 4; ++t) {
            int idx = t * 512 + tid;
            int row = idx >> 3, k8 = idx & 7;
            *(short8v*)&Ws[row * 72 + k8 * 8] =
                *(const short8v*)(Wop + (size_t)row * 256 + kc + k8 * 8);
        }
        __syncthreads();
        short8v a[2];
#pragma unroll
        for (int ks = 0; ks < 2; ++ks)
            a[ks] = *(const short8v*)&As[(rg * 16 + rA) * 72 + ks * 32 + k8r * 8];
#pragma unroll
        for (int ks = 0; ks < 2; ++ks)
#pragma unroll
            for (int ct = 0; ct < 4; ++ct) {
                short8v b = *(const short8v*)&Ws[(ch * 64 + ct * 16 + rA) * 72 + ks * 32 + k8r * 8];
                acc[ct] = __builtin_amdgcn_mfma_f32_16x16x32_bf16(a[ks], b, acc[ct], 0, 0, 0);
            }
        __syncthreads();
    }

    float s[4] = {0.f, 0.f, 0.f, 0.f}, q[4] = {0.f, 0.f, 0.f, 0.f};
#pragma unroll
    for (int ct = 0; ct < 4; ++ct) {
        int col = ch * 64 + ct * 16 + rA;
#pragma unroll
        for (int r = 0; r < 4; ++r) {
            int row = m0 + rg * 16 + g * 4 + r;
            float v = acc[ct][r] + epi_tok[(size_t)row * 256 + col];
            acc[ct][r] = v;
            s[r] += v; q[r] += v * v;
        }
    }
#pragma unroll
    for (int off = 8; off; off >>= 1)
#pragma unroll
        for (int r = 0; r < 4; ++r) {
            s[r] += __shfl_xor(s[r], off);
            q[r] += __shfl_xor(q[r], off);
        }
    if (rA == 0) {
#pragma unroll
        for (int r = 0; r < 4; ++r) {
            part[rg][ch][g][r][0] = s[r];
            part[rg][ch][g][r][1] = q[r];
        }
    }
    __syncthreads();
    float mu[4], rs[4];
#pragma unroll
    for (int r = 0; r < 4; ++r) {
        float S = part[rg][0][g][r][0] + part[rg][1][g][r][0]
                + part[rg][2][g][r][0] + part[rg][3][g][r][0];
        float Q = part[rg][0][g][r][1] + part[rg][1][g][r][1]
                + part[rg][2][g][r][1] + part[rg][3][g][r][1];
        mu[r] = S * (1.f / 256.f);
        rs[r] = rsqrtf(Q * (1.f / 256.f) - mu[r] * mu[r] + 1e-5f);
    }
#pragma unroll
    for (int ct = 0; ct < 4; ++ct) {
        int col = ch * 64 + ct * 16 + rA;
        float gg = g2[col], bv = b2[col];
#pragma unroll
        for (int r = 0; r < 4; ++r) {
            int row = m0 + rg * 16 + g * 4 + r;
            size_t o = (size_t)row * 256 + col;
            epi_tok[o] = acc[ct][r];
            ffin[o] = f2bf((acc[ct][r] - mu[r]) * rs[r] * gg + bv);
        }
    }
}

// ---------------------------------------------------------------------------
// K6: FF2 + residual + final E->32 projection + transposed store, fused.
// 32-row tile, 512 threads / 8 waves, BK=64, pitch-72 (8 barrier rounds).
// ---------------------------------------------------------------------------
__global__ __launch_bounds__(512) void ff2_final_kernel(
    const unsigned short* __restrict__ ffh, const unsigned short* __restrict__ W2,
    const float* __restrict__ epi_tok, const float* __restrict__ w_out,
    float* __restrict__ out)
{
    __shared__ unsigned short As[32 * 72];
    __shared__ unsigned short Ws[256 * 72];
    __shared__ unsigned short Ts[32 * 264];

    int tid = threadIdx.x, lane = tid & 63, wv = tid >> 6;
    int m0 = blockIdx.x * 32;
    int rA = lane & 15, k8r = lane >> 4, g = lane >> 4;
    int rg = wv & 1, ch = wv >> 1;

    f32x4 acc[4];
#pragma unroll
    for (int ct = 0; ct < 4; ++ct)
#pragma unroll
        for (int r = 0; r < 4; ++r) acc[ct][r] = 0.f;

    for (int kc = 0; kc < 512; kc += 64) {
        if (tid < 256) {
            int row = tid >> 3, k8 = tid & 7;
            *(short8v*)&As[row * 72 + k8 * 8] =
                *(const short8v*)(ffh + (size_t)(m0 + row) * 512 + kc + k8 * 8);
        }
#pragma unroll
        for (int t = 0; t < 4; ++t) {
            int idx = t * 512 + tid;
            int row = idx >> 3, k8 = idx & 7;
            *(short8v*)&Ws[row * 72 + k8 * 8] =
                *(const short8v*)(W2 + (size_t)row * 512 + kc + k8 * 8);
        }
        __syncthreads();
        short8v a[2];
#pragma unroll
        for (int ks = 0; ks < 2; ++ks)
            a[ks] = *(const short8v*)&As[(rg * 16 + rA) * 72 + ks * 32 + k8r * 8];
#pragma unroll
        for (int ks = 0; ks < 2; ++ks)
#pragma unroll
            for (int ct = 0; ct < 4; ++ct) {
                short8v b = *(const short8v*)&Ws[(ch * 64 + ct * 16 + rA) * 72 + ks * 32 + k8r * 8];
                acc[ct] = __builtin_amdgcn_mfma_f32_16x16x32_bf16(a[ks], b, acc[ct], 0, 0, 0);
            }
        __syncthreads();
    }

#pragma unroll
    for (int ct = 0; ct < 4; ++ct) {
        int col = ch * 64 + ct * 16 + rA;
#pragma unroll
        for (int r = 0; r < 4; ++r) {
            int lrow = rg * 16 + g * 4 + r;
            float v = acc[ct][r] + epi_tok[(size_t)(m0 + lrow) * 256 + col];
            Ts[lrow * 264 + col] = f2bf(v);
        }
    }
    __syncthreads();

    int bn = m0 >> 10, l0 = m0 & 1023;
    int bb = bn >> 2, nn = bn & 3;

    if (wv < 4) {
        int rw = wv & 1, cw = wv >> 1;
        f32x4 a2;
#pragma unroll
        for (int r = 0; r < 4; ++r) a2[r] = 0.f;
#pragma unroll
        for (int ks = 0; ks < 8; ++ks) {
            short8v af = *(const short8v*)&Ts[(rw * 16 + rA) * 264 + ks * 32 + k8r * 8];
            const float* wp = w_out + (cw * 16 + rA) * 256 + ks * 32 + k8r * 8;
            float4 w0 = *(const float4*)wp;
            float4 w1 = *(const float4*)(wp + 4);
            short8v bf;
            bf[0] = (short)f2bf(w0.x); bf[1] = (short)f2bf(w0.y);
            bf[2] = (short)f2bf(w0.z); bf[3] = (short)f2bf(w0.w);
            bf[4] = (short)f2bf(w1.x); bf[5] = (short)f2bf(w1.y);
            bf[6] = (short)f2bf(w1.z); bf[7] = (short)f2bf(w1.w);
            a2 = __builtin_amdgcn_mfma_f32_16x16x32_bf16(af, bf, a2, 0, 0, 0);
        }
        int c = cw * 16 + rA;
        int l = l0 + rw * 16 + g * 4;
        float4 st; st.x = a2[0]; st.y = a2[1]; st.z = a2[2]; st.w = a2[3];
        *(float4*)(out + ((size_t)(bb * 32 + c) * 4 + nn) * 1024 + l) = st;
    }
}

// ---------------------------------------------------------------------------
extern "C" void kernel_launch(void* const* d_in, const int* in_sizes, int n_in,
                              void* d_out, int out_size, void* d_ws, size_t ws_size,
                              hipStream_t stream) {
    const float* x_lf       = (const float*)d_in[0];
    const float* x_hf       = (const float*)d_in[1];
    const float* w_in       = (const float*)d_in[2];
    const float* w_qk       = (const float*)d_in[3];
    const float* ln_g       = (const float*)d_in[4];
    const float* ln_b       = (const float*)d_in[5];
    const float* in_proj_w  = (const float*)d_in[6];
    const float* out_proj_w = (const float*)d_in[7];
    const float* ln2_g      = (const float*)d_in[8];
    const float* ln2_b      = (const float*)d_in[9];
    const float* ff_w1      = (const float*)d_in[10];
    const float* ff_w2      = (const float*)d_in[11];
    const float* w_out      = (const float*)d_in[12];
    float* out = (float*)d_out;

    char* w = (char*)d_ws;
    float* epi_tok         = (float*)(w);                         // 8 MB fp32
    unsigned short* Qb     = (unsigned short*)(w + (8u  << 20));  // 4 MB bf16
    unsigned short* Kb     = (unsigned short*)(w + (12u << 20));
    unsigned short* Vb     = (unsigned short*)(w + (16u << 20));
    unsigned short* q_b    = (unsigned short*)(w + (20u << 20));
    unsigned short* k_b    = (unsigned short*)(w + (24u << 20));
    unsigned short* kv_b   = (unsigned short*)(w + (28u << 20));
    unsigned short* ctx_b  = (unsigned short*)(w + (32u << 20));
    unsigned short* ffin_b = (unsigned short*)(w + (36u << 20));
    unsigned short* ffh_b  = (unsigned short*)(w + (40u << 20));  // 8 MB
    unsigned short* wqkv_b = (unsigned short*)(w + (48u << 20));
    unsigned short* wop_b  = (unsigned short*)(w + (49u << 20));
    unsigned short* wff1_b = (unsigned short*)(w + (50u << 20));
    unsigned short* wff2_b = (unsigned short*)(w + (51u << 20));

    // 1. gather + input proj + dual LN + weight conversion  [256 blocks]
    embed_conv_kernel<<<256, 256, 0, stream>>>(
        x_lf, x_hf, w_in, w_qk, ln_g, ln_b, epi_tok, kv_b, q_b, k_b,
        in_proj_w, out_proj_w, ff_w1, ff_w2, wqkv_b, wop_b, wff1_b, wff2_b);
    // 2. QKV projection -> bf16 (bn,h,l,d)   [768 blocks, BK=64]
    gemm_mfma64<1, false><<<dim3(128, 2, 3), 256, 0, stream>>>(
        q_b, k_b, kv_b, wqkv_b, Qb, 256, 256);
    // 3. local-window attention (MFMA) -> ctx bf16
    attn_mfma_kernel<<<2048, 256, 0, stream>>>(Qb, Kb, Vb, ctx_b);
    // 4. out_proj + residual + LN2  [512 thr, BK=64]
    outproj_ln_kernel<<<256, 512, 0, stream>>>(ctx_b, wop_b, epi_tok,
                                               ln2_g, ln2_b, ffin_b);
    // 5. FF1 + ReLU -> bf16 [8192,512]   [512 blocks, BK=64]
    gemm_mfma64<0, true><<<dim3(128, 4, 1), 256, 0, stream>>>(
        ffin_b, ffin_b, ffin_b, wff1_b, ffh_b, 256, 512);
    // 6. FF2 + residual + final projection + transposed store  [512 thr, BK=64]
    ff2_final_kernel<<<256, 512, 0, stream>>>(ffh_b, wff2_b, epi_tok, w_out, out);
}

// Round 14
// 77.087 us; speedup vs baseline: 1.4902x; 1.0160x over previous
//
#include <hip/hip_runtime.h>
#include <hip/hip_bf16.h>

// Problem constants: B=2,C=32,N=4,V=32,W=32,E=256,H=8,D=32,K_H=K_W=7
// L=1024, Bn=8, M=8192.  Internal row ordering: m = bn*1024 + l  (bn-major)

typedef __attribute__((ext_vector_type(8))) short short8v;   // 8 bf16 (4 VGPR)
typedef __attribute__((ext_vector_type(4))) float f32x4;

__device__ __forceinline__ unsigned short f2bf(float x) {
    union { float f; unsigned u; } c; c.f = x;
    unsigned r = c.u + 0x7FFFu + ((c.u >> 16) & 1u);
    return (unsigned short)(r >> 16);
}
__device__ __forceinline__ float bf2f(short b) {
    union { unsigned u; float f; } c;
    c.u = ((unsigned)(unsigned short)b) << 16;
    return c.f;
}

// ---------------------------------------------------------------------------
// K1: 256 uniform blocks.  Each: 32-row gather + input proj (MFMA) + dual LN,
// then a small weight-conversion tail (2 float4s/thread covers all W's).
// ---------------------------------------------------------------------------
__global__ __launch_bounds__(256) void embed_conv_kernel(
    const float* __restrict__ x_lf, const float* __restrict__ x_hf,
    const float* __restrict__ w_in, const float* __restrict__ w_qk,
    const float* __restrict__ ln_g, const float* __restrict__ ln_b,
    float* __restrict__ epi_tok, unsigned short* __restrict__ kv_b,
    unsigned short* __restrict__ q_b, unsigned short* __restrict__ k_b,
    const float* __restrict__ wqkv, const float* __restrict__ wop,
    const float* __restrict__ wff1, const float* __restrict__ wff2,
    unsigned short* __restrict__ o1, unsigned short* __restrict__ o2,
    unsigned short* __restrict__ o3, unsigned short* __restrict__ o4)
{
    __shared__ float xs[2][32][36];

    int tid = threadIdx.x;
    int m0 = blockIdx.x * 32;
    int bn = m0 >> 10, l0 = m0 & 1023;
    int bb = bn >> 2, nn = bn & 3;

    {
        int c = tid >> 3, i0 = (tid & 7) * 4;
        size_t base = (size_t)bb * 131072 + (size_t)c * 4096 + nn * 1024 + l0 + i0;
        *(float4*)&xs[0][c][i0] = *(const float4*)(x_lf + base);
        *(float4*)&xs[1][c][i0] = *(const float4*)(x_hf + base);
    }
    __syncthreads();

    int lane = tid & 63, wv = tid >> 6;
    int rA = lane & 15, k8r = lane >> 4, g = k8r, k0 = k8r * 8;
    int p = wv >> 1, rg = wv & 1;
    const float* W = p ? w_qk : w_in;

    short8v afrag;
#pragma unroll
    for (int j = 0; j < 8; ++j)
        afrag[j] = (short)f2bf(xs[p][k0 + j][rg * 16 + rA]);

    f32x4 acc[16];
#pragma unroll
    for (int ct = 0; ct < 16; ++ct)
#pragma unroll
        for (int r = 0; r < 4; ++r) acc[ct][r] = 0.f;

#pragma unroll
    for (int ct = 0; ct < 16; ++ct) {
        const float* wp = W + (ct * 16 + rA) * 32 + k0;
        float4 w0 = *(const float4*)wp;
        float4 w1 = *(const float4*)(wp + 4);
        short8v bfrag;
        bfrag[0] = (short)f2bf(w0.x); bfrag[1] = (short)f2bf(w0.y);
        bfrag[2] = (short)f2bf(w0.z); bfrag[3] = (short)f2bf(w0.w);
        bfrag[4] = (short)f2bf(w1.x); bfrag[5] = (short)f2bf(w1.y);
        bfrag[6] = (short)f2bf(w1.z); bfrag[7] = (short)f2bf(w1.w);
        acc[ct] = __builtin_amdgcn_mfma_f32_16x16x32_bf16(afrag, bfrag, acc[ct], 0, 0, 0);
    }

    float s[4] = {0.f, 0.f, 0.f, 0.f}, q[4] = {0.f, 0.f, 0.f, 0.f};
#pragma unroll
    for (int ct = 0; ct < 16; ++ct)
#pragma unroll
        for (int r = 0; r < 4; ++r) {
            float v = acc[ct][r];
            s[r] += v; q[r] += v * v;
        }
#pragma unroll
    for (int off = 8; off; off >>= 1)
#pragma unroll
        for (int r = 0; r < 4; ++r) {
            s[r] += __shfl_xor(s[r], off);
            q[r] += __shfl_xor(q[r], off);
        }
    float mu[4], rs[4];
#pragma unroll
    for (int r = 0; r < 4; ++r) {
        mu[r] = s[r] * (1.f / 256.f);
        rs[r] = rsqrtf(q[r] * (1.f / 256.f) - mu[r] * mu[r] + 1e-5f);
    }

#pragma unroll
    for (int ct = 0; ct < 16; ++ct) {
        int col = ct * 16 + rA;
        float gg = ln_g[col], bv = ln_b[col];
#pragma unroll
        for (int r = 0; r < 4; ++r) {
            int row = m0 + rg * 16 + g * 4 + r;
            float v = acc[ct][r];
            float lnv = (v - mu[r]) * rs[r] * gg + bv;
            size_t o = (size_t)row * 256 + col;
            if (p == 0) {
                epi_tok[o] = v;
                q_b[o] = f2bf(lnv);
            } else {
                kv_b[o] = f2bf(v);
                k_b[o] = f2bf(lnv);
            }
        }
    }

    // ---- weight conversion tail ----
    {
        int gid = blockIdx.x * 256 + tid;
#pragma unroll
        for (int j = 0; j < 2; ++j) {
            int i4 = gid * 2 + j;
            const float* src; unsigned short* dst; int off;
            if (i4 < 49152)      { src = wqkv; dst = o1; off = i4 * 4; }
            else if (i4 < 65536) { src = wop;  dst = o2; off = (i4 - 49152) * 4; }
            else if (i4 < 98304) { src = wff1; dst = o3; off = (i4 - 65536) * 4; }
            else                 { src = wff2; dst = o4; off = (i4 - 98304) * 4; }
            float4 v = *(const float4*)(src + off);
            ushort4 u;
            u.x = f2bf(v.x); u.y = f2bf(v.y); u.z = f2bf(v.z); u.w = f2bf(v.w);
            *(ushort4*)(dst + off) = u;
        }
    }
}

// ---------------------------------------------------------------------------
// K2: bf16 MFMA GEMM, 64x128 tile, 4 waves, BK=64, pitch-72 LDS.
// ---------------------------------------------------------------------------
template <int OUTMAP, bool RELU>
__global__ __launch_bounds__(256) void gemm_mfma64(
    const unsigned short* __restrict__ A0, const unsigned short* __restrict__ A1,
    const unsigned short* __restrict__ A2, const unsigned short* __restrict__ Wb,
    unsigned short* __restrict__ OUT, int K, int N)
{
    int z = blockIdx.z;
    const unsigned short* A = (z == 0) ? A0 : (z == 1) ? A1 : A2;
    const unsigned short* W = Wb + (size_t)z * 65536;

    __shared__ unsigned short As[64 * 72];
    __shared__ unsigned short Ws[128 * 72];

    int tid = threadIdx.x;
    int lane = tid & 63, wid = tid >> 6;
    int wm = wid >> 1, wn = wid & 1;
    int m0 = blockIdx.x * 64, n0 = blockIdx.y * 128;

    f32x4 acc[2][4];
#pragma unroll
    for (int i = 0; i < 2; ++i)
#pragma unroll
        for (int j = 0; j < 4; ++j)
#pragma unroll
            for (int r = 0; r < 4; ++r) acc[i][j][r] = 0.f;

    int rA = lane & 15, k8r = lane >> 4, g = lane >> 4;

    for (int kc = 0; kc < K; kc += 64) {
#pragma unroll
        for (int t = 0; t < 2; ++t) {
            int idx = t * 256 + tid;
            int row = idx >> 3, k8 = idx & 7;
            *(short8v*)&As[row * 72 + k8 * 8] =
                *(const short8v*)(A + (size_t)(m0 + row) * K + kc + k8 * 8);
        }
#pragma unroll
        for (int t = 0; t < 4; ++t) {
            int idx = t * 256 + tid;
            int row = idx >> 3, k8 = idx & 7;
            *(short8v*)&Ws[row * 72 + k8 * 8] =
                *(const short8v*)(W + (size_t)(n0 + row) * K + kc + k8 * 8);
        }
        __syncthreads();

        short8v a[2][2], b[2][4];
#pragma unroll
        for (int ks = 0; ks < 2; ++ks) {
#pragma unroll
            for (int mi = 0; mi < 2; ++mi)
                a[ks][mi] = *(const short8v*)&As[(wm * 32 + mi * 16 + rA) * 72 + ks * 32 + k8r * 8];
#pragma unroll
            for (int ni = 0; ni < 4; ++ni)
                b[ks][ni] = *(const short8v*)&Ws[(wn * 64 + ni * 16 + rA) * 72 + ks * 32 + k8r * 8];
        }
#pragma unroll
        for (int ks = 0; ks < 2; ++ks)
#pragma unroll
            for (int mi = 0; mi < 2; ++mi)
#pragma unroll
                for (int ni = 0; ni < 4; ++ni)
                    acc[mi][ni] = __builtin_amdgcn_mfma_f32_16x16x32_bf16(
                        a[ks][mi], b[ks][ni], acc[mi][ni], 0, 0, 0);
        __syncthreads();
    }

#pragma unroll
    for (int mi = 0; mi < 2; ++mi) {
#pragma unroll
        for (int ni = 0; ni < 4; ++ni) {
#pragma unroll
            for (int r = 0; r < 4; ++r) {
                int row = m0 + wm * 32 + mi * 16 + g * 4 + r;
                int col = n0 + wn * 64 + ni * 16 + rA;
                float v = acc[mi][ni][r];
                if (RELU) v = fmaxf(v, 0.f);
                if (OUTMAP == 0) {
                    OUT[(size_t)row * N + col] = f2bf(v);
                } else {
                    int l = row & 1023, bn = row >> 10;
                    int h = col >> 5, d = col & 31;
                    OUT[(size_t)z * 2097152 + ((bn * 8 + h) * 1024 + l) * 32 + d] = f2bf(v);
                }
            }
        }
    }
}

// ---------------------------------------------------------------------------
// K3: local-window attention, MFMA version.
// LDS: Ks (QK phase) and Ps (PV phase) UNION one buffer (disjoint in time,
// two barriers apart) -> ~33 KB -> 4 blocks/CU.  Softmax normalization
// deferred to after PV (P holds raw exp, bounded <=1).
// ---------------------------------------------------------------------------
__global__ __launch_bounds__(256) void attn_mfma_kernel(
    const unsigned short* __restrict__ Qb, const unsigned short* __restrict__ Kb,
    const unsigned short* __restrict__ Vb, unsigned short* __restrict__ ctx)
{
    int bh = blockIdx.x >> 5;
    int qv = blockIdx.x & 31;
    int tid = threadIdx.x, lane = tid & 63, wv = tid >> 6;
    int rA = lane & 15, k8r = lane >> 4, g = lane >> 4;

    __shared__ unsigned short KPs[7 * 32 * 40];  // Ks: [n][d] pitch 40 | later Ps: [q][n] pitch 232
    __shared__ unsigned short Vt[32 * 232];      // [d][n], pitch 232
    __shared__ float redm[2][2][4][4];
    __shared__ float reds[2][2][4][4];

    unsigned short* Ks = KPs;
    unsigned short* Ps = KPs;

    int mt = wv & 1, nh = wv >> 1;

    short8v qfrag = *(const short8v*)(
        Qb + ((size_t)bh * 1024 + qv * 32 + mt * 16 + rA) * 32 + k8r * 8);

#pragma unroll
    for (int it = 0; it < 4; ++it) {
        int idx = it * 256 + tid;
        if (idx < 896) {
            int dv = idx >> 7, rem = idx & 127;
            int kw = rem >> 2, c8 = (rem & 3) * 8;
            int kvc = min(max(qv - 3 + dv, 0), 31);
            size_t base = ((size_t)bh * 1024 + kvc * 32 + kw) * 32 + c8;
            int n = dv * 32 + kw;
            *(short8v*)&Ks[n * 40 + c8] = *(const short8v*)(Kb + base);
            short8v v8 = *(const short8v*)(Vb + base);
#pragma unroll
            for (int j = 0; j < 8; ++j)
                Vt[(c8 + j) * 232 + n] = (unsigned short)v8[j];
        }
    }
    __syncthreads();

    f32x4 sc[7];
#pragma unroll
    for (int ct = 0; ct < 7; ++ct)
#pragma unroll
        for (int r = 0; r < 4; ++r) sc[ct][r] = 0.f;
#pragma unroll
    for (int ct = 0; ct < 7; ++ct) {
        short8v b = *(const short8v*)&Ks[(nh * 112 + ct * 16 + rA) * 40 + k8r * 8];
        sc[ct] = __builtin_amdgcn_mfma_f32_16x16x32_bf16(qfrag, b, sc[ct], 0, 0, 0);
    }

    const float scale = 0.17677669529663687f;
    float mx[4] = {-1e30f, -1e30f, -1e30f, -1e30f};
#pragma unroll
    for (int ct = 0; ct < 7; ++ct) {
        int n = nh * 112 + ct * 16 + rA;
        int dv = n >> 5, kw = n & 31;
        int kv = qv - 3 + dv;
        bool vv = (kv >= 0) && (kv < 32);
#pragma unroll
        for (int r = 0; r < 4; ++r) {
            int qw = mt * 16 + g * 4 + r;
            int dj = kw - qw;
            bool ok = vv && (dj >= -3) && (dj <= 3);
            float s = ok ? sc[ct][r] * scale : -1e30f;
            sc[ct][r] = s;
            mx[r] = fmaxf(mx[r], s);
        }
    }
#pragma unroll
    for (int off = 8; off; off >>= 1)
#pragma unroll
        for (int r = 0; r < 4; ++r) mx[r] = fmaxf(mx[r], __shfl_xor(mx[r], off));
    if (rA == 0) {
#pragma unroll
        for (int r = 0; r < 4; ++r) redm[mt][nh][g][r] = mx[r];
    }
    __syncthreads();
#pragma unroll
    for (int r = 0; r < 4; ++r)
        mx[r] = fmaxf(redm[mt][0][g][r], redm[mt][1][g][r]);

    float sm[4] = {0.f, 0.f, 0.f, 0.f};
#pragma unroll
    for (int ct = 0; ct < 7; ++ct)
#pragma unroll
        for (int r = 0; r < 4; ++r) {
            float e = __expf(sc[ct][r] - mx[r]);
            sc[ct][r] = e;
            sm[r] += e;
        }
#pragma unroll
    for (int off = 8; off; off >>= 1)
#pragma unroll
        for (int r = 0; r < 4; ++r) sm[r] += __shfl_xor(sm[r], off);
    if (rA == 0) {
#pragma unroll
        for (int r = 0; r < 4; ++r) reds[mt][nh][g][r] = sm[r];
    }
    __syncthreads();   // after this barrier Ks is dead everywhere -> reuse as Ps
    float inv[4];
#pragma unroll
    for (int r = 0; r < 4; ++r)
        inv[r] = 1.f / (reds[mt][0][g][r] + reds[mt][1][g][r]);

    // P (raw exp) -> bf16 LDS [q][n] pitch 232, overlaying Ks
#pragma unroll
    for (int ct = 0; ct < 7; ++ct) {
        int n = nh * 112 + ct * 16 + rA;
#pragma unroll
        for (int r = 0; r < 4; ++r) {
            int q = mt * 16 + g * 4 + r;
            Ps[q * 232 + n] = f2bf(sc[ct][r]);
        }
    }
    __syncthreads();

    f32x4 o;
#pragma unroll
    for (int r = 0; r < 4; ++r) o[r] = 0.f;
#pragma unroll
    for (int kb = 0; kb < 7; ++kb) {
        short8v pa = *(const short8v*)&Ps[(mt * 16 + rA) * 232 + kb * 32 + k8r * 8];
        short8v vb = *(const short8v*)&Vt[(nh * 16 + rA) * 232 + kb * 32 + k8r * 8];
        o = __builtin_amdgcn_mfma_f32_16x16x32_bf16(pa, vb, o, 0, 0, 0);
    }

    {
        int bn = bh >> 3, h = bh & 7;
        int d = nh * 16 + rA;
#pragma unroll
        for (int r = 0; r < 4; ++r) {
            int q = qv * 32 + mt * 16 + g * 4 + r;
            ctx[((size_t)bn * 1024 + q) * 256 + h * 32 + d] = f2bf(o[r] * inv[r]);
        }
    }
}

// ---------------------------------------------------------------------------
// K4: out_proj + residual + LN2.  32-row tile, 512 threads / 8 waves,
// BK=64, pitch-72 LDS.
// ---------------------------------------------------------------------------
__global__ __launch_bounds__(512) void outproj_ln_kernel(
    const unsigned short* __restrict__ ctx, const unsigned short* __restrict__ Wop,
    float* __restrict__ epi_tok, const float* __restrict__ g2,
    const float* __restrict__ b2, unsigned short* __restrict__ ffin)
{
    __shared__ unsigned short As[32 * 72];
    __shared__ unsigned short Ws[256 * 72];
    __shared__ float part[2][4][4][4][2];

    int tid = threadIdx.x, lane = tid & 63, wv = tid >> 6;
    int m0 = blockIdx.x * 32;
    int rA = lane & 15, k8r = lane >> 4, g = lane >> 4;
    int rg = wv & 1, ch = wv >> 1;

    f32x4 acc[4];
#pragma unroll
    for (int ct = 0; ct < 4; ++ct)
#pragma unroll
        for (int r = 0; r < 4; ++r) acc[ct][r] = 0.f;

    for (int kc = 0; kc < 256; kc += 64) {
        if (tid < 256) {
            int row = tid >> 3, k8 = tid & 7;
            *(short8v*)&As[row * 72 + k8 * 8] =
                *(const short8v*)(ctx + (size_t)(m0 + row) * 256 + kc + k8 * 8);
        }
#pragma unroll
        for (int t = 0; t < 4; ++t) {
            int idx = t * 512 + tid;
            int row = idx >> 3, k8 = idx & 7;
            *(short8v*)&Ws[row * 72 + k8 * 8] =
                *(const short8v*)(Wop + (size_t)row * 256 + kc + k8 * 8);
        }
        __syncthreads();
        short8v a[2];
#pragma unroll
        for (int ks = 0; ks < 2; ++ks)
            a[ks] = *(const short8v*)&As[(rg * 16 + rA) * 72 + ks * 32 + k8r * 8];
#pragma unroll
        for (int ks = 0; ks < 2; ++ks)
#pragma unroll
            for (int ct = 0; ct < 4; ++ct) {
                short8v b = *(const short8v*)&Ws[(ch * 64 + ct * 16 + rA) * 72 + ks * 32 + k8r * 8];
                acc[ct] = __builtin_amdgcn_mfma_f32_16x16x32_bf16(a[ks], b, acc[ct], 0, 0, 0);
            }
        __syncthreads();
    }

    float s[4] = {0.f, 0.f, 0.f, 0.f}, q[4] = {0.f, 0.f, 0.f, 0.f};
#pragma unroll
    for (int ct = 0; ct < 4; ++ct) {
        int col = ch * 64 + ct * 16 + rA;
#pragma unroll
        for (int r = 0; r < 4; ++r) {
            int row = m0 + rg * 16 + g * 4 + r;
            float v = acc[ct][r] + epi_tok[(size_t)row * 256 + col];
            acc[ct][r] = v;
            s[r] += v; q[r] += v * v;
        }
    }
#pragma unroll
    for (int off = 8; off; off >>= 1)
#pragma unroll
        for (int r = 0; r < 4; ++r) {
            s[r] += __shfl_xor(s[r], off);
            q[r] += __shfl_xor(q[r], off);
        }
    if (rA == 0) {
#pragma unroll
        for (int r = 0; r < 4; ++r) {
            part[rg][ch][g][r][0] = s[r];
            part[rg][ch][g][r][1] = q[r];
        }
    }
    __syncthreads();
    float mu[4], rs[4];
#pragma unroll
    for (int r = 0; r < 4; ++r) {
        float S = part[rg][0][g][r][0] + part[rg][1][g][r][0]
                + part[rg][2][g][r][0] + part[rg][3][g][r][0];
        float Q = part[rg][0][g][r][1] + part[rg][1][g][r][1]
                + part[rg][2][g][r][1] + part[rg][3][g][r][1];
        mu[r] = S * (1.f / 256.f);
        rs[r] = rsqrtf(Q * (1.f / 256.f) - mu[r] * mu[r] + 1e-5f);
    }
#pragma unroll
    for (int ct = 0; ct < 4; ++ct) {
        int col = ch * 64 + ct * 16 + rA;
        float gg = g2[col], bv = b2[col];
#pragma unroll
        for (int r = 0; r < 4; ++r) {
            int row = m0 + rg * 16 + g * 4 + r;
            size_t o = (size_t)row * 256 + col;
            epi_tok[o] = acc[ct][r];
            ffin[o] = f2bf((acc[ct][r] - mu[r]) * rs[r] * gg + bv);
        }
    }
}

// ---------------------------------------------------------------------------
// K6: FF2 + residual + final E->32 projection + transposed store, fused.
// 32-row tile, 512 threads / 8 waves, BK=64, pitch-72.
// ---------------------------------------------------------------------------
__global__ __launch_bounds__(512) void ff2_final_kernel(
    const unsigned short* __restrict__ ffh, const unsigned short* __restrict__ W2,
    const float* __restrict__ epi_tok, const float* __restrict__ w_out,
    float* __restrict__ out)
{
    __shared__ unsigned short As[32 * 72];
    __shared__ unsigned short Ws[256 * 72];
    __shared__ unsigned short Ts[32 * 264];

    int tid = threadIdx.x, lane = tid & 63, wv = tid >> 6;
    int m0 = blockIdx.x * 32;
    int rA = lane & 15, k8r = lane >> 4, g = lane >> 4;
    int rg = wv & 1, ch = wv >> 1;

    f32x4 acc[4];
#pragma unroll
    for (int ct = 0; ct < 4; ++ct)
#pragma unroll
        for (int r = 0; r < 4; ++r) acc[ct][r] = 0.f;

    for (int kc = 0; kc < 512; kc += 64) {
        if (tid < 256) {
            int row = tid >> 3, k8 = tid & 7;
            *(short8v*)&As[row * 72 + k8 * 8] =
                *(const short8v*)(ffh + (size_t)(m0 + row) * 512 + kc + k8 * 8);
        }
#pragma unroll
        for (int t = 0; t < 4; ++t) {
            int idx = t * 512 + tid;
            int row = idx >> 3, k8 = idx & 7;
            *(short8v*)&Ws[row * 72 + k8 * 8] =
                *(const short8v*)(W2 + (size_t)row * 512 + kc + k8 * 8);
        }
        __syncthreads();
        short8v a[2];
#pragma unroll
        for (int ks = 0; ks < 2; ++ks)
            a[ks] = *(const short8v*)&As[(rg * 16 + rA) * 72 + ks * 32 + k8r * 8];
#pragma unroll
        for (int ks = 0; ks < 2; ++ks)
#pragma unroll
            for (int ct = 0; ct < 4; ++ct) {
                short8v b = *(const short8v*)&Ws[(ch * 64 + ct * 16 + rA) * 72 + ks * 32 + k8r * 8];
                acc[ct] = __builtin_amdgcn_mfma_f32_16x16x32_bf16(a[ks], b, acc[ct], 0, 0, 0);
            }
        __syncthreads();
    }

#pragma unroll
    for (int ct = 0; ct < 4; ++ct) {
        int col = ch * 64 + ct * 16 + rA;
#pragma unroll
        for (int r = 0; r < 4; ++r) {
            int lrow = rg * 16 + g * 4 + r;
            float v = acc[ct][r] + epi_tok[(size_t)(m0 + lrow) * 256 + col];
            Ts[lrow * 264 + col] = f2bf(v);
        }
    }
    __syncthreads();

    int bn = m0 >> 10, l0 = m0 & 1023;
    int bb = bn >> 2, nn = bn & 3;

    if (wv < 4) {
        int rw = wv & 1, cw = wv >> 1;
        f32x4 a2;
#pragma unroll
        for (int r = 0; r < 4; ++r) a2[r] = 0.f;
#pragma unroll
        for (int ks = 0; ks < 8; ++ks) {
            short8v af = *(const short8v*)&Ts[(rw * 16 + rA) * 264 + ks * 32 + k8r * 8];
            const float* wp = w_out + (cw * 16 + rA) * 256 + ks * 32 + k8r * 8;
            float4 w0 = *(const float4*)wp;
            float4 w1 = *(const float4*)(wp + 4);
            short8v bf;
            bf[0] = (short)f2bf(w0.x); bf[1] = (short)f2bf(w0.y);
            bf[2] = (short)f2bf(w0.z); bf[3] = (short)f2bf(w0.w);
            bf[4] = (short)f2bf(w1.x); bf[5] = (short)f2bf(w1.y);
            bf[6] = (short)f2bf(w1.z); bf[7] = (short)f2bf(w1.w);
            a2 = __builtin_amdgcn_mfma_f32_16x16x32_bf16(af, bf, a2, 0, 0, 0);
        }
        int c = cw * 16 + rA;
        int l = l0 + rw * 16 + g * 4;
        float4 st; st.x = a2[0]; st.y = a2[1]; st.z = a2[2]; st.w = a2[3];
        *(float4*)(out + ((size_t)(bb * 32 + c) * 4 + nn) * 1024 + l) = st;
    }
}

// ---------------------------------------------------------------------------
extern "C" void kernel_launch(void* const* d_in, const int* in_sizes, int n_in,
                              void* d_out, int out_size, void* d_ws, size_t ws_size,
                              hipStream_t stream) {
    const float* x_lf       = (const float*)d_in[0];
    const float* x_hf       = (const float*)d_in[1];
    const float* w_in       = (const float*)d_in[2];
    const float* w_qk       = (const float*)d_in[3];
    const float* ln_g       = (const float*)d_in[4];
    const float* ln_b       = (const float*)d_in[5];
    const float* in_proj_w  = (const float*)d_in[6];
    const float* out_proj_w = (const float*)d_in[7];
    const float* ln2_g      = (const float*)d_in[8];
    const float* ln2_b      = (const float*)d_in[9];
    const float* ff_w1      = (const float*)d_in[10];
    const float* ff_w2      = (const float*)d_in[11];
    const float* w_out      = (const float*)d_in[12];
    float* out = (float*)d_out;

    char* w = (char*)d_ws;
    float* epi_tok         = (float*)(w);                         // 8 MB fp32
    unsigned short* Qb     = (unsigned short*)(w + (8u  << 20));  // 4 MB bf16
    unsigned short* Kb     = (unsigned short*)(w + (12u << 20));
    unsigned short* Vb     = (unsigned short*)(w + (16u << 20));
    unsigned short* q_b    = (unsigned short*)(w + (20u << 20));
    unsigned short* k_b    = (unsigned short*)(w + (24u << 20));
    unsigned short* kv_b   = (unsigned short*)(w + (28u << 20));
    unsigned short* ctx_b  = (unsigned short*)(w + (32u << 20));
    unsigned short* ffin_b = (unsigned short*)(w + (36u << 20));
    unsigned short* ffh_b  = (unsigned short*)(w + (40u << 20));  // 8 MB
    unsigned short* wqkv_b = (unsigned short*)(w + (48u << 20));
    unsigned short* wop_b  = (unsigned short*)(w + (49u << 20));
    unsigned short* wff1_b = (unsigned short*)(w + (50u << 20));
    unsigned short* wff2_b = (unsigned short*)(w + (51u << 20));

    // 1. gather + input proj + dual LN + weight conversion  [256 blocks]
    embed_conv_kernel<<<256, 256, 0, stream>>>(
        x_lf, x_hf, w_in, w_qk, ln_g, ln_b, epi_tok, kv_b, q_b, k_b,
        in_proj_w, out_proj_w, ff_w1, ff_w2, wqkv_b, wop_b, wff1_b, wff2_b);
    // 2. QKV projection -> bf16 (bn,h,l,d)   [768 blocks, BK=64]
    gemm_mfma64<1, false><<<dim3(128, 2, 3), 256, 0, stream>>>(
        q_b, k_b, kv_b, wqkv_b, Qb, 256, 256);
    // 3. local-window attention (MFMA, 4 blocks/CU) -> ctx bf16
    attn_mfma_kernel<<<2048, 256, 0, stream>>>(Qb, Kb, Vb, ctx_b);
    // 4. out_proj + residual + LN2  [512 thr, BK=64]
    outproj_ln_kernel<<<256, 512, 0, stream>>>(ctx_b, wop_b, epi_tok,
                                               ln2_g, ln2_b, ffin_b);
    // 5. FF1 + ReLU -> bf16 [8192,512]   [512 blocks, BK=64]
    gemm_mfma64<0, true><<<dim3(128, 4, 1), 256, 0, stream>>>(
        ffin_b, ffin_b, ffin_b, wff1_b, ffh_b, 256, 512);
    // 6. FF2 + residual + final projection + transposed store  [512 thr, BK=64]
    ff2_final_kernel<<<256, 512, 0, stream>>>(ffh_b, wff2_b, epi_tok, w_out, out);
}

// Round 15
// 74.944 us; speedup vs baseline: 1.5328x; 1.0286x over previous
//
#include <hip/hip_runtime.h>
#include <hip/hip_bf16.h>

// Problem constants: B=2,C=32,N=4,V=32,W=32,E=256,H=8,D=32,K_H=K_W=7
// L=1024, Bn=8, M=8192.  Internal row ordering: m = bn*1024 + l  (bn-major)

typedef __attribute__((ext_vector_type(8))) short short8v;   // 8 bf16 (4 VGPR)
typedef __attribute__((ext_vector_type(4))) float f32x4;

__device__ __forceinline__ unsigned short f2bf(float x) {
    union { float f; unsigned u; } c; c.f = x;
    unsigned r = c.u + 0x7FFFu + ((c.u >> 16) & 1u);
    return (unsigned short)(r >> 16);
}
__device__ __forceinline__ float bf2f(short b) {
    union { unsigned u; float f; } c;
    c.u = ((unsigned)(unsigned short)b) << 16;
    return c.f;
}

// ---------------------------------------------------------------------------
// K1: 256 blocks x 512 threads (8 waves = 2/SIMD).  32-row gather + input
// proj (MFMA) + dual LN.  Wave = (p = wv>>2, rg = (wv>>1)&1, chh = wv&1);
// each wave covers 8 col-tiles (half of E).  LN stats cross-wave via LDS.
// Weight-conversion tail: exactly 1 float4 per thread.
// ---------------------------------------------------------------------------
__global__ __launch_bounds__(512) void embed_conv_kernel(
    const float* __restrict__ x_lf, const float* __restrict__ x_hf,
    const float* __restrict__ w_in, const float* __restrict__ w_qk,
    const float* __restrict__ ln_g, const float* __restrict__ ln_b,
    float* __restrict__ epi_tok, unsigned short* __restrict__ kv_b,
    unsigned short* __restrict__ q_b, unsigned short* __restrict__ k_b,
    const float* __restrict__ wqkv, const float* __restrict__ wop,
    const float* __restrict__ wff1, const float* __restrict__ wff2,
    unsigned short* __restrict__ o1, unsigned short* __restrict__ o2,
    unsigned short* __restrict__ o3, unsigned short* __restrict__ o4)
{
    __shared__ float xs[2][32][36];
    __shared__ float part[2][2][2][4][4][2];  // [p][rg][chh][g][r][{s,q}]

    int tid = threadIdx.x;
    int m0 = blockIdx.x * 32;
    int bn = m0 >> 10, l0 = m0 & 1023;
    int bb = bn >> 2, nn = bn & 3;

    // gather: 2 tensors x 256 float4s = 512 = 1 per thread
    {
        int t = tid >> 8, rem = tid & 255;
        int c = rem >> 3, i0 = (rem & 7) * 4;
        size_t base = (size_t)bb * 131072 + (size_t)c * 4096 + nn * 1024 + l0 + i0;
        const float* src = t ? x_hf : x_lf;
        *(float4*)&xs[t][c][i0] = *(const float4*)(src + base);
    }
    __syncthreads();

    int lane = tid & 63, wv = tid >> 6;
    int rA = lane & 15, k8r = lane >> 4, g = k8r, k0 = k8r * 8;
    int p = wv >> 2, rg = (wv >> 1) & 1, chh = wv & 1;
    const float* W = p ? w_qk : w_in;

    short8v afrag;
#pragma unroll
    for (int j = 0; j < 8; ++j)
        afrag[j] = (short)f2bf(xs[p][k0 + j][rg * 16 + rA]);

    f32x4 acc[8];
#pragma unroll
    for (int ct = 0; ct < 8; ++ct)
#pragma unroll
        for (int r = 0; r < 4; ++r) acc[ct][r] = 0.f;

#pragma unroll
    for (int ct = 0; ct < 8; ++ct) {
        const float* wp = W + ((chh * 8 + ct) * 16 + rA) * 32 + k0;
        float4 w0 = *(const float4*)wp;
        float4 w1 = *(const float4*)(wp + 4);
        short8v bfrag;
        bfrag[0] = (short)f2bf(w0.x); bfrag[1] = (short)f2bf(w0.y);
        bfrag[2] = (short)f2bf(w0.z); bfrag[3] = (short)f2bf(w0.w);
        bfrag[4] = (short)f2bf(w1.x); bfrag[5] = (short)f2bf(w1.y);
        bfrag[6] = (short)f2bf(w1.z); bfrag[7] = (short)f2bf(w1.w);
        acc[ct] = __builtin_amdgcn_mfma_f32_16x16x32_bf16(afrag, bfrag, acc[ct], 0, 0, 0);
    }

    float s[4] = {0.f, 0.f, 0.f, 0.f}, q[4] = {0.f, 0.f, 0.f, 0.f};
#pragma unroll
    for (int ct = 0; ct < 8; ++ct)
#pragma unroll
        for (int r = 0; r < 4; ++r) {
            float v = acc[ct][r];
            s[r] += v; q[r] += v * v;
        }
#pragma unroll
    for (int off = 8; off; off >>= 1)
#pragma unroll
        for (int r = 0; r < 4; ++r) {
            s[r] += __shfl_xor(s[r], off);
            q[r] += __shfl_xor(q[r], off);
        }
    if (rA == 0) {
#pragma unroll
        for (int r = 0; r < 4; ++r) {
            part[p][rg][chh][g][r][0] = s[r];
            part[p][rg][chh][g][r][1] = q[r];
        }
    }
    __syncthreads();
    float mu[4], rs[4];
#pragma unroll
    for (int r = 0; r < 4; ++r) {
        float S = part[p][rg][0][g][r][0] + part[p][rg][1][g][r][0];
        float Q = part[p][rg][0][g][r][1] + part[p][rg][1][g][r][1];
        mu[r] = S * (1.f / 256.f);
        rs[r] = rsqrtf(Q * (1.f / 256.f) - mu[r] * mu[r] + 1e-5f);
    }

#pragma unroll
    for (int ct = 0; ct < 8; ++ct) {
        int col = (chh * 8 + ct) * 16 + rA;
        float gg = ln_g[col], bv = ln_b[col];
#pragma unroll
        for (int r = 0; r < 4; ++r) {
            int row = m0 + rg * 16 + g * 4 + r;
            float v = acc[ct][r];
            float lnv = (v - mu[r]) * rs[r] * gg + bv;
            size_t o = (size_t)row * 256 + col;
            if (p == 0) {
                epi_tok[o] = v;
                q_b[o] = f2bf(lnv);
            } else {
                kv_b[o] = f2bf(v);
                k_b[o] = f2bf(lnv);
            }
        }
    }

    // ---- weight conversion tail: 131072 float4s = 1 per thread ----
    {
        int i4 = blockIdx.x * 512 + tid;
        const float* src; unsigned short* dst; int off;
        if (i4 < 49152)      { src = wqkv; dst = o1; off = i4 * 4; }
        else if (i4 < 65536) { src = wop;  dst = o2; off = (i4 - 49152) * 4; }
        else if (i4 < 98304) { src = wff1; dst = o3; off = (i4 - 65536) * 4; }
        else                 { src = wff2; dst = o4; off = (i4 - 98304) * 4; }
        float4 v = *(const float4*)(src + off);
        ushort4 u;
        u.x = f2bf(v.x); u.y = f2bf(v.y); u.z = f2bf(v.z); u.w = f2bf(v.w);
        *(ushort4*)(dst + off) = u;
    }
}

// ---------------------------------------------------------------------------
// K2: bf16 MFMA GEMM, 64x128 tile, 4 waves, BK=64, pitch-72 LDS.
// ---------------------------------------------------------------------------
template <int OUTMAP, bool RELU>
__global__ __launch_bounds__(256) void gemm_mfma64(
    const unsigned short* __restrict__ A0, const unsigned short* __restrict__ A1,
    const unsigned short* __restrict__ A2, const unsigned short* __restrict__ Wb,
    unsigned short* __restrict__ OUT, int K, int N)
{
    int z = blockIdx.z;
    const unsigned short* A = (z == 0) ? A0 : (z == 1) ? A1 : A2;
    const unsigned short* W = Wb + (size_t)z * 65536;

    __shared__ unsigned short As[64 * 72];
    __shared__ unsigned short Ws[128 * 72];

    int tid = threadIdx.x;
    int lane = tid & 63, wid = tid >> 6;
    int wm = wid >> 1, wn = wid & 1;
    int m0 = blockIdx.x * 64, n0 = blockIdx.y * 128;

    f32x4 acc[2][4];
#pragma unroll
    for (int i = 0; i < 2; ++i)
#pragma unroll
        for (int j = 0; j < 4; ++j)
#pragma unroll
            for (int r = 0; r < 4; ++r) acc[i][j][r] = 0.f;

    int rA = lane & 15, k8r = lane >> 4, g = lane >> 4;

    for (int kc = 0; kc < K; kc += 64) {
#pragma unroll
        for (int t = 0; t < 2; ++t) {
            int idx = t * 256 + tid;
            int row = idx >> 3, k8 = idx & 7;
            *(short8v*)&As[row * 72 + k8 * 8] =
                *(const short8v*)(A + (size_t)(m0 + row) * K + kc + k8 * 8);
        }
#pragma unroll
        for (int t = 0; t < 4; ++t) {
            int idx = t * 256 + tid;
            int row = idx >> 3, k8 = idx & 7;
            *(short8v*)&Ws[row * 72 + k8 * 8] =
                *(const short8v*)(W + (size_t)(n0 + row) * K + kc + k8 * 8);
        }
        __syncthreads();

        short8v a[2][2], b[2][4];
#pragma unroll
        for (int ks = 0; ks < 2; ++ks) {
#pragma unroll
            for (int mi = 0; mi < 2; ++mi)
                a[ks][mi] = *(const short8v*)&As[(wm * 32 + mi * 16 + rA) * 72 + ks * 32 + k8r * 8];
#pragma unroll
            for (int ni = 0; ni < 4; ++ni)
                b[ks][ni] = *(const short8v*)&Ws[(wn * 64 + ni * 16 + rA) * 72 + ks * 32 + k8r * 8];
        }
#pragma unroll
        for (int ks = 0; ks < 2; ++ks)
#pragma unroll
            for (int mi = 0; mi < 2; ++mi)
#pragma unroll
                for (int ni = 0; ni < 4; ++ni)
                    acc[mi][ni] = __builtin_amdgcn_mfma_f32_16x16x32_bf16(
                        a[ks][mi], b[ks][ni], acc[mi][ni], 0, 0, 0);
        __syncthreads();
    }

#pragma unroll
    for (int mi = 0; mi < 2; ++mi) {
#pragma unroll
        for (int ni = 0; ni < 4; ++ni) {
#pragma unroll
            for (int r = 0; r < 4; ++r) {
                int row = m0 + wm * 32 + mi * 16 + g * 4 + r;
                int col = n0 + wn * 64 + ni * 16 + rA;
                float v = acc[mi][ni][r];
                if (RELU) v = fmaxf(v, 0.f);
                if (OUTMAP == 0) {
                    OUT[(size_t)row * N + col] = f2bf(v);
                } else {
                    int l = row & 1023, bn = row >> 10;
                    int h = col >> 5, d = col & 31;
                    OUT[(size_t)z * 2097152 + ((bn * 8 + h) * 1024 + l) * 32 + d] = f2bf(v);
                }
            }
        }
    }
}

// ---------------------------------------------------------------------------
// K3: local-window attention, MFMA version.  Ks/Ps LDS union, deferred
// softmax normalization.  (unchanged from R14, passing)
// ---------------------------------------------------------------------------
__global__ __launch_bounds__(256) void attn_mfma_kernel(
    const unsigned short* __restrict__ Qb, const unsigned short* __restrict__ Kb,
    const unsigned short* __restrict__ Vb, unsigned short* __restrict__ ctx)
{
    int bh = blockIdx.x >> 5;
    int qv = blockIdx.x & 31;
    int tid = threadIdx.x, lane = tid & 63, wv = tid >> 6;
    int rA = lane & 15, k8r = lane >> 4, g = lane >> 4;

    __shared__ unsigned short KPs[7 * 32 * 40];
    __shared__ unsigned short Vt[32 * 232];
    __shared__ float redm[2][2][4][4];
    __shared__ float reds[2][2][4][4];

    unsigned short* Ks = KPs;
    unsigned short* Ps = KPs;

    int mt = wv & 1, nh = wv >> 1;

    short8v qfrag = *(const short8v*)(
        Qb + ((size_t)bh * 1024 + qv * 32 + mt * 16 + rA) * 32 + k8r * 8);

#pragma unroll
    for (int it = 0; it < 4; ++it) {
        int idx = it * 256 + tid;
        if (idx < 896) {
            int dv = idx >> 7, rem = idx & 127;
            int kw = rem >> 2, c8 = (rem & 3) * 8;
            int kvc = min(max(qv - 3 + dv, 0), 31);
            size_t base = ((size_t)bh * 1024 + kvc * 32 + kw) * 32 + c8;
            int n = dv * 32 + kw;
            *(short8v*)&Ks[n * 40 + c8] = *(const short8v*)(Kb + base);
            short8v v8 = *(const short8v*)(Vb + base);
#pragma unroll
            for (int j = 0; j < 8; ++j)
                Vt[(c8 + j) * 232 + n] = (unsigned short)v8[j];
        }
    }
    __syncthreads();

    f32x4 sc[7];
#pragma unroll
    for (int ct = 0; ct < 7; ++ct)
#pragma unroll
        for (int r = 0; r < 4; ++r) sc[ct][r] = 0.f;
#pragma unroll
    for (int ct = 0; ct < 7; ++ct) {
        short8v b = *(const short8v*)&Ks[(nh * 112 + ct * 16 + rA) * 40 + k8r * 8];
        sc[ct] = __builtin_amdgcn_mfma_f32_16x16x32_bf16(qfrag, b, sc[ct], 0, 0, 0);
    }

    const float scale = 0.17677669529663687f;
    float mx[4] = {-1e30f, -1e30f, -1e30f, -1e30f};
#pragma unroll
    for (int ct = 0; ct < 7; ++ct) {
        int n = nh * 112 + ct * 16 + rA;
        int dv = n >> 5, kw = n & 31;
        int kv = qv - 3 + dv;
        bool vv = (kv >= 0) && (kv < 32);
#pragma unroll
        for (int r = 0; r < 4; ++r) {
            int qw = mt * 16 + g * 4 + r;
            int dj = kw - qw;
            bool ok = vv && (dj >= -3) && (dj <= 3);
            float s = ok ? sc[ct][r] * scale : -1e30f;
            sc[ct][r] = s;
            mx[r] = fmaxf(mx[r], s);
        }
    }
#pragma unroll
    for (int off = 8; off; off >>= 1)
#pragma unroll
        for (int r = 0; r < 4; ++r) mx[r] = fmaxf(mx[r], __shfl_xor(mx[r], off));
    if (rA == 0) {
#pragma unroll
        for (int r = 0; r < 4; ++r) redm[mt][nh][g][r] = mx[r];
    }
    __syncthreads();
#pragma unroll
    for (int r = 0; r < 4; ++r)
        mx[r] = fmaxf(redm[mt][0][g][r], redm[mt][1][g][r]);

    float sm[4] = {0.f, 0.f, 0.f, 0.f};
#pragma unroll
    for (int ct = 0; ct < 7; ++ct)
#pragma unroll
        for (int r = 0; r < 4; ++r) {
            float e = __expf(sc[ct][r] - mx[r]);
            sc[ct][r] = e;
            sm[r] += e;
        }
#pragma unroll
    for (int off = 8; off; off >>= 1)
#pragma unroll
        for (int r = 0; r < 4; ++r) sm[r] += __shfl_xor(sm[r], off);
    if (rA == 0) {
#pragma unroll
        for (int r = 0; r < 4; ++r) reds[mt][nh][g][r] = sm[r];
    }
    __syncthreads();
    float inv[4];
#pragma unroll
    for (int r = 0; r < 4; ++r)
        inv[r] = 1.f / (reds[mt][0][g][r] + reds[mt][1][g][r]);

#pragma unroll
    for (int ct = 0; ct < 7; ++ct) {
        int n = nh * 112 + ct * 16 + rA;
#pragma unroll
        for (int r = 0; r < 4; ++r) {
            int q = mt * 16 + g * 4 + r;
            Ps[q * 232 + n] = f2bf(sc[ct][r]);
        }
    }
    __syncthreads();

    f32x4 o;
#pragma unroll
    for (int r = 0; r < 4; ++r) o[r] = 0.f;
#pragma unroll
    for (int kb = 0; kb < 7; ++kb) {
        short8v pa = *(const short8v*)&Ps[(mt * 16 + rA) * 232 + kb * 32 + k8r * 8];
        short8v vb = *(const short8v*)&Vt[(nh * 16 + rA) * 232 + kb * 32 + k8r * 8];
        o = __builtin_amdgcn_mfma_f32_16x16x32_bf16(pa, vb, o, 0, 0, 0);
    }

    {
        int bn = bh >> 3, h = bh & 7;
        int d = nh * 16 + rA;
#pragma unroll
        for (int r = 0; r < 4; ++r) {
            int q = qv * 32 + mt * 16 + g * 4 + r;
            ctx[((size_t)bn * 1024 + q) * 256 + h * 32 + d] = f2bf(o[r] * inv[r]);
        }
    }
}

// ---------------------------------------------------------------------------
// K4: out_proj + residual + LN2.  32-row tile, 512 threads / 8 waves,
// BK=64, pitch-72 LDS.  (unchanged, passing)
// ---------------------------------------------------------------------------
__global__ __launch_bounds__(512) void outproj_ln_kernel(
    const unsigned short* __restrict__ ctx, const unsigned short* __restrict__ Wop,
    float* __restrict__ epi_tok, const float* __restrict__ g2,
    const float* __restrict__ b2, unsigned short* __restrict__ ffin)
{
    __shared__ unsigned short As[32 * 72];
    __shared__ unsigned short Ws[256 * 72];
    __shared__ float part[2][4][4][4][2];

    int tid = threadIdx.x, lane = tid & 63, wv = tid >> 6;
    int m0 = blockIdx.x * 32;
    int rA = lane & 15, k8r = lane >> 4, g = lane >> 4;
    int rg = wv & 1, ch = wv >> 1;

    f32x4 acc[4];
#pragma unroll
    for (int ct = 0; ct < 4; ++ct)
#pragma unroll
        for (int r = 0; r < 4; ++r) acc[ct][r] = 0.f;

    for (int kc = 0; kc < 256; kc += 64) {
        if (tid < 256) {
            int row = tid >> 3, k8 = tid & 7;
            *(short8v*)&As[row * 72 + k8 * 8] =
                *(const short8v*)(ctx + (size_t)(m0 + row) * 256 + kc + k8 * 8);
        }
#pragma unroll
        for (int t = 0; t < 4; ++t) {
            int idx = t * 512 + tid;
            int row = idx >> 3, k8 = idx & 7;
            *(short8v*)&Ws[row * 72 + k8 * 8] =
                *(const short8v*)(Wop + (size_t)row * 256 + kc + k8 * 8);
        }
        __syncthreads();
        short8v a[2];
#pragma unroll
        for (int ks = 0; ks < 2; ++ks)
            a[ks] = *(const short8v*)&As[(rg * 16 + rA) * 72 + ks * 32 + k8r * 8];
#pragma unroll
        for (int ks = 0; ks < 2; ++ks)
#pragma unroll
            for (int ct = 0; ct < 4; ++ct) {
                short8v b = *(const short8v*)&Ws[(ch * 64 + ct * 16 + rA) * 72 + ks * 32 + k8r * 8];
                acc[ct] = __builtin_amdgcn_mfma_f32_16x16x32_bf16(a[ks], b, acc[ct], 0, 0, 0);
            }
        __syncthreads();
    }

    float s[4] = {0.f, 0.f, 0.f, 0.f}, q[4] = {0.f, 0.f, 0.f, 0.f};
#pragma unroll
    for (int ct = 0; ct < 4; ++ct) {
        int col = ch * 64 + ct * 16 + rA;
#pragma unroll
        for (int r = 0; r < 4; ++r) {
            int row = m0 + rg * 16 + g * 4 + r;
            float v = acc[ct][r] + epi_tok[(size_t)row * 256 + col];
            acc[ct][r] = v;
            s[r] += v; q[r] += v * v;
        }
    }
#pragma unroll
    for (int off = 8; off; off >>= 1)
#pragma unroll
        for (int r = 0; r < 4; ++r) {
            s[r] += __shfl_xor(s[r], off);
            q[r] += __shfl_xor(q[r], off);
        }
    if (rA == 0) {
#pragma unroll
        for (int r = 0; r < 4; ++r) {
            part[rg][ch][g][r][0] = s[r];
            part[rg][ch][g][r][1] = q[r];
        }
    }
    __syncthreads();
    float mu[4], rs[4];
#pragma unroll
    for (int r = 0; r < 4; ++r) {
        float S = part[rg][0][g][r][0] + part[rg][1][g][r][0]
                + part[rg][2][g][r][0] + part[rg][3][g][r][0];
        float Q = part[rg][0][g][r][1] + part[rg][1][g][r][1]
                + part[rg][2][g][r][1] + part[rg][3][g][r][1];
        mu[r] = S * (1.f / 256.f);
        rs[r] = rsqrtf(Q * (1.f / 256.f) - mu[r] * mu[r] + 1e-5f);
    }
#pragma unroll
    for (int ct = 0; ct < 4; ++ct) {
        int col = ch * 64 + ct * 16 + rA;
        float gg = g2[col], bv = b2[col];
#pragma unroll
        for (int r = 0; r < 4; ++r) {
            int row = m0 + rg * 16 + g * 4 + r;
            size_t o = (size_t)row * 256 + col;
            epi_tok[o] = acc[ct][r];
            ffin[o] = f2bf((acc[ct][r] - mu[r]) * rs[r] * gg + bv);
        }
    }
}

// ---------------------------------------------------------------------------
// K6: FF2 + residual + final E->32 projection + transposed store, fused.
// 32-row tile, 512 threads / 8 waves, BK=64, pitch-72.  (unchanged, passing)
// ---------------------------------------------------------------------------
__global__ __launch_bounds__(512) void ff2_final_kernel(
    const unsigned short* __restrict__ ffh, const unsigned short* __restrict__ W2,
    const float* __restrict__ epi_tok, const float* __restrict__ w_out,
    float* __restrict__ out)
{
    __shared__ unsigned short As[32 * 72];
    __shared__ unsigned short Ws[256 * 72];
    __shared__ unsigned short Ts[32 * 264];

    int tid = threadIdx.x, lane = tid & 63, wv = tid >> 6;
    int m0 = blockIdx.x * 32;
    int rA = lane & 15, k8r = lane >> 4, g = lane >> 4;
    int rg = wv & 1, ch = wv >> 1;

    f32x4 acc[4];
#pragma unroll
    for (int ct = 0; ct < 4; ++ct)
#pragma unroll
        for (int r = 0; r < 4; ++r) acc[ct][r] = 0.f;

    for (int kc = 0; kc < 512; kc += 64) {
        if (tid < 256) {
            int row = tid >> 3, k8 = tid & 7;
            *(short8v*)&As[row * 72 + k8 * 8] =
                *(const short8v*)(ffh + (size_t)(m0 + row) * 512 + kc + k8 * 8);
        }
#pragma unroll
        for (int t = 0; t < 4; ++t) {
            int idx = t * 512 + tid;
            int row = idx >> 3, k8 = idx & 7;
            *(short8v*)&Ws[row * 72 + k8 * 8] =
                *(const short8v*)(W2 + (size_t)row * 512 + kc + k8 * 8);
        }
        __syncthreads();
        short8v a[2];
#pragma unroll
        for (int ks = 0; ks < 2; ++ks)
            a[ks] = *(const short8v*)&As[(rg * 16 + rA) * 72 + ks * 32 + k8r * 8];
#pragma unroll
        for (int ks = 0; ks < 2; ++ks)
#pragma unroll
            for (int ct = 0; ct < 4; ++ct) {
                short8v b = *(const short8v*)&Ws[(ch * 64 + ct * 16 + rA) * 72 + ks * 32 + k8r * 8];
                acc[ct] = __builtin_amdgcn_mfma_f32_16x16x32_bf16(a[ks], b, acc[ct], 0, 0, 0);
            }
        __syncthreads();
    }

#pragma unroll
    for (int ct = 0; ct < 4; ++ct) {
        int col = ch * 64 + ct * 16 + rA;
#pragma unroll
        for (int r = 0; r < 4; ++r) {
            int lrow = rg * 16 + g * 4 + r;
            float v = acc[ct][r] + epi_tok[(size_t)(m0 + lrow) * 256 + col];
            Ts[lrow * 264 + col] = f2bf(v);
        }
    }
    __syncthreads();

    int bn = m0 >> 10, l0 = m0 & 1023;
    int bb = bn >> 2, nn = bn & 3;

    if (wv < 4) {
        int rw = wv & 1, cw = wv >> 1;
        f32x4 a2;
#pragma unroll
        for (int r = 0; r < 4; ++r) a2[r] = 0.f;
#pragma unroll
        for (int ks = 0; ks < 8; ++ks) {
            short8v af = *(const short8v*)&Ts[(rw * 16 + rA) * 264 + ks * 32 + k8r * 8];
            const float* wp = w_out + (cw * 16 + rA) * 256 + ks * 32 + k8r * 8;
            float4 w0 = *(const float4*)wp;
            float4 w1 = *(const float4*)(wp + 4);
            short8v bf;
            bf[0] = (short)f2bf(w0.x); bf[1] = (short)f2bf(w0.y);
            bf[2] = (short)f2bf(w0.z); bf[3] = (short)f2bf(w0.w);
            bf[4] = (short)f2bf(w1.x); bf[5] = (short)f2bf(w1.y);
            bf[6] = (short)f2bf(w1.z); bf[7] = (short)f2bf(w1.w);
            a2 = __builtin_amdgcn_mfma_f32_16x16x32_bf16(af, bf, a2, 0, 0, 0);
        }
        int c = cw * 16 + rA;
        int l = l0 + rw * 16 + g * 4;
        float4 st; st.x = a2[0]; st.y = a2[1]; st.z = a2[2]; st.w = a2[3];
        *(float4*)(out + ((size_t)(bb * 32 + c) * 4 + nn) * 1024 + l) = st;
    }
}

// ---------------------------------------------------------------------------
extern "C" void kernel_launch(void* const* d_in, const int* in_sizes, int n_in,
                              void* d_out, int out_size, void* d_ws, size_t ws_size,
                              hipStream_t stream) {
    const float* x_lf       = (const float*)d_in[0];
    const float* x_hf       = (const float*)d_in[1];
    const float* w_in       = (const float*)d_in[2];
    const float* w_qk       = (const float*)d_in[3];
    const float* ln_g       = (const float*)d_in[4];
    const float* ln_b       = (const float*)d_in[5];
    const float* in_proj_w  = (const float*)d_in[6];
    const float* out_proj_w = (const float*)d_in[7];
    const float* ln2_g      = (const float*)d_in[8];
    const float* ln2_b      = (const float*)d_in[9];
    const float* ff_w1      = (const float*)d_in[10];
    const float* ff_w2      = (const float*)d_in[11];
    const float* w_out      = (const float*)d_in[12];
    float* out = (float*)d_out;

    char* w = (char*)d_ws;
    float* epi_tok         = (float*)(w);                         // 8 MB fp32
    unsigned short* Qb     = (unsigned short*)(w + (8u  << 20));  // 4 MB bf16
    unsigned short* Kb     = (unsigned short*)(w + (12u << 20));
    unsigned short* Vb     = (unsigned short*)(w + (16u << 20));
    unsigned short* q_b    = (unsigned short*)(w + (20u << 20));
    unsigned short* k_b    = (unsigned short*)(w + (24u << 20));
    unsigned short* kv_b   = (unsigned short*)(w + (28u << 20));
    unsigned short* ctx_b  = (unsigned short*)(w + (32u << 20));
    unsigned short* ffin_b = (unsigned short*)(w + (36u << 20));
    unsigned short* ffh_b  = (unsigned short*)(w + (40u << 20));  // 8 MB
    unsigned short* wqkv_b = (unsigned short*)(w + (48u << 20));
    unsigned short* wop_b  = (unsigned short*)(w + (49u << 20));
    unsigned short* wff1_b = (unsigned short*)(w + (50u << 20));
    unsigned short* wff2_b = (unsigned short*)(w + (51u << 20));

    // 1. gather + input proj + dual LN + weight conversion  [256 blk x 512]
    embed_conv_kernel<<<256, 512, 0, stream>>>(
        x_lf, x_hf, w_in, w_qk, ln_g, ln_b, epi_tok, kv_b, q_b, k_b,
        in_proj_w, out_proj_w, ff_w1, ff_w2, wqkv_b, wop_b, wff1_b, wff2_b);
    // 2. QKV projection -> bf16 (bn,h,l,d)   [768 blocks, BK=64]
    gemm_mfma64<1, false><<<dim3(128, 2, 3), 256, 0, stream>>>(
        q_b, k_b, kv_b, wqkv_b, Qb, 256, 256);
    // 3. local-window attention (MFMA, 4 blocks/CU) -> ctx bf16
    attn_mfma_kernel<<<2048, 256, 0, stream>>>(Qb, Kb, Vb, ctx_b);
    // 4. out_proj + residual + LN2  [512 thr, BK=64]
    outproj_ln_kernel<<<256, 512, 0, stream>>>(ctx_b, wop_b, epi_tok,
                                               ln2_g, ln2_b, ffin_b);
    // 5. FF1 + ReLU -> bf16 [8192,512]   [512 blocks, BK=64]
    gemm_mfma64<0, true><<<dim3(128, 4, 1), 256, 0, stream>>>(
        ffin_b, ffin_b, ffin_b, wff1_b, ffh_b, 256, 512);
    // 6. FF2 + residual + final projection + transposed store  [512 thr, BK=64]
    ff2_final_kernel<<<256, 512, 0, stream>>>(ffh_b, wff2_b, epi_tok, w_out, out);
}

// Round 16
// 73.570 us; speedup vs baseline: 1.5614x; 1.0187x over previous
//
#include <hip/hip_runtime.h>
#include <hip/hip_bf16.h>

// Problem constants: B=2,C=32,N=4,V=32,W=32,E=256,H=8,D=32,K_H=K_W=7
// L=1024, Bn=8, M=8192.  Internal row ordering: m = bn*1024 + l  (bn-major)
// Residual stream epi_b is bf16 (storage only; all arithmetic fp32).

typedef __attribute__((ext_vector_type(8))) short short8v;   // 8 bf16 (4 VGPR)
typedef __attribute__((ext_vector_type(4))) float f32x4;

__device__ __forceinline__ unsigned short f2bf(float x) {
    union { float f; unsigned u; } c; c.f = x;
    unsigned r = c.u + 0x7FFFu + ((c.u >> 16) & 1u);
    return (unsigned short)(r >> 16);
}
__device__ __forceinline__ float bf2f(short b) {
    union { unsigned u; float f; } c;
    c.u = ((unsigned)(unsigned short)b) << 16;
    return c.f;
}

// ---------------------------------------------------------------------------
// K1: 256 blocks x 512 threads.  32-row gather + input proj (MFMA) + dual LN.
// Residual stream stored bf16.  Weight-conversion tail: 1 float4/thread.
// ---------------------------------------------------------------------------
__global__ __launch_bounds__(512) void embed_conv_kernel(
    const float* __restrict__ x_lf, const float* __restrict__ x_hf,
    const float* __restrict__ w_in, const float* __restrict__ w_qk,
    const float* __restrict__ ln_g, const float* __restrict__ ln_b,
    unsigned short* __restrict__ epi_b, unsigned short* __restrict__ kv_b,
    unsigned short* __restrict__ q_b, unsigned short* __restrict__ k_b,
    const float* __restrict__ wqkv, const float* __restrict__ wop,
    const float* __restrict__ wff1, const float* __restrict__ wff2,
    unsigned short* __restrict__ o1, unsigned short* __restrict__ o2,
    unsigned short* __restrict__ o3, unsigned short* __restrict__ o4)
{
    __shared__ float xs[2][32][36];
    __shared__ float part[2][2][2][4][4][2];  // [p][rg][chh][g][r][{s,q}]

    int tid = threadIdx.x;
    int m0 = blockIdx.x * 32;
    int bn = m0 >> 10, l0 = m0 & 1023;
    int bb = bn >> 2, nn = bn & 3;

    {
        int t = tid >> 8, rem = tid & 255;
        int c = rem >> 3, i0 = (rem & 7) * 4;
        size_t base = (size_t)bb * 131072 + (size_t)c * 4096 + nn * 1024 + l0 + i0;
        const float* src = t ? x_hf : x_lf;
        *(float4*)&xs[t][c][i0] = *(const float4*)(src + base);
    }
    __syncthreads();

    int lane = tid & 63, wv = tid >> 6;
    int rA = lane & 15, k8r = lane >> 4, g = k8r, k0 = k8r * 8;
    int p = wv >> 2, rg = (wv >> 1) & 1, chh = wv & 1;
    const float* W = p ? w_qk : w_in;

    short8v afrag;
#pragma unroll
    for (int j = 0; j < 8; ++j)
        afrag[j] = (short)f2bf(xs[p][k0 + j][rg * 16 + rA]);

    f32x4 acc[8];
#pragma unroll
    for (int ct = 0; ct < 8; ++ct)
#pragma unroll
        for (int r = 0; r < 4; ++r) acc[ct][r] = 0.f;

#pragma unroll
    for (int ct = 0; ct < 8; ++ct) {
        const float* wp = W + ((chh * 8 + ct) * 16 + rA) * 32 + k0;
        float4 w0 = *(const float4*)wp;
        float4 w1 = *(const float4*)(wp + 4);
        short8v bfrag;
        bfrag[0] = (short)f2bf(w0.x); bfrag[1] = (short)f2bf(w0.y);
        bfrag[2] = (short)f2bf(w0.z); bfrag[3] = (short)f2bf(w0.w);
        bfrag[4] = (short)f2bf(w1.x); bfrag[5] = (short)f2bf(w1.y);
        bfrag[6] = (short)f2bf(w1.z); bfrag[7] = (short)f2bf(w1.w);
        acc[ct] = __builtin_amdgcn_mfma_f32_16x16x32_bf16(afrag, bfrag, acc[ct], 0, 0, 0);
    }

    float s[4] = {0.f, 0.f, 0.f, 0.f}, q[4] = {0.f, 0.f, 0.f, 0.f};
#pragma unroll
    for (int ct = 0; ct < 8; ++ct)
#pragma unroll
        for (int r = 0; r < 4; ++r) {
            float v = acc[ct][r];
            s[r] += v; q[r] += v * v;
        }
#pragma unroll
    for (int off = 8; off; off >>= 1)
#pragma unroll
        for (int r = 0; r < 4; ++r) {
            s[r] += __shfl_xor(s[r], off);
            q[r] += __shfl_xor(q[r], off);
        }
    if (rA == 0) {
#pragma unroll
        for (int r = 0; r < 4; ++r) {
            part[p][rg][chh][g][r][0] = s[r];
            part[p][rg][chh][g][r][1] = q[r];
        }
    }
    __syncthreads();
    float mu[4], rs[4];
#pragma unroll
    for (int r = 0; r < 4; ++r) {
        float S = part[p][rg][0][g][r][0] + part[p][rg][1][g][r][0];
        float Q = part[p][rg][0][g][r][1] + part[p][rg][1][g][r][1];
        mu[r] = S * (1.f / 256.f);
        rs[r] = rsqrtf(Q * (1.f / 256.f) - mu[r] * mu[r] + 1e-5f);
    }

#pragma unroll
    for (int ct = 0; ct < 8; ++ct) {
        int col = (chh * 8 + ct) * 16 + rA;
        float gg = ln_g[col], bv = ln_b[col];
#pragma unroll
        for (int r = 0; r < 4; ++r) {
            int row = m0 + rg * 16 + g * 4 + r;
            float v = acc[ct][r];
            float lnv = (v - mu[r]) * rs[r] * gg + bv;
            size_t o = (size_t)row * 256 + col;
            if (p == 0) {
                epi_b[o] = f2bf(v);
                q_b[o] = f2bf(lnv);
            } else {
                kv_b[o] = f2bf(v);
                k_b[o] = f2bf(lnv);
            }
        }
    }

    // ---- weight conversion tail: 131072 float4s = 1 per thread ----
    {
        int i4 = blockIdx.x * 512 + tid;
        const float* src; unsigned short* dst; int off;
        if (i4 < 49152)      { src = wqkv; dst = o1; off = i4 * 4; }
        else if (i4 < 65536) { src = wop;  dst = o2; off = (i4 - 49152) * 4; }
        else if (i4 < 98304) { src = wff1; dst = o3; off = (i4 - 65536) * 4; }
        else                 { src = wff2; dst = o4; off = (i4 - 98304) * 4; }
        float4 v = *(const float4*)(src + off);
        ushort4 u;
        u.x = f2bf(v.x); u.y = f2bf(v.y); u.z = f2bf(v.z); u.w = f2bf(v.w);
        *(ushort4*)(dst + off) = u;
    }
}

// ---------------------------------------------------------------------------
// K2: bf16 MFMA GEMM, 64x128 tile, 4 waves, BK=64, pitch-72 LDS.
// ---------------------------------------------------------------------------
template <int OUTMAP, bool RELU>
__global__ __launch_bounds__(256) void gemm_mfma64(
    const unsigned short* __restrict__ A0, const unsigned short* __restrict__ A1,
    const unsigned short* __restrict__ A2, const unsigned short* __restrict__ Wb,
    unsigned short* __restrict__ OUT, int K, int N)
{
    int z = blockIdx.z;
    const unsigned short* A = (z == 0) ? A0 : (z == 1) ? A1 : A2;
    const unsigned short* W = Wb + (size_t)z * 65536;

    __shared__ unsigned short As[64 * 72];
    __shared__ unsigned short Ws[128 * 72];

    int tid = threadIdx.x;
    int lane = tid & 63, wid = tid >> 6;
    int wm = wid >> 1, wn = wid & 1;
    int m0 = blockIdx.x * 64, n0 = blockIdx.y * 128;

    f32x4 acc[2][4];
#pragma unroll
    for (int i = 0; i < 2; ++i)
#pragma unroll
        for (int j = 0; j < 4; ++j)
#pragma unroll
            for (int r = 0; r < 4; ++r) acc[i][j][r] = 0.f;

    int rA = lane & 15, k8r = lane >> 4, g = lane >> 4;

    for (int kc = 0; kc < K; kc += 64) {
#pragma unroll
        for (int t = 0; t < 2; ++t) {
            int idx = t * 256 + tid;
            int row = idx >> 3, k8 = idx & 7;
            *(short8v*)&As[row * 72 + k8 * 8] =
                *(const short8v*)(A + (size_t)(m0 + row) * K + kc + k8 * 8);
        }
#pragma unroll
        for (int t = 0; t < 4; ++t) {
            int idx = t * 256 + tid;
            int row = idx >> 3, k8 = idx & 7;
            *(short8v*)&Ws[row * 72 + k8 * 8] =
                *(const short8v*)(W + (size_t)(n0 + row) * K + kc + k8 * 8);
        }
        __syncthreads();

        short8v a[2][2], b[2][4];
#pragma unroll
        for (int ks = 0; ks < 2; ++ks) {
#pragma unroll
            for (int mi = 0; mi < 2; ++mi)
                a[ks][mi] = *(const short8v*)&As[(wm * 32 + mi * 16 + rA) * 72 + ks * 32 + k8r * 8];
#pragma unroll
            for (int ni = 0; ni < 4; ++ni)
                b[ks][ni] = *(const short8v*)&Ws[(wn * 64 + ni * 16 + rA) * 72 + ks * 32 + k8r * 8];
        }
#pragma unroll
        for (int ks = 0; ks < 2; ++ks)
#pragma unroll
            for (int mi = 0; mi < 2; ++mi)
#pragma unroll
                for (int ni = 0; ni < 4; ++ni)
                    acc[mi][ni] = __builtin_amdgcn_mfma_f32_16x16x32_bf16(
                        a[ks][mi], b[ks][ni], acc[mi][ni], 0, 0, 0);
        __syncthreads();
    }

#pragma unroll
    for (int mi = 0; mi < 2; ++mi) {
#pragma unroll
        for (int ni = 0; ni < 4; ++ni) {
#pragma unroll
            for (int r = 0; r < 4; ++r) {
                int row = m0 + wm * 32 + mi * 16 + g * 4 + r;
                int col = n0 + wn * 64 + ni * 16 + rA;
                float v = acc[mi][ni][r];
                if (RELU) v = fmaxf(v, 0.f);
                if (OUTMAP == 0) {
                    OUT[(size_t)row * N + col] = f2bf(v);
                } else {
                    int l = row & 1023, bn = row >> 10;
                    int h = col >> 5, d = col & 31;
                    OUT[(size_t)z * 2097152 + ((bn * 8 + h) * 1024 + l) * 32 + d] = f2bf(v);
                }
            }
        }
    }
}

// ---------------------------------------------------------------------------
// K3: local-window attention, MFMA version.  Ks/Ps LDS union, deferred
// softmax normalization.  (unchanged, passing)
// ---------------------------------------------------------------------------
__global__ __launch_bounds__(256) void attn_mfma_kernel(
    const unsigned short* __restrict__ Qb, const unsigned short* __restrict__ Kb,
    const unsigned short* __restrict__ Vb, unsigned short* __restrict__ ctx)
{
    int bh = blockIdx.x >> 5;
    int qv = blockIdx.x & 31;
    int tid = threadIdx.x, lane = tid & 63, wv = tid >> 6;
    int rA = lane & 15, k8r = lane >> 4, g = lane >> 4;

    __shared__ unsigned short KPs[7 * 32 * 40];
    __shared__ unsigned short Vt[32 * 232];
    __shared__ float redm[2][2][4][4];
    __shared__ float reds[2][2][4][4];

    unsigned short* Ks = KPs;
    unsigned short* Ps = KPs;

    int mt = wv & 1, nh = wv >> 1;

    short8v qfrag = *(const short8v*)(
        Qb + ((size_t)bh * 1024 + qv * 32 + mt * 16 + rA) * 32 + k8r * 8);

#pragma unroll
    for (int it = 0; it < 4; ++it) {
        int idx = it * 256 + tid;
        if (idx < 896) {
            int dv = idx >> 7, rem = idx & 127;
            int kw = rem >> 2, c8 = (rem & 3) * 8;
            int kvc = min(max(qv - 3 + dv, 0), 31);
            size_t base = ((size_t)bh * 1024 + kvc * 32 + kw) * 32 + c8;
            int n = dv * 32 + kw;
            *(short8v*)&Ks[n * 40 + c8] = *(const short8v*)(Kb + base);
            short8v v8 = *(const short8v*)(Vb + base);
#pragma unroll
            for (int j = 0; j < 8; ++j)
                Vt[(c8 + j) * 232 + n] = (unsigned short)v8[j];
        }
    }
    __syncthreads();

    f32x4 sc[7];
#pragma unroll
    for (int ct = 0; ct < 7; ++ct)
#pragma unroll
        for (int r = 0; r < 4; ++r) sc[ct][r] = 0.f;
#pragma unroll
    for (int ct = 0; ct < 7; ++ct) {
        short8v b = *(const short8v*)&Ks[(nh * 112 + ct * 16 + rA) * 40 + k8r * 8];
        sc[ct] = __builtin_amdgcn_mfma_f32_16x16x32_bf16(qfrag, b, sc[ct], 0, 0, 0);
    }

    const float scale = 0.17677669529663687f;
    float mx[4] = {-1e30f, -1e30f, -1e30f, -1e30f};
#pragma unroll
    for (int ct = 0; ct < 7; ++ct) {
        int n = nh * 112 + ct * 16 + rA;
        int dv = n >> 5, kw = n & 31;
        int kv = qv - 3 + dv;
        bool vv = (kv >= 0) && (kv < 32);
#pragma unroll
        for (int r = 0; r < 4; ++r) {
            int qw = mt * 16 + g * 4 + r;
            int dj = kw - qw;
            bool ok = vv && (dj >= -3) && (dj <= 3);
            float s = ok ? sc[ct][r] * scale : -1e30f;
            sc[ct][r] = s;
            mx[r] = fmaxf(mx[r], s);
        }
    }
#pragma unroll
    for (int off = 8; off; off >>= 1)
#pragma unroll
        for (int r = 0; r < 4; ++r) mx[r] = fmaxf(mx[r], __shfl_xor(mx[r], off));
    if (rA == 0) {
#pragma unroll
        for (int r = 0; r < 4; ++r) redm[mt][nh][g][r] = mx[r];
    }
    __syncthreads();
#pragma unroll
    for (int r = 0; r < 4; ++r)
        mx[r] = fmaxf(redm[mt][0][g][r], redm[mt][1][g][r]);

    float sm[4] = {0.f, 0.f, 0.f, 0.f};
#pragma unroll
    for (int ct = 0; ct < 7; ++ct)
#pragma unroll
        for (int r = 0; r < 4; ++r) {
            float e = __expf(sc[ct][r] - mx[r]);
            sc[ct][r] = e;
            sm[r] += e;
        }
#pragma unroll
    for (int off = 8; off; off >>= 1)
#pragma unroll
        for (int r = 0; r < 4; ++r) sm[r] += __shfl_xor(sm[r], off);
    if (rA == 0) {
#pragma unroll
        for (int r = 0; r < 4; ++r) reds[mt][nh][g][r] = sm[r];
    }
    __syncthreads();
    float inv[4];
#pragma unroll
    for (int r = 0; r < 4; ++r)
        inv[r] = 1.f / (reds[mt][0][g][r] + reds[mt][1][g][r]);

#pragma unroll
    for (int ct = 0; ct < 7; ++ct) {
        int n = nh * 112 + ct * 16 + rA;
#pragma unroll
        for (int r = 0; r < 4; ++r) {
            int q = mt * 16 + g * 4 + r;
            Ps[q * 232 + n] = f2bf(sc[ct][r]);
        }
    }
    __syncthreads();

    f32x4 o;
#pragma unroll
    for (int r = 0; r < 4; ++r) o[r] = 0.f;
#pragma unroll
    for (int kb = 0; kb < 7; ++kb) {
        short8v pa = *(const short8v*)&Ps[(mt * 16 + rA) * 232 + kb * 32 + k8r * 8];
        short8v vb = *(const short8v*)&Vt[(nh * 16 + rA) * 232 + kb * 32 + k8r * 8];
        o = __builtin_amdgcn_mfma_f32_16x16x32_bf16(pa, vb, o, 0, 0, 0);
    }

    {
        int bn = bh >> 3, h = bh & 7;
        int d = nh * 16 + rA;
#pragma unroll
        for (int r = 0; r < 4; ++r) {
            int q = qv * 32 + mt * 16 + g * 4 + r;
            ctx[((size_t)bn * 1024 + q) * 256 + h * 32 + d] = f2bf(o[r] * inv[r]);
        }
    }
}

// ---------------------------------------------------------------------------
// K4: out_proj + residual(bf16) + LN2.  32-row tile, 512 threads / 8 waves,
// BK=64, pitch-72 LDS.
// ---------------------------------------------------------------------------
__global__ __launch_bounds__(512) void outproj_ln_kernel(
    const unsigned short* __restrict__ ctx, const unsigned short* __restrict__ Wop,
    unsigned short* __restrict__ epi_b, const float* __restrict__ g2,
    const float* __restrict__ b2, unsigned short* __restrict__ ffin)
{
    __shared__ unsigned short As[32 * 72];
    __shared__ unsigned short Ws[256 * 72];
    __shared__ float part[2][4][4][4][2];

    int tid = threadIdx.x, lane = tid & 63, wv = tid >> 6;
    int m0 = blockIdx.x * 32;
    int rA = lane & 15, k8r = lane >> 4, g = lane >> 4;
    int rg = wv & 1, ch = wv >> 1;

    f32x4 acc[4];
#pragma unroll
    for (int ct = 0; ct < 4; ++ct)
#pragma unroll
        for (int r = 0; r < 4; ++r) acc[ct][r] = 0.f;

    for (int kc = 0; kc < 256; kc += 64) {
        if (tid < 256) {
            int row = tid >> 3, k8 = tid & 7;
            *(short8v*)&As[row * 72 + k8 * 8] =
                *(const short8v*)(ctx + (size_t)(m0 + row) * 256 + kc + k8 * 8);
        }
#pragma unroll
        for (int t = 0; t < 4; ++t) {
            int idx = t * 512 + tid;
            int row = idx >> 3, k8 = idx & 7;
            *(short8v*)&Ws[row * 72 + k8 * 8] =
                *(const short8v*)(Wop + (size_t)row * 256 + kc + k8 * 8);
        }
        __syncthreads();
        short8v a[2];
#pragma unroll
        for (int ks = 0; ks < 2; ++ks)
            a[ks] = *(const short8v*)&As[(rg * 16 + rA) * 72 + ks * 32 + k8r * 8];
#pragma unroll
        for (int ks = 0; ks < 2; ++ks)
#pragma unroll
            for (int ct = 0; ct < 4; ++ct) {
                short8v b = *(const short8v*)&Ws[(ch * 64 + ct * 16 + rA) * 72 + ks * 32 + k8r * 8];
                acc[ct] = __builtin_amdgcn_mfma_f32_16x16x32_bf16(a[ks], b, acc[ct], 0, 0, 0);
            }
        __syncthreads();
    }

    float s[4] = {0.f, 0.f, 0.f, 0.f}, q[4] = {0.f, 0.f, 0.f, 0.f};
#pragma unroll
    for (int ct = 0; ct < 4; ++ct) {
        int col = ch * 64 + ct * 16 + rA;
#pragma unroll
        for (int r = 0; r < 4; ++r) {
            int row = m0 + rg * 16 + g * 4 + r;
            float v = acc[ct][r] + bf2f(epi_b[(size_t)row * 256 + col]);
            acc[ct][r] = v;
            s[r] += v; q[r] += v * v;
        }
    }
#pragma unroll
    for (int off = 8; off; off >>= 1)
#pragma unroll
        for (int r = 0; r < 4; ++r) {
            s[r] += __shfl_xor(s[r], off);
            q[r] += __shfl_xor(q[r], off);
        }
    if (rA == 0) {
#pragma unroll
        for (int r = 0; r < 4; ++r) {
            part[rg][ch][g][r][0] = s[r];
            part[rg][ch][g][r][1] = q[r];
        }
    }
    __syncthreads();
    float mu[4], rs[4];
#pragma unroll
    for (int r = 0; r < 4; ++r) {
        float S = part[rg][0][g][r][0] + part[rg][1][g][r][0]
                + part[rg][2][g][r][0] + part[rg][3][g][r][0];
        float Q = part[rg][0][g][r][1] + part[rg][1][g][r][1]
                + part[rg][2][g][r][1] + part[rg][3][g][r][1];
        mu[r] = S * (1.f / 256.f);
        rs[r] = rsqrtf(Q * (1.f / 256.f) - mu[r] * mu[r] + 1e-5f);
    }
#pragma unroll
    for (int ct = 0; ct < 4; ++ct) {
        int col = ch * 64 + ct * 16 + rA;
        float gg = g2[col], bv = b2[col];
#pragma unroll
        for (int r = 0; r < 4; ++r) {
            int row = m0 + rg * 16 + g * 4 + r;
            size_t o = (size_t)row * 256 + col;
            epi_b[o] = f2bf(acc[ct][r]);
            ffin[o] = f2bf((acc[ct][r] - mu[r]) * rs[r] * gg + bv);
        }
    }
}

// ---------------------------------------------------------------------------
// K6: FF2 + residual(bf16) + final E->32 projection + transposed store.
// 32-row tile, 512 threads / 8 waves, BK=64, pitch-72.
// ---------------------------------------------------------------------------
__global__ __launch_bounds__(512) void ff2_final_kernel(
    const unsigned short* __restrict__ ffh, const unsigned short* __restrict__ W2,
    const unsigned short* __restrict__ epi_b, const float* __restrict__ w_out,
    float* __restrict__ out)
{
    __shared__ unsigned short As[32 * 72];
    __shared__ unsigned short Ws[256 * 72];
    __shared__ unsigned short Ts[32 * 264];

    int tid = threadIdx.x, lane = tid & 63, wv = tid >> 6;
    int m0 = blockIdx.x * 32;
    int rA = lane & 15, k8r = lane >> 4, g = lane >> 4;
    int rg = wv & 1, ch = wv >> 1;

    f32x4 acc[4];
#pragma unroll
    for (int ct = 0; ct < 4; ++ct)
#pragma unroll
        for (int r = 0; r < 4; ++r) acc[ct][r] = 0.f;

    for (int kc = 0; kc < 512; kc += 64) {
        if (tid < 256) {
            int row = tid >> 3, k8 = tid & 7;
            *(short8v*)&As[row * 72 + k8 * 8] =
                *(const short8v*)(ffh + (size_t)(m0 + row) * 512 + kc + k8 * 8);
        }
#pragma unroll
        for (int t = 0; t < 4; ++t) {
            int idx = t * 512 + tid;
            int row = idx >> 3, k8 = idx & 7;
            *(short8v*)&Ws[row * 72 + k8 * 8] =
                *(const short8v*)(W2 + (size_t)row * 512 + kc + k8 * 8);
        }
        __syncthreads();
        short8v a[2];
#pragma unroll
        for (int ks = 0; ks < 2; ++ks)
            a[ks] = *(const short8v*)&As[(rg * 16 + rA) * 72 + ks * 32 + k8r * 8];
#pragma unroll
        for (int ks = 0; ks < 2; ++ks)
#pragma unroll
            for (int ct = 0; ct < 4; ++ct) {
                short8v b = *(const short8v*)&Ws[(ch * 64 + ct * 16 + rA) * 72 + ks * 32 + k8r * 8];
                acc[ct] = __builtin_amdgcn_mfma_f32_16x16x32_bf16(a[ks], b, acc[ct], 0, 0, 0);
            }
        __syncthreads();
    }

#pragma unroll
    for (int ct = 0; ct < 4; ++ct) {
        int col = ch * 64 + ct * 16 + rA;
#pragma unroll
        for (int r = 0; r < 4; ++r) {
            int lrow = rg * 16 + g * 4 + r;
            float v = acc[ct][r] + bf2f(epi_b[(size_t)(m0 + lrow) * 256 + col]);
            Ts[lrow * 264 + col] = f2bf(v);
        }
    }
    __syncthreads();

    int bn = m0 >> 10, l0 = m0 & 1023;
    int bb = bn >> 2, nn = bn & 3;

    if (wv < 4) {
        int rw = wv & 1, cw = wv >> 1;
        f32x4 a2;
#pragma unroll
        for (int r = 0; r < 4; ++r) a2[r] = 0.f;
#pragma unroll
        for (int ks = 0; ks < 8; ++ks) {
            short8v af = *(const short8v*)&Ts[(rw * 16 + rA) * 264 + ks * 32 + k8r * 8];
            const float* wp = w_out + (cw * 16 + rA) * 256 + ks * 32 + k8r * 8;
            float4 w0 = *(const float4*)wp;
            float4 w1 = *(const float4*)(wp + 4);
            short8v bf;
            bf[0] = (short)f2bf(w0.x); bf[1] = (short)f2bf(w0.y);
            bf[2] = (short)f2bf(w0.z); bf[3] = (short)f2bf(w0.w);
            bf[4] = (short)f2bf(w1.x); bf[5] = (short)f2bf(w1.y);
            bf[6] = (short)f2bf(w1.z); bf[7] = (short)f2bf(w1.w);
            a2 = __builtin_amdgcn_mfma_f32_16x16x32_bf16(af, bf, a2, 0, 0, 0);
        }
        int c = cw * 16 + rA;
        int l = l0 + rw * 16 + g * 4;
        float4 st; st.x = a2[0]; st.y = a2[1]; st.z = a2[2]; st.w = a2[3];
        *(float4*)(out + ((size_t)(bb * 32 + c) * 4 + nn) * 1024 + l) = st;
    }
}

// ---------------------------------------------------------------------------
extern "C" void kernel_launch(void* const* d_in, const int* in_sizes, int n_in,
                              void* d_out, int out_size, void* d_ws, size_t ws_size,
                              hipStream_t stream) {
    const float* x_lf       = (const float*)d_in[0];
    const float* x_hf       = (const float*)d_in[1];
    const float* w_in       = (const float*)d_in[2];
    const float* w_qk       = (const float*)d_in[3];
    const float* ln_g       = (const float*)d_in[4];
    const float* ln_b       = (const float*)d_in[5];
    const float* in_proj_w  = (const float*)d_in[6];
    const float* out_proj_w = (const float*)d_in[7];
    const float* ln2_g      = (const float*)d_in[8];
    const float* ln2_b      = (const float*)d_in[9];
    const float* ff_w1      = (const float*)d_in[10];
    const float* ff_w2      = (const float*)d_in[11];
    const float* w_out      = (const float*)d_in[12];
    float* out = (float*)d_out;

    char* w = (char*)d_ws;
    unsigned short* epi_b  = (unsigned short*)(w);                // 4 MB bf16
    unsigned short* Qb     = (unsigned short*)(w + (4u  << 20));  // 4 MB bf16
    unsigned short* Kb     = (unsigned short*)(w + (8u  << 20));
    unsigned short* Vb     = (unsigned short*)(w + (12u << 20));
    unsigned short* q_b    = (unsigned short*)(w + (16u << 20));
    unsigned short* k_b    = (unsigned short*)(w + (20u << 20));
    unsigned short* kv_b   = (unsigned short*)(w + (24u << 20));
    unsigned short* ctx_b  = (unsigned short*)(w + (28u << 20));
    unsigned short* ffin_b = (unsigned short*)(w + (32u << 20));
    unsigned short* ffh_b  = (unsigned short*)(w + (36u << 20));  // 8 MB
    unsigned short* wqkv_b = (unsigned short*)(w + (44u << 20));
    unsigned short* wop_b  = (unsigned short*)(w + (45u << 20));
    unsigned short* wff1_b = (unsigned short*)(w + (46u << 20));
    unsigned short* wff2_b = (unsigned short*)(w + (47u << 20));

    // 1. gather + input proj + dual LN + weight conversion  [256 blk x 512]
    embed_conv_kernel<<<256, 512, 0, stream>>>(
        x_lf, x_hf, w_in, w_qk, ln_g, ln_b, epi_b, kv_b, q_b, k_b,
        in_proj_w, out_proj_w, ff_w1, ff_w2, wqkv_b, wop_b, wff1_b, wff2_b);
    // 2. QKV projection -> bf16 (bn,h,l,d)   [768 blocks, BK=64]
    gemm_mfma64<1, false><<<dim3(128, 2, 3), 256, 0, stream>>>(
        q_b, k_b, kv_b, wqkv_b, Qb, 256, 256);
    // 3. local-window attention (MFMA, 4 blocks/CU) -> ctx bf16
    attn_mfma_kernel<<<2048, 256, 0, stream>>>(Qb, Kb, Vb, ctx_b);
    // 4. out_proj + residual(bf16) + LN2  [512 thr, BK=64]
    outproj_ln_kernel<<<256, 512, 0, stream>>>(ctx_b, wop_b, epi_b,
                                               ln2_g, ln2_b, ffin_b);
    // 5. FF1 + ReLU -> bf16 [8192,512]   [512 blocks, BK=64]
    gemm_mfma64<0, true><<<dim3(128, 4, 1), 256, 0, stream>>>(
        ffin_b, ffin_b, ffin_b, wff1_b, ffh_b, 256, 512);
    // 6. FF2 + residual(bf16) + final projection + transposed store
    ff2_final_kernel<<<256, 512, 0, stream>>>(ffh_b, wff2_b, epi_b, w_out, out);
}

// Round 17
// 67.559 us; speedup vs baseline: 1.7003x; 1.0890x over previous
//
#include <hip/hip_runtime.h>
#include <hip/hip_bf16.h>

// Problem constants: B=2,C=32,N=4,V=32,W=32,E=256,H=8,D=32,K_H=K_W=7
// L=1024, Bn=8, M=8192.  Internal row ordering: m = bn*1024 + l  (bn-major)
// Residual stream epi_b is bf16 (storage only; all arithmetic fp32).

typedef __attribute__((ext_vector_type(8))) short short8v;   // 8 bf16 (4 VGPR)
typedef __attribute__((ext_vector_type(4))) float f32x4;

__device__ __forceinline__ unsigned short f2bf(float x) {
    union { float f; unsigned u; } c; c.f = x;
    unsigned r = c.u + 0x7FFFu + ((c.u >> 16) & 1u);
    return (unsigned short)(r >> 16);
}
__device__ __forceinline__ float bf2f(short b) {
    union { unsigned u; float f; } c;
    c.u = ((unsigned)(unsigned short)b) << 16;
    return c.f;
}

// ---------------------------------------------------------------------------
// K1: 256 blocks x 512 threads.  32-row gather + input proj (MFMA) + dual LN.
// Residual stream stored bf16.  Weight-conversion tail: 1 float4/thread.
// ---------------------------------------------------------------------------
__global__ __launch_bounds__(512) void embed_conv_kernel(
    const float* __restrict__ x_lf, const float* __restrict__ x_hf,
    const float* __restrict__ w_in, const float* __restrict__ w_qk,
    const float* __restrict__ ln_g, const float* __restrict__ ln_b,
    unsigned short* __restrict__ epi_b, unsigned short* __restrict__ kv_b,
    unsigned short* __restrict__ q_b, unsigned short* __restrict__ k_b,
    const float* __restrict__ wqkv, const float* __restrict__ wop,
    const float* __restrict__ wff1, const float* __restrict__ wff2,
    unsigned short* __restrict__ o1, unsigned short* __restrict__ o2,
    unsigned short* __restrict__ o3, unsigned short* __restrict__ o4)
{
    __shared__ float xs[2][32][36];
    __shared__ float part[2][2][2][4][4][2];  // [p][rg][chh][g][r][{s,q}]

    int tid = threadIdx.x;
    int m0 = blockIdx.x * 32;
    int bn = m0 >> 10, l0 = m0 & 1023;
    int bb = bn >> 2, nn = bn & 3;

    {
        int t = tid >> 8, rem = tid & 255;
        int c = rem >> 3, i0 = (rem & 7) * 4;
        size_t base = (size_t)bb * 131072 + (size_t)c * 4096 + nn * 1024 + l0 + i0;
        const float* src = t ? x_hf : x_lf;
        *(float4*)&xs[t][c][i0] = *(const float4*)(src + base);
    }
    __syncthreads();

    int lane = tid & 63, wv = tid >> 6;
    int rA = lane & 15, k8r = lane >> 4, g = k8r, k0 = k8r * 8;
    int p = wv >> 2, rg = (wv >> 1) & 1, chh = wv & 1;
    const float* W = p ? w_qk : w_in;

    short8v afrag;
#pragma unroll
    for (int j = 0; j < 8; ++j)
        afrag[j] = (short)f2bf(xs[p][k0 + j][rg * 16 + rA]);

    f32x4 acc[8];
#pragma unroll
    for (int ct = 0; ct < 8; ++ct)
#pragma unroll
        for (int r = 0; r < 4; ++r) acc[ct][r] = 0.f;

#pragma unroll
    for (int ct = 0; ct < 8; ++ct) {
        const float* wp = W + ((chh * 8 + ct) * 16 + rA) * 32 + k0;
        float4 w0 = *(const float4*)wp;
        float4 w1 = *(const float4*)(wp + 4);
        short8v bfrag;
        bfrag[0] = (short)f2bf(w0.x); bfrag[1] = (short)f2bf(w0.y);
        bfrag[2] = (short)f2bf(w0.z); bfrag[3] = (short)f2bf(w0.w);
        bfrag[4] = (short)f2bf(w1.x); bfrag[5] = (short)f2bf(w1.y);
        bfrag[6] = (short)f2bf(w1.z); bfrag[7] = (short)f2bf(w1.w);
        acc[ct] = __builtin_amdgcn_mfma_f32_16x16x32_bf16(afrag, bfrag, acc[ct], 0, 0, 0);
    }

    float s[4] = {0.f, 0.f, 0.f, 0.f}, q[4] = {0.f, 0.f, 0.f, 0.f};
#pragma unroll
    for (int ct = 0; ct < 8; ++ct)
#pragma unroll
        for (int r = 0; r < 4; ++r) {
            float v = acc[ct][r];
            s[r] += v; q[r] += v * v;
        }
#pragma unroll
    for (int off = 8; off; off >>= 1)
#pragma unroll
        for (int r = 0; r < 4; ++r) {
            s[r] += __shfl_xor(s[r], off);
            q[r] += __shfl_xor(q[r], off);
        }
    if (rA == 0) {
#pragma unroll
        for (int r = 0; r < 4; ++r) {
            part[p][rg][chh][g][r][0] = s[r];
            part[p][rg][chh][g][r][1] = q[r];
        }
    }
    __syncthreads();
    float mu[4], rs[4];
#pragma unroll
    for (int r = 0; r < 4; ++r) {
        float S = part[p][rg][0][g][r][0] + part[p][rg][1][g][r][0];
        float Q = part[p][rg][0][g][r][1] + part[p][rg][1][g][r][1];
        mu[r] = S * (1.f / 256.f);
        rs[r] = rsqrtf(Q * (1.f / 256.f) - mu[r] * mu[r] + 1e-5f);
    }

#pragma unroll
    for (int ct = 0; ct < 8; ++ct) {
        int col = (chh * 8 + ct) * 16 + rA;
        float gg = ln_g[col], bv = ln_b[col];
#pragma unroll
        for (int r = 0; r < 4; ++r) {
            int row = m0 + rg * 16 + g * 4 + r;
            float v = acc[ct][r];
            float lnv = (v - mu[r]) * rs[r] * gg + bv;
            size_t o = (size_t)row * 256 + col;
            if (p == 0) {
                epi_b[o] = f2bf(v);
                q_b[o] = f2bf(lnv);
            } else {
                kv_b[o] = f2bf(v);
                k_b[o] = f2bf(lnv);
            }
        }
    }

    // ---- weight conversion tail: 131072 float4s = 1 per thread ----
    {
        int i4 = blockIdx.x * 512 + tid;
        const float* src; unsigned short* dst; int off;
        if (i4 < 49152)      { src = wqkv; dst = o1; off = i4 * 4; }
        else if (i4 < 65536) { src = wop;  dst = o2; off = (i4 - 49152) * 4; }
        else if (i4 < 98304) { src = wff1; dst = o3; off = (i4 - 65536) * 4; }
        else                 { src = wff2; dst = o4; off = (i4 - 98304) * 4; }
        float4 v = *(const float4*)(src + off);
        ushort4 u;
        u.x = f2bf(v.x); u.y = f2bf(v.y); u.z = f2bf(v.z); u.w = f2bf(v.w);
        *(ushort4*)(dst + off) = u;
    }
}

// ---------------------------------------------------------------------------
// K2: bf16 MFMA GEMM, 64x128 tile, 4 waves, BK=64, pitch-72 LDS.
// ---------------------------------------------------------------------------
template <int OUTMAP, bool RELU>
__global__ __launch_bounds__(256) void gemm_mfma64(
    const unsigned short* __restrict__ A0, const unsigned short* __restrict__ A1,
    const unsigned short* __restrict__ A2, const unsigned short* __restrict__ Wb,
    unsigned short* __restrict__ OUT, int K, int N)
{
    int z = blockIdx.z;
    const unsigned short* A = (z == 0) ? A0 : (z == 1) ? A1 : A2;
    const unsigned short* W = Wb + (size_t)z * 65536;

    __shared__ unsigned short As[64 * 72];
    __shared__ unsigned short Ws[128 * 72];

    int tid = threadIdx.x;
    int lane = tid & 63, wid = tid >> 6;
    int wm = wid >> 1, wn = wid & 1;
    int m0 = blockIdx.x * 64, n0 = blockIdx.y * 128;

    f32x4 acc[2][4];
#pragma unroll
    for (int i = 0; i < 2; ++i)
#pragma unroll
        for (int j = 0; j < 4; ++j)
#pragma unroll
            for (int r = 0; r < 4; ++r) acc[i][j][r] = 0.f;

    int rA = lane & 15, k8r = lane >> 4, g = lane >> 4;

    for (int kc = 0; kc < K; kc += 64) {
#pragma unroll
        for (int t = 0; t < 2; ++t) {
            int idx = t * 256 + tid;
            int row = idx >> 3, k8 = idx & 7;
            *(short8v*)&As[row * 72 + k8 * 8] =
                *(const short8v*)(A + (size_t)(m0 + row) * K + kc + k8 * 8);
        }
#pragma unroll
        for (int t = 0; t < 4; ++t) {
            int idx = t * 256 + tid;
            int row = idx >> 3, k8 = idx & 7;
            *(short8v*)&Ws[row * 72 + k8 * 8] =
                *(const short8v*)(W + (size_t)(n0 + row) * K + kc + k8 * 8);
        }
        __syncthreads();

        short8v a[2][2], b[2][4];
#pragma unroll
        for (int ks = 0; ks < 2; ++ks) {
#pragma unroll
            for (int mi = 0; mi < 2; ++mi)
                a[ks][mi] = *(const short8v*)&As[(wm * 32 + mi * 16 + rA) * 72 + ks * 32 + k8r * 8];
#pragma unroll
            for (int ni = 0; ni < 4; ++ni)
                b[ks][ni] = *(const short8v*)&Ws[(wn * 64 + ni * 16 + rA) * 72 + ks * 32 + k8r * 8];
        }
#pragma unroll
        for (int ks = 0; ks < 2; ++ks)
#pragma unroll
            for (int mi = 0; mi < 2; ++mi)
#pragma unroll
                for (int ni = 0; ni < 4; ++ni)
                    acc[mi][ni] = __builtin_amdgcn_mfma_f32_16x16x32_bf16(
                        a[ks][mi], b[ks][ni], acc[mi][ni], 0, 0, 0);
        __syncthreads();
    }

#pragma unroll
    for (int mi = 0; mi < 2; ++mi) {
#pragma unroll
        for (int ni = 0; ni < 4; ++ni) {
#pragma unroll
            for (int r = 0; r < 4; ++r) {
                int row = m0 + wm * 32 + mi * 16 + g * 4 + r;
                int col = n0 + wn * 64 + ni * 16 + rA;
                float v = acc[mi][ni][r];
                if (RELU) v = fmaxf(v, 0.f);
                if (OUTMAP == 0) {
                    OUT[(size_t)row * N + col] = f2bf(v);
                } else {
                    int l = row & 1023, bn = row >> 10;
                    int h = col >> 5, d = col & 31;
                    OUT[(size_t)z * 2097152 + ((bn * 8 + h) * 1024 + l) * 32 + d] = f2bf(v);
                }
            }
        }
    }
}

// ---------------------------------------------------------------------------
// K3: local-window attention, MFMA, 2 qv-rows per block (64 q, 8 kv-rows,
// 256 candidate keys).  Wave mt owns 16 q rows x all 256 keys -> softmax is
// wave-local (16-lane shfl, no LDS exchange).  Ks/Ps LDS union; deferred
// normalization.  Grid: 64 bh x 16 qp (qv0 = 2*qp).
// ---------------------------------------------------------------------------
__global__ __launch_bounds__(256) void attn_mfma_kernel(
    const unsigned short* __restrict__ Qb, const unsigned short* __restrict__ Kb,
    const unsigned short* __restrict__ Vb, unsigned short* __restrict__ ctx)
{
    int bh = blockIdx.x >> 4;       // bn*8 + h
    int qv0 = (blockIdx.x & 15) * 2;
    int tid = threadIdx.x, lane = tid & 63, mt = tid >> 6;
    int rA = lane & 15, k8r = lane >> 4, g = lane >> 4;

    __shared__ unsigned short KPs[64 * 264];   // Ks: [n<256][40] | Ps: [q<64][264]
    __shared__ unsigned short Vt[32 * 264];    // [d][n], pitch 264

    unsigned short* Ks = KPs;
    unsigned short* Ps = KPs;

    // Q A-fragment: wave mt owns q rows qq = mt*16 + rA
    short8v qfrag;
    {
        int qq = mt * 16 + rA;
        int l = (qv0 + (qq >> 5)) * 32 + (qq & 31);
        qfrag = *(const short8v*)(Qb + ((size_t)bh * 1024 + l) * 32 + k8r * 8);
    }

    // stage K (row-major pitch 40) + V transposed: 8 kv-rows x 32 kw x 4 c8
    // = 1024 chunks = 4 per thread
#pragma unroll
    for (int it = 0; it < 4; ++it) {
        int idx = it * 256 + tid;
        int dv = idx >> 7, rem = idx & 127;
        int kw = rem >> 2, c8 = (rem & 3) * 8;
        int kvc = min(max(qv0 - 3 + dv, 0), 31);
        size_t base = ((size_t)bh * 1024 + kvc * 32 + kw) * 32 + c8;
        int n = dv * 32 + kw;
        *(short8v*)&Ks[n * 40 + c8] = *(const short8v*)(Kb + base);
        short8v v8 = *(const short8v*)(Vb + base);
#pragma unroll
        for (int j = 0; j < 8; ++j)
            Vt[(c8 + j) * 264 + n] = (unsigned short)v8[j];
    }
    __syncthreads();

    // QK^T: 16 n-tiles of 16 keys
    f32x4 sc[16];
#pragma unroll
    for (int ct = 0; ct < 16; ++ct)
#pragma unroll
        for (int r = 0; r < 4; ++r) sc[ct][r] = 0.f;
#pragma unroll
    for (int ct = 0; ct < 16; ++ct) {
        short8v b = *(const short8v*)&Ks[(ct * 16 + rA) * 40 + k8r * 8];
        sc[ct] = __builtin_amdgcn_mfma_f32_16x16x32_bf16(qfrag, b, sc[ct], 0, 0, 0);
    }
    __syncthreads();   // all waves done reading Ks before Ps overlay writes

    // mask + scale + wave-local softmax (rows owned entirely by this wave)
    const float scale = 0.17677669529663687f;
    float mx[4] = {-1e30f, -1e30f, -1e30f, -1e30f};
#pragma unroll
    for (int ct = 0; ct < 16; ++ct) {
        int n = ct * 16 + rA;
        int dv = n >> 5, kw = n & 31;
        int kv = qv0 - 3 + dv;
        bool vok = (kv >= 0) && (kv < 32);
#pragma unroll
        for (int r = 0; r < 4; ++r) {
            int qq = mt * 16 + g * 4 + r;
            int v = qv0 + (qq >> 5), w = qq & 31;
            int djv = kv - v, djw = kw - w;
            bool ok = vok && (djv >= -3) && (djv <= 3) && (djw >= -3) && (djw <= 3);
            float s = ok ? sc[ct][r] * scale : -1e30f;
            sc[ct][r] = s;
            mx[r] = fmaxf(mx[r], s);
        }
    }
#pragma unroll
    for (int off = 8; off; off >>= 1)
#pragma unroll
        for (int r = 0; r < 4; ++r) mx[r] = fmaxf(mx[r], __shfl_xor(mx[r], off));

    float sm[4] = {0.f, 0.f, 0.f, 0.f};
#pragma unroll
    for (int ct = 0; ct < 16; ++ct)
#pragma unroll
        for (int r = 0; r < 4; ++r) {
            float e = __expf(sc[ct][r] - mx[r]);
            sc[ct][r] = e;
            sm[r] += e;
        }
#pragma unroll
    for (int off = 8; off; off >>= 1)
#pragma unroll
        for (int r = 0; r < 4; ++r) sm[r] += __shfl_xor(sm[r], off);
    float inv[4];
#pragma unroll
    for (int r = 0; r < 4; ++r) inv[r] = 1.f / sm[r];

    // P (raw exp, <=1) -> bf16 LDS [q][n] pitch 264, overlaying Ks
#pragma unroll
    for (int ct = 0; ct < 16; ++ct) {
        int n = ct * 16 + rA;
#pragma unroll
        for (int r = 0; r < 4; ++r) {
            int q = mt * 16 + g * 4 + r;
            Ps[q * 264 + n] = f2bf(sc[ct][r]);
        }
    }
    __syncthreads();

    // PV: wave mt -> 16 q x 32 d, 8 k-steps over 256 keys
    f32x4 o[2];
#pragma unroll
    for (int dt = 0; dt < 2; ++dt)
#pragma unroll
        for (int r = 0; r < 4; ++r) o[dt][r] = 0.f;
#pragma unroll
    for (int kb = 0; kb < 8; ++kb) {
        short8v pa = *(const short8v*)&Ps[(mt * 16 + rA) * 264 + kb * 32 + k8r * 8];
#pragma unroll
        for (int dt = 0; dt < 2; ++dt) {
            short8v vb = *(const short8v*)&Vt[(dt * 16 + rA) * 264 + kb * 32 + k8r * 8];
            o[dt] = __builtin_amdgcn_mfma_f32_16x16x32_bf16(pa, vb, o[dt], 0, 0, 0);
        }
    }

    {
        int bn = bh >> 3, h = bh & 7;
#pragma unroll
        for (int dt = 0; dt < 2; ++dt) {
            int d = dt * 16 + rA;
#pragma unroll
            for (int r = 0; r < 4; ++r) {
                int qq = mt * 16 + g * 4 + r;
                int l = (qv0 + (qq >> 5)) * 32 + (qq & 31);
                ctx[((size_t)bn * 1024 + l) * 256 + h * 32 + d] = f2bf(o[dt][r] * inv[r]);
            }
        }
    }
}

// ---------------------------------------------------------------------------
// K4: out_proj + residual(bf16) + LN2.  32-row tile, 512 threads / 8 waves,
// BK=64, pitch-72 LDS.  (unchanged, passing)
// ---------------------------------------------------------------------------
__global__ __launch_bounds__(512) void outproj_ln_kernel(
    const unsigned short* __restrict__ ctx, const unsigned short* __restrict__ Wop,
    unsigned short* __restrict__ epi_b, const float* __restrict__ g2,
    const float* __restrict__ b2, unsigned short* __restrict__ ffin)
{
    __shared__ unsigned short As[32 * 72];
    __shared__ unsigned short Ws[256 * 72];
    __shared__ float part[2][4][4][4][2];

    int tid = threadIdx.x, lane = tid & 63, wv = tid >> 6;
    int m0 = blockIdx.x * 32;
    int rA = lane & 15, k8r = lane >> 4, g = lane >> 4;
    int rg = wv & 1, ch = wv >> 1;

    f32x4 acc[4];
#pragma unroll
    for (int ct = 0; ct < 4; ++ct)
#pragma unroll
        for (int r = 0; r < 4; ++r) acc[ct][r] = 0.f;

    for (int kc = 0; kc < 256; kc += 64) {
        if (tid < 256) {
            int row = tid >> 3, k8 = tid & 7;
            *(short8v*)&As[row * 72 + k8 * 8] =
                *(const short8v*)(ctx + (size_t)(m0 + row) * 256 + kc + k8 * 8);
        }
#pragma unroll
        for (int t = 0; t < 4; ++t) {
            int idx = t * 512 + tid;
            int row = idx >> 3, k8 = idx & 7;
            *(short8v*)&Ws[row * 72 + k8 * 8] =
                *(const short8v*)(Wop + (size_t)row * 256 + kc + k8 * 8);
        }
        __syncthreads();
        short8v a[2];
#pragma unroll
        for (int ks = 0; ks < 2; ++ks)
            a[ks] = *(const short8v*)&As[(rg * 16 + rA) * 72 + ks * 32 + k8r * 8];
#pragma unroll
        for (int ks = 0; ks < 2; ++ks)
#pragma unroll
            for (int ct = 0; ct < 4; ++ct) {
                short8v b = *(const short8v*)&Ws[(ch * 64 + ct * 16 + rA) * 72 + ks * 32 + k8r * 8];
                acc[ct] = __builtin_amdgcn_mfma_f32_16x16x32_bf16(a[ks], b, acc[ct], 0, 0, 0);
            }
        __syncthreads();
    }

    float s[4] = {0.f, 0.f, 0.f, 0.f}, q[4] = {0.f, 0.f, 0.f, 0.f};
#pragma unroll
    for (int ct = 0; ct < 4; ++ct) {
        int col = ch * 64 + ct * 16 + rA;
#pragma unroll
        for (int r = 0; r < 4; ++r) {
            int row = m0 + rg * 16 + g * 4 + r;
            float v = acc[ct][r] + bf2f(epi_b[(size_t)row * 256 + col]);
            acc[ct][r] = v;
            s[r] += v; q[r] += v * v;
        }
    }
#pragma unroll
    for (int off = 8; off; off >>= 1)
#pragma unroll
        for (int r = 0; r < 4; ++r) {
            s[r] += __shfl_xor(s[r], off);
            q[r] += __shfl_xor(q[r], off);
        }
    if (rA == 0) {
#pragma unroll
        for (int r = 0; r < 4; ++r) {
            part[rg][ch][g][r][0] = s[r];
            part[rg][ch][g][r][1] = q[r];
        }
    }
    __syncthreads();
    float mu[4], rs[4];
#pragma unroll
    for (int r = 0; r < 4; ++r) {
        float S = part[rg][0][g][r][0] + part[rg][1][g][r][0]
                + part[rg][2][g][r][0] + part[rg][3][g][r][0];
        float Q = part[rg][0][g][r][1] + part[rg][1][g][r][1]
                + part[rg][2][g][r][1] + part[rg][3][g][r][1];
        mu[r] = S * (1.f / 256.f);
        rs[r] = rsqrtf(Q * (1.f / 256.f) - mu[r] * mu[r] + 1e-5f);
    }
#pragma unroll
    for (int ct = 0; ct < 4; ++ct) {
        int col = ch * 64 + ct * 16 + rA;
        float gg = g2[col], bv = b2[col];
#pragma unroll
        for (int r = 0; r < 4; ++r) {
            int row = m0 + rg * 16 + g * 4 + r;
            size_t o = (size_t)row * 256 + col;
            epi_b[o] = f2bf(acc[ct][r]);
            ffin[o] = f2bf((acc[ct][r] - mu[r]) * rs[r] * gg + bv);
        }
    }
}

// ---------------------------------------------------------------------------
// K6: FF2 + residual(bf16) + final E->32 projection + transposed store.
// 32-row tile, 512 threads / 8 waves, BK=64, pitch-72.  (unchanged, passing)
// ---------------------------------------------------------------------------
__global__ __launch_bounds__(512) void ff2_final_kernel(
    const unsigned short* __restrict__ ffh, const unsigned short* __restrict__ W2,
    const unsigned short* __restrict__ epi_b, const float* __restrict__ w_out,
    float* __restrict__ out)
{
    __shared__ unsigned short As[32 * 72];
    __shared__ unsigned short Ws[256 * 72];
    __shared__ unsigned short Ts[32 * 264];

    int tid = threadIdx.x, lane = tid & 63, wv = tid >> 6;
    int m0 = blockIdx.x * 32;
    int rA = lane & 15, k8r = lane >> 4, g = lane >> 4;
    int rg = wv & 1, ch = wv >> 1;

    f32x4 acc[4];
#pragma unroll
    for (int ct = 0; ct < 4; ++ct)
#pragma unroll
        for (int r = 0; r < 4; ++r) acc[ct][r] = 0.f;

    for (int kc = 0; kc < 512; kc += 64) {
        if (tid < 256) {
            int row = tid >> 3, k8 = tid & 7;
            *(short8v*)&As[row * 72 + k8 * 8] =
                *(const short8v*)(ffh + (size_t)(m0 + row) * 512 + kc + k8 * 8);
        }
#pragma unroll
        for (int t = 0; t < 4; ++t) {
            int idx = t * 512 + tid;
            int row = idx >> 3, k8 = idx & 7;
            *(short8v*)&Ws[row * 72 + k8 * 8] =
                *(const short8v*)(W2 + (size_t)row * 512 + kc + k8 * 8);
        }
        __syncthreads();
        short8v a[2];
#pragma unroll
        for (int ks = 0; ks < 2; ++ks)
            a[ks] = *(const short8v*)&As[(rg * 16 + rA) * 72 + ks * 32 + k8r * 8];
#pragma unroll
        for (int ks = 0; ks < 2; ++ks)
#pragma unroll
            for (int ct = 0; ct < 4; ++ct) {
                short8v b = *(const short8v*)&Ws[(ch * 64 + ct * 16 + rA) * 72 + ks * 32 + k8r * 8];
                acc[ct] = __builtin_amdgcn_mfma_f32_16x16x32_bf16(a[ks], b, acc[ct], 0, 0, 0);
            }
        __syncthreads();
    }

#pragma unroll
    for (int ct = 0; ct < 4; ++ct) {
        int col = ch * 64 + ct * 16 + rA;
#pragma unroll
        for (int r = 0; r < 4; ++r) {
            int lrow = rg * 16 + g * 4 + r;
            float v = acc[ct][r] + bf2f(epi_b[(size_t)(m0 + lrow) * 256 + col]);
            Ts[lrow * 264 + col] = f2bf(v);
        }
    }
    __syncthreads();

    int bn = m0 >> 10, l0 = m0 & 1023;
    int bb = bn >> 2, nn = bn & 3;

    if (wv < 4) {
        int rw = wv & 1, cw = wv >> 1;
        f32x4 a2;
#pragma unroll
        for (int r = 0; r < 4; ++r) a2[r] = 0.f;
#pragma unroll
        for (int ks = 0; ks < 8; ++ks) {
            short8v af = *(const short8v*)&Ts[(rw * 16 + rA) * 264 + ks * 32 + k8r * 8];
            const float* wp = w_out + (cw * 16 + rA) * 256 + ks * 32 + k8r * 8;
            float4 w0 = *(const float4*)wp;
            float4 w1 = *(const float4*)(wp + 4);
            short8v bf;
            bf[0] = (short)f2bf(w0.x); bf[1] = (short)f2bf(w0.y);
            bf[2] = (short)f2bf(w0.z); bf[3] = (short)f2bf(w0.w);
            bf[4] = (short)f2bf(w1.x); bf[5] = (short)f2bf(w1.y);
            bf[6] = (short)f2bf(w1.z); bf[7] = (short)f2bf(w1.w);
            a2 = __builtin_amdgcn_mfma_f32_16x16x32_bf16(af, bf, a2, 0, 0, 0);
        }
        int c = cw * 16 + rA;
        int l = l0 + rw * 16 + g * 4;
        float4 st; st.x = a2[0]; st.y = a2[1]; st.z = a2[2]; st.w = a2[3];
        *(float4*)(out + ((size_t)(bb * 32 + c) * 4 + nn) * 1024 + l) = st;
    }
}

// ---------------------------------------------------------------------------
extern "C" void kernel_launch(void* const* d_in, const int* in_sizes, int n_in,
                              void* d_out, int out_size, void* d_ws, size_t ws_size,
                              hipStream_t stream) {
    const float* x_lf       = (const float*)d_in[0];
    const float* x_hf       = (const float*)d_in[1];
    const float* w_in       = (const float*)d_in[2];
    const float* w_qk       = (const float*)d_in[3];
    const float* ln_g       = (const float*)d_in[4];
    const float* ln_b       = (const float*)d_in[5];
    const float* in_proj_w  = (const float*)d_in[6];
    const float* out_proj_w = (const float*)d_in[7];
    const float* ln2_g      = (const float*)d_in[8];
    const float* ln2_b      = (const float*)d_in[9];
    const float* ff_w1      = (const float*)d_in[10];
    const float* ff_w2      = (const float*)d_in[11];
    const float* w_out      = (const float*)d_in[12];
    float* out = (float*)d_out;

    char* w = (char*)d_ws;
    unsigned short* epi_b  = (unsigned short*)(w);                // 4 MB bf16
    unsigned short* Qb     = (unsigned short*)(w + (4u  << 20));  // 4 MB bf16
    unsigned short* Kb     = (unsigned short*)(w + (8u  << 20));
    unsigned short* Vb     = (unsigned short*)(w + (12u << 20));
    unsigned short* q_b    = (unsigned short*)(w + (16u << 20));
    unsigned short* k_b    = (unsigned short*)(w + (20u << 20));
    unsigned short* kv_b   = (unsigned short*)(w + (24u << 20));
    unsigned short* ctx_b  = (unsigned short*)(w + (28u << 20));
    unsigned short* ffin_b = (unsigned short*)(w + (32u << 20));
    unsigned short* ffh_b  = (unsigned short*)(w + (36u << 20));  // 8 MB
    unsigned short* wqkv_b = (unsigned short*)(w + (44u << 20));
    unsigned short* wop_b  = (unsigned short*)(w + (45u << 20));
    unsigned short* wff1_b = (unsigned short*)(w + (46u << 20));
    unsigned short* wff2_b = (unsigned short*)(w + (47u << 20));

    // 1. gather + input proj + dual LN + weight conversion  [256 blk x 512]
    embed_conv_kernel<<<256, 512, 0, stream>>>(
        x_lf, x_hf, w_in, w_qk, ln_g, ln_b, epi_b, kv_b, q_b, k_b,
        in_proj_w, out_proj_w, ff_w1, ff_w2, wqkv_b, wop_b, wff1_b, wff2_b);
    // 2. QKV projection -> bf16 (bn,h,l,d)   [768 blocks, BK=64]
    gemm_mfma64<1, false><<<dim3(128, 2, 3), 256, 0, stream>>>(
        q_b, k_b, kv_b, wqkv_b, Qb, 256, 256);
    // 3. local-window attention (MFMA, 2 qv-rows/block) -> ctx bf16
    attn_mfma_kernel<<<1024, 256, 0, stream>>>(Qb, Kb, Vb, ctx_b);
    // 4. out_proj + residual(bf16) + LN2  [512 thr, BK=64]
    outproj_ln_kernel<<<256, 512, 0, stream>>>(ctx_b, wop_b, epi_b,
                                               ln2_g, ln2_b, ffin_b);
    // 5. FF1 + ReLU -> bf16 [8192,512]   [512 blocks, BK=64]
    gemm_mfma64<0, true><<<dim3(128, 4, 1), 256, 0, stream>>>(
        ffin_b, ffin_b, ffin_b, wff1_b, ffh_b, 256, 512);
    // 6. FF2 + residual(bf16) + final projection + transposed store
    ff2_final_kernel<<<256, 512, 0, stream>>>(ffh_b, wff2_b, epi_b, w_out, out);
}

// Round 18
// 65.804 us; speedup vs baseline: 1.7457x; 1.0267x over previous
//
#include <hip/hip_runtime.h>
#include <hip/hip_bf16.h>

// Problem constants: B=2,C=32,N=4,V=32,W=32,E=256,H=8,D=32,K_H=K_W=7
// L=1024, Bn=8, M=8192.  Internal row ordering: m = bn*1024 + l  (bn-major)
// Residual stream epi_b is bf16 (storage only; all arithmetic fp32).

typedef __attribute__((ext_vector_type(8))) short short8v;   // 8 bf16 (4 VGPR)
typedef __attribute__((ext_vector_type(4))) float f32x4;

__device__ __forceinline__ unsigned short f2bf(float x) {
    union { float f; unsigned u; } c; c.f = x;
    unsigned r = c.u + 0x7FFFu + ((c.u >> 16) & 1u);
    return (unsigned short)(r >> 16);
}
__device__ __forceinline__ float bf2f(short b) {
    union { unsigned u; float f; } c;
    c.u = ((unsigned)(unsigned short)b) << 16;
    return c.f;
}

// ---------------------------------------------------------------------------
// K1: 256 blocks x 512 threads.  32-row gather + input proj (MFMA) + dual LN.
// Residual stream stored bf16.  Weight-conversion tail: 1 float4/thread.
// (unchanged, passing)
// ---------------------------------------------------------------------------
__global__ __launch_bounds__(512) void embed_conv_kernel(
    const float* __restrict__ x_lf, const float* __restrict__ x_hf,
    const float* __restrict__ w_in, const float* __restrict__ w_qk,
    const float* __restrict__ ln_g, const float* __restrict__ ln_b,
    unsigned short* __restrict__ epi_b, unsigned short* __restrict__ kv_b,
    unsigned short* __restrict__ q_b, unsigned short* __restrict__ k_b,
    const float* __restrict__ wqkv, const float* __restrict__ wop,
    const float* __restrict__ wff1, const float* __restrict__ wff2,
    unsigned short* __restrict__ o1, unsigned short* __restrict__ o2,
    unsigned short* __restrict__ o3, unsigned short* __restrict__ o4)
{
    __shared__ float xs[2][32][36];
    __shared__ float part[2][2][2][4][4][2];  // [p][rg][chh][g][r][{s,q}]

    int tid = threadIdx.x;
    int m0 = blockIdx.x * 32;
    int bn = m0 >> 10, l0 = m0 & 1023;
    int bb = bn >> 2, nn = bn & 3;

    {
        int t = tid >> 8, rem = tid & 255;
        int c = rem >> 3, i0 = (rem & 7) * 4;
        size_t base = (size_t)bb * 131072 + (size_t)c * 4096 + nn * 1024 + l0 + i0;
        const float* src = t ? x_hf : x_lf;
        *(float4*)&xs[t][c][i0] = *(const float4*)(src + base);
    }
    __syncthreads();

    int lane = tid & 63, wv = tid >> 6;
    int rA = lane & 15, k8r = lane >> 4, g = k8r, k0 = k8r * 8;
    int p = wv >> 2, rg = (wv >> 1) & 1, chh = wv & 1;
    const float* W = p ? w_qk : w_in;

    short8v afrag;
#pragma unroll
    for (int j = 0; j < 8; ++j)
        afrag[j] = (short)f2bf(xs[p][k0 + j][rg * 16 + rA]);

    f32x4 acc[8];
#pragma unroll
    for (int ct = 0; ct < 8; ++ct)
#pragma unroll
        for (int r = 0; r < 4; ++r) acc[ct][r] = 0.f;

#pragma unroll
    for (int ct = 0; ct < 8; ++ct) {
        const float* wp = W + ((chh * 8 + ct) * 16 + rA) * 32 + k0;
        float4 w0 = *(const float4*)wp;
        float4 w1 = *(const float4*)(wp + 4);
        short8v bfrag;
        bfrag[0] = (short)f2bf(w0.x); bfrag[1] = (short)f2bf(w0.y);
        bfrag[2] = (short)f2bf(w0.z); bfrag[3] = (short)f2bf(w0.w);
        bfrag[4] = (short)f2bf(w1.x); bfrag[5] = (short)f2bf(w1.y);
        bfrag[6] = (short)f2bf(w1.z); bfrag[7] = (short)f2bf(w1.w);
        acc[ct] = __builtin_amdgcn_mfma_f32_16x16x32_bf16(afrag, bfrag, acc[ct], 0, 0, 0);
    }

    float s[4] = {0.f, 0.f, 0.f, 0.f}, q[4] = {0.f, 0.f, 0.f, 0.f};
#pragma unroll
    for (int ct = 0; ct < 8; ++ct)
#pragma unroll
        for (int r = 0; r < 4; ++r) {
            float v = acc[ct][r];
            s[r] += v; q[r] += v * v;
        }
#pragma unroll
    for (int off = 8; off; off >>= 1)
#pragma unroll
        for (int r = 0; r < 4; ++r) {
            s[r] += __shfl_xor(s[r], off);
            q[r] += __shfl_xor(q[r], off);
        }
    if (rA == 0) {
#pragma unroll
        for (int r = 0; r < 4; ++r) {
            part[p][rg][chh][g][r][0] = s[r];
            part[p][rg][chh][g][r][1] = q[r];
        }
    }
    __syncthreads();
    float mu[4], rs[4];
#pragma unroll
    for (int r = 0; r < 4; ++r) {
        float S = part[p][rg][0][g][r][0] + part[p][rg][1][g][r][0];
        float Q = part[p][rg][0][g][r][1] + part[p][rg][1][g][r][1];
        mu[r] = S * (1.f / 256.f);
        rs[r] = rsqrtf(Q * (1.f / 256.f) - mu[r] * mu[r] + 1e-5f);
    }

#pragma unroll
    for (int ct = 0; ct < 8; ++ct) {
        int col = (chh * 8 + ct) * 16 + rA;
        float gg = ln_g[col], bv = ln_b[col];
#pragma unroll
        for (int r = 0; r < 4; ++r) {
            int row = m0 + rg * 16 + g * 4 + r;
            float v = acc[ct][r];
            float lnv = (v - mu[r]) * rs[r] * gg + bv;
            size_t o = (size_t)row * 256 + col;
            if (p == 0) {
                epi_b[o] = f2bf(v);
                q_b[o] = f2bf(lnv);
            } else {
                kv_b[o] = f2bf(v);
                k_b[o] = f2bf(lnv);
            }
        }
    }

    // ---- weight conversion tail: 131072 float4s = 1 per thread ----
    {
        int i4 = blockIdx.x * 512 + tid;
        const float* src; unsigned short* dst; int off;
        if (i4 < 49152)      { src = wqkv; dst = o1; off = i4 * 4; }
        else if (i4 < 65536) { src = wop;  dst = o2; off = (i4 - 49152) * 4; }
        else if (i4 < 98304) { src = wff1; dst = o3; off = (i4 - 65536) * 4; }
        else                 { src = wff2; dst = o4; off = (i4 - 98304) * 4; }
        float4 v = *(const float4*)(src + off);
        ushort4 u;
        u.x = f2bf(v.x); u.y = f2bf(v.y); u.z = f2bf(v.z); u.w = f2bf(v.w);
        *(ushort4*)(dst + off) = u;
    }
}

// ---------------------------------------------------------------------------
// K2: bf16 MFMA GEMM, 64x128 tile, 4 waves, BK=64.
// Staging via global_load_lds (16B/lane, wave-uniform LDS base, linear LDS).
// Bank conflicts on fragment reads handled by both-sides XOR swizzle:
// physical chunk p of row holds logical chunk p^(row&7); swizzle applied on
// the global SOURCE address at stage time and on the READ address.
// ---------------------------------------------------------------------------
template <int OUTMAP, bool RELU>
__global__ __launch_bounds__(256) void gemm_mfma64(
    const unsigned short* __restrict__ A0, const unsigned short* __restrict__ A1,
    const unsigned short* __restrict__ A2, const unsigned short* __restrict__ Wb,
    unsigned short* __restrict__ OUT, int K, int N)
{
    int z = blockIdx.z;
    const unsigned short* A = (z == 0) ? A0 : (z == 1) ? A1 : A2;
    const unsigned short* W = Wb + (size_t)z * 65536;

    __shared__ unsigned short As[64 * 64];     // linear, 8 chunks(16B) per row
    __shared__ unsigned short Ws[128 * 64];

    int tid = threadIdx.x;
    int lane = tid & 63, wid = tid >> 6;
    int wm = wid >> 1, wn = wid & 1;
    int m0 = blockIdx.x * 64, n0 = blockIdx.y * 128;

    f32x4 acc[2][4];
#pragma unroll
    for (int i = 0; i < 2; ++i)
#pragma unroll
        for (int j = 0; j < 4; ++j)
#pragma unroll
            for (int r = 0; r < 4; ++r) acc[i][j][r] = 0.f;

    int rA = lane & 15, k8r = lane >> 4, g = lane >> 4;

    for (int kc = 0; kc < K; kc += 64) {
        // As: 512 16B-chunks = 8 wave-instructions (2 per wave)
#pragma unroll
        for (int t = 0; t < 2; ++t) {
            int cb = (t * 4 + wid) * 64;           // chunk base (wave-uniform)
            int c = cb + lane;
            int row = c >> 3, k8p = (c & 7) ^ (row & 7);
            __builtin_amdgcn_global_load_lds(
                (const unsigned int*)(A + (size_t)(m0 + row) * K + kc + k8p * 8),
                (unsigned int*)&As[cb * 8], 16, 0, 0);
        }
        // Ws: 1024 chunks = 16 wave-instructions (4 per wave)
#pragma unroll
        for (int t = 0; t < 4; ++t) {
            int cb = (t * 4 + wid) * 64;
            int c = cb + lane;
            int row = c >> 3, k8p = (c & 7) ^ (row & 7);
            __builtin_amdgcn_global_load_lds(
                (const unsigned int*)(W + (size_t)(n0 + row) * K + kc + k8p * 8),
                (unsigned int*)&Ws[cb * 8], 16, 0, 0);
        }
        __syncthreads();   // drains vmcnt (global_load_lds) before reads

        short8v a[2][2], b[2][4];
#pragma unroll
        for (int ks = 0; ks < 2; ++ks) {
#pragma unroll
            for (int mi = 0; mi < 2; ++mi) {
                int row = wm * 32 + mi * 16 + rA;
                int ch = (ks * 4 + k8r) ^ (row & 7);
                a[ks][mi] = *(const short8v*)&As[row * 64 + ch * 8];
            }
#pragma unroll
            for (int ni = 0; ni < 4; ++ni) {
                int row = wn * 64 + ni * 16 + rA;
                int ch = (ks * 4 + k8r) ^ (row & 7);
                b[ks][ni] = *(const short8v*)&Ws[row * 64 + ch * 8];
            }
        }
#pragma unroll
        for (int ks = 0; ks < 2; ++ks)
#pragma unroll
            for (int mi = 0; mi < 2; ++mi)
#pragma unroll
                for (int ni = 0; ni < 4; ++ni)
                    acc[mi][ni] = __builtin_amdgcn_mfma_f32_16x16x32_bf16(
                        a[ks][mi], b[ks][ni], acc[mi][ni], 0, 0, 0);
        __syncthreads();
    }

#pragma unroll
    for (int mi = 0; mi < 2; ++mi) {
#pragma unroll
        for (int ni = 0; ni < 4; ++ni) {
#pragma unroll
            for (int r = 0; r < 4; ++r) {
                int row = m0 + wm * 32 + mi * 16 + g * 4 + r;
                int col = n0 + wn * 64 + ni * 16 + rA;
                float v = acc[mi][ni][r];
                if (RELU) v = fmaxf(v, 0.f);
                if (OUTMAP == 0) {
                    OUT[(size_t)row * N + col] = f2bf(v);
                } else {
                    int l = row & 1023, bn = row >> 10;
                    int h = col >> 5, d = col & 31;
                    OUT[(size_t)z * 2097152 + ((bn * 8 + h) * 1024 + l) * 32 + d] = f2bf(v);
                }
            }
        }
    }
}

// ---------------------------------------------------------------------------
// K3: local-window attention, MFMA, 2 qv-rows per block (64 q, 8 kv-rows,
// 256 candidate keys).  Wave-local softmax; Ks/Ps union; deferred norm.
// (unchanged, passing)
// ---------------------------------------------------------------------------
__global__ __launch_bounds__(256) void attn_mfma_kernel(
    const unsigned short* __restrict__ Qb, const unsigned short* __restrict__ Kb,
    const unsigned short* __restrict__ Vb, unsigned short* __restrict__ ctx)
{
    int bh = blockIdx.x >> 4;       // bn*8 + h
    int qv0 = (blockIdx.x & 15) * 2;
    int tid = threadIdx.x, lane = tid & 63, mt = tid >> 6;
    int rA = lane & 15, k8r = lane >> 4, g = lane >> 4;

    __shared__ unsigned short KPs[64 * 264];   // Ks: [n<256][40] | Ps: [q<64][264]
    __shared__ unsigned short Vt[32 * 264];    // [d][n], pitch 264

    unsigned short* Ks = KPs;
    unsigned short* Ps = KPs;

    short8v qfrag;
    {
        int qq = mt * 16 + rA;
        int l = (qv0 + (qq >> 5)) * 32 + (qq & 31);
        qfrag = *(const short8v*)(Qb + ((size_t)bh * 1024 + l) * 32 + k8r * 8);
    }

#pragma unroll
    for (int it = 0; it < 4; ++it) {
        int idx = it * 256 + tid;
        int dv = idx >> 7, rem = idx & 127;
        int kw = rem >> 2, c8 = (rem & 3) * 8;
        int kvc = min(max(qv0 - 3 + dv, 0), 31);
        size_t base = ((size_t)bh * 1024 + kvc * 32 + kw) * 32 + c8;
        int n = dv * 32 + kw;
        *(short8v*)&Ks[n * 40 + c8] = *(const short8v*)(Kb + base);
        short8v v8 = *(const short8v*)(Vb + base);
#pragma unroll
        for (int j = 0; j < 8; ++j)
            Vt[(c8 + j) * 264 + n] = (unsigned short)v8[j];
    }
    __syncthreads();

    f32x4 sc[16];
#pragma unroll
    for (int ct = 0; ct < 16; ++ct)
#pragma unroll
        for (int r = 0; r < 4; ++r) sc[ct][r] = 0.f;
#pragma unroll
    for (int ct = 0; ct < 16; ++ct) {
        short8v b = *(const short8v*)&Ks[(ct * 16 + rA) * 40 + k8r * 8];
        sc[ct] = __builtin_amdgcn_mfma_f32_16x16x32_bf16(qfrag, b, sc[ct], 0, 0, 0);
    }
    __syncthreads();

    const float scale = 0.17677669529663687f;
    float mx[4] = {-1e30f, -1e30f, -1e30f, -1e30f};
#pragma unroll
    for (int ct = 0; ct < 16; ++ct) {
        int n = ct * 16 + rA;
        int dv = n >> 5, kw = n & 31;
        int kv = qv0 - 3 + dv;
        bool vok = (kv >= 0) && (kv < 32);
#pragma unroll
        for (int r = 0; r < 4; ++r) {
            int qq = mt * 16 + g * 4 + r;
            int v = qv0 + (qq >> 5), w = qq & 31;
            int djv = kv - v, djw = kw - w;
            bool ok = vok && (djv >= -3) && (djv <= 3) && (djw >= -3) && (djw <= 3);
            float s = ok ? sc[ct][r] * scale : -1e30f;
            sc[ct][r] = s;
            mx[r] = fmaxf(mx[r], s);
        }
    }
#pragma unroll
    for (int off = 8; off; off >>= 1)
#pragma unroll
        for (int r = 0; r < 4; ++r) mx[r] = fmaxf(mx[r], __shfl_xor(mx[r], off));

    float sm[4] = {0.f, 0.f, 0.f, 0.f};
#pragma unroll
    for (int ct = 0; ct < 16; ++ct)
#pragma unroll
        for (int r = 0; r < 4; ++r) {
            float e = __expf(sc[ct][r] - mx[r]);
            sc[ct][r] = e;
            sm[r] += e;
        }
#pragma unroll
    for (int off = 8; off; off >>= 1)
#pragma unroll
        for (int r = 0; r < 4; ++r) sm[r] += __shfl_xor(sm[r], off);
    float inv[4];
#pragma unroll
    for (int r = 0; r < 4; ++r) inv[r] = 1.f / sm[r];

#pragma unroll
    for (int ct = 0; ct < 16; ++ct) {
        int n = ct * 16 + rA;
#pragma unroll
        for (int r = 0; r < 4; ++r) {
            int q = mt * 16 + g * 4 + r;
            Ps[q * 264 + n] = f2bf(sc[ct][r]);
        }
    }
    __syncthreads();

    f32x4 o[2];
#pragma unroll
    for (int dt = 0; dt < 2; ++dt)
#pragma unroll
        for (int r = 0; r < 4; ++r) o[dt][r] = 0.f;
#pragma unroll
    for (int kb = 0; kb < 8; ++kb) {
        short8v pa = *(const short8v*)&Ps[(mt * 16 + rA) * 264 + kb * 32 + k8r * 8];
#pragma unroll
        for (int dt = 0; dt < 2; ++dt) {
            short8v vb = *(const short8v*)&Vt[(dt * 16 + rA) * 264 + kb * 32 + k8r * 8];
            o[dt] = __builtin_amdgcn_mfma_f32_16x16x32_bf16(pa, vb, o[dt], 0, 0, 0);
        }
    }

    {
        int bn = bh >> 3, h = bh & 7;
#pragma unroll
        for (int dt = 0; dt < 2; ++dt) {
            int d = dt * 16 + rA;
#pragma unroll
            for (int r = 0; r < 4; ++r) {
                int qq = mt * 16 + g * 4 + r;
                int l = (qv0 + (qq >> 5)) * 32 + (qq & 31);
                ctx[((size_t)bn * 1024 + l) * 256 + h * 32 + d] = f2bf(o[dt][r] * inv[r]);
            }
        }
    }
}

// ---------------------------------------------------------------------------
// K4: out_proj + residual(bf16) + LN2.  32-row tile, 512 threads / 8 waves,
// BK=64, pitch-72 LDS.  (unchanged, passing)
// ---------------------------------------------------------------------------
__global__ __launch_bounds__(512) void outproj_ln_kernel(
    const unsigned short* __restrict__ ctx, const unsigned short* __restrict__ Wop,
    unsigned short* __restrict__ epi_b, const float* __restrict__ g2,
    const float* __restrict__ b2, unsigned short* __restrict__ ffin)
{
    __shared__ unsigned short As[32 * 72];
    __shared__ unsigned short Ws[256 * 72];
    __shared__ float part[2][4][4][4][2];

    int tid = threadIdx.x, lane = tid & 63, wv = tid >> 6;
    int m0 = blockIdx.x * 32;
    int rA = lane & 15, k8r = lane >> 4, g = lane >> 4;
    int rg = wv & 1, ch = wv >> 1;

    f32x4 acc[4];
#pragma unroll
    for (int ct = 0; ct < 4; ++ct)
#pragma unroll
        for (int r = 0; r < 4; ++r) acc[ct][r] = 0.f;

    for (int kc = 0; kc < 256; kc += 64) {
        if (tid < 256) {
            int row = tid >> 3, k8 = tid & 7;
            *(short8v*)&As[row * 72 + k8 * 8] =
                *(const short8v*)(ctx + (size_t)(m0 + row) * 256 + kc + k8 * 8);
        }
#pragma unroll
        for (int t = 0; t < 4; ++t) {
            int idx = t * 512 + tid;
            int row = idx >> 3, k8 = idx & 7;
            *(short8v*)&Ws[row * 72 + k8 * 8] =
                *(const short8v*)(Wop + (size_t)row * 256 + kc + k8 * 8);
        }
        __syncthreads();
        short8v a[2];
#pragma unroll
        for (int ks = 0; ks < 2; ++ks)
            a[ks] = *(const short8v*)&As[(rg * 16 + rA) * 72 + ks * 32 + k8r * 8];
#pragma unroll
        for (int ks = 0; ks < 2; ++ks)
#pragma unroll
            for (int ct = 0; ct < 4; ++ct) {
                short8v b = *(const short8v*)&Ws[(ch * 64 + ct * 16 + rA) * 72 + ks * 32 + k8r * 8];
                acc[ct] = __builtin_amdgcn_mfma_f32_16x16x32_bf16(a[ks], b, acc[ct], 0, 0, 0);
            }
        __syncthreads();
    }

    float s[4] = {0.f, 0.f, 0.f, 0.f}, q[4] = {0.f, 0.f, 0.f, 0.f};
#pragma unroll
    for (int ct = 0; ct < 4; ++ct) {
        int col = ch * 64 + ct * 16 + rA;
#pragma unroll
        for (int r = 0; r < 4; ++r) {
            int row = m0 + rg * 16 + g * 4 + r;
            float v = acc[ct][r] + bf2f(epi_b[(size_t)row * 256 + col]);
            acc[ct][r] = v;
            s[r] += v; q[r] += v * v;
        }
    }
#pragma unroll
    for (int off = 8; off; off >>= 1)
#pragma unroll
        for (int r = 0; r < 4; ++r) {
            s[r] += __shfl_xor(s[r], off);
            q[r] += __shfl_xor(q[r], off);
        }
    if (rA == 0) {
#pragma unroll
        for (int r = 0; r < 4; ++r) {
            part[rg][ch][g][r][0] = s[r];
            part[rg][ch][g][r][1] = q[r];
        }
    }
    __syncthreads();
    float mu[4], rs[4];
#pragma unroll
    for (int r = 0; r < 4; ++r) {
        float S = part[rg][0][g][r][0] + part[rg][1][g][r][0]
                + part[rg][2][g][r][0] + part[rg][3][g][r][0];
        float Q = part[rg][0][g][r][1] + part[rg][1][g][r][1]
                + part[rg][2][g][r][1] + part[rg][3][g][r][1];
        mu[r] = S * (1.f / 256.f);
        rs[r] = rsqrtf(Q * (1.f / 256.f) - mu[r] * mu[r] + 1e-5f);
    }
#pragma unroll
    for (int ct = 0; ct < 4; ++ct) {
        int col = ch * 64 + ct * 16 + rA;
        float gg = g2[col], bv = b2[col];
#pragma unroll
        for (int r = 0; r < 4; ++r) {
            int row = m0 + rg * 16 + g * 4 + r;
            size_t o = (size_t)row * 256 + col;
            epi_b[o] = f2bf(acc[ct][r]);
            ffin[o] = f2bf((acc[ct][r] - mu[r]) * rs[r] * gg + bv);
        }
    }
}

// ---------------------------------------------------------------------------
// K6: FF2 + residual(bf16) + final E->32 projection + transposed store.
// 32-row tile, 512 threads / 8 waves, BK=64, pitch-72.  (unchanged, passing)
// ---------------------------------------------------------------------------
__global__ __launch_bounds__(512) void ff2_final_kernel(
    const unsigned short* __restrict__ ffh, const unsigned short* __restrict__ W2,
    const unsigned short* __restrict__ epi_b, const float* __restrict__ w_out,
    float* __restrict__ out)
{
    __shared__ unsigned short As[32 * 72];
    __shared__ unsigned short Ws[256 * 72];
    __shared__ unsigned short Ts[32 * 264];

    int tid = threadIdx.x, lane = tid & 63, wv = tid >> 6;
    int m0 = blockIdx.x * 32;
    int rA = lane & 15, k8r = lane >> 4, g = lane >> 4;
    int rg = wv & 1, ch = wv >> 1;

    f32x4 acc[4];
#pragma unroll
    for (int ct = 0; ct < 4; ++ct)
#pragma unroll
        for (int r = 0; r < 4; ++r) acc[ct][r] = 0.f;

    for (int kc = 0; kc < 512; kc += 64) {
        if (tid < 256) {
            int row = tid >> 3, k8 = tid & 7;
            *(short8v*)&As[row * 72 + k8 * 8] =
                *(const short8v*)(ffh + (size_t)(m0 + row) * 512 + kc + k8 * 8);
        }
#pragma unroll
        for (int t = 0; t < 4; ++t) {
            int idx = t * 512 + tid;
            int row = idx >> 3, k8 = idx & 7;
            *(short8v*)&Ws[row * 72 + k8 * 8] =
                *(const short8v*)(W2 + (size_t)row * 512 + kc + k8 * 8);
        }
        __syncthreads();
        short8v a[2];
#pragma unroll
        for (int ks = 0; ks < 2; ++ks)
            a[ks] = *(const short8v*)&As[(rg * 16 + rA) * 72 + ks * 32 + k8r * 8];
#pragma unroll
        for (int ks = 0; ks < 2; ++ks)
#pragma unroll
            for (int ct = 0; ct < 4; ++ct) {
                short8v b = *(const short8v*)&Ws[(ch * 64 + ct * 16 + rA) * 72 + ks * 32 + k8r * 8];
                acc[ct] = __builtin_amdgcn_mfma_f32_16x16x32_bf16(a[ks], b, acc[ct], 0, 0, 0);
            }
        __syncthreads();
    }

#pragma unroll
    for (int ct = 0; ct < 4; ++ct) {
        int col = ch * 64 + ct * 16 + rA;
#pragma unroll
        for (int r = 0; r < 4; ++r) {
            int lrow = rg * 16 + g * 4 + r;
            float v = acc[ct][r] + bf2f(epi_b[(size_t)(m0 + lrow) * 256 + col]);
            Ts[lrow * 264 + col] = f2bf(v);
        }
    }
    __syncthreads();

    int bn = m0 >> 10, l0 = m0 & 1023;
    int bb = bn >> 2, nn = bn & 3;

    if (wv < 4) {
        int rw = wv & 1, cw = wv >> 1;
        f32x4 a2;
#pragma unroll
        for (int r = 0; r < 4; ++r) a2[r] = 0.f;
#pragma unroll
        for (int ks = 0; ks < 8; ++ks) {
            short8v af = *(const short8v*)&Ts[(rw * 16 + rA) * 264 + ks * 32 + k8r * 8];
            const float* wp = w_out + (cw * 16 + rA) * 256 + ks * 32 + k8r * 8;
            float4 w0 = *(const float4*)wp;
            float4 w1 = *(const float4*)(wp + 4);
            short8v bf;
            bf[0] = (short)f2bf(w0.x); bf[1] = (short)f2bf(w0.y);
            bf[2] = (short)f2bf(w0.z); bf[3] = (short)f2bf(w0.w);
            bf[4] = (short)f2bf(w1.x); bf[5] = (short)f2bf(w1.y);
            bf[6] = (short)f2bf(w1.z); bf[7] = (short)f2bf(w1.w);
            a2 = __builtin_amdgcn_mfma_f32_16x16x32_bf16(af, bf, a2, 0, 0, 0);
        }
        int c = cw * 16 + rA;
        int l = l0 + rw * 16 + g * 4;
        float4 st; st.x = a2[0]; st.y = a2[1]; st.z = a2[2]; st.w = a2[3];
        *(float4*)(out + ((size_t)(bb * 32 + c) * 4 + nn) * 1024 + l) = st;
    }
}

// ---------------------------------------------------------------------------
extern "C" void kernel_launch(void* const* d_in, const int* in_sizes, int n_in,
                              void* d_out, int out_size, void* d_ws, size_t ws_size,
                              hipStream_t stream) {
    const float* x_lf       = (const float*)d_in[0];
    const float* x_hf       = (const float*)d_in[1];
    const float* w_in       = (const float*)d_in[2];
    const float* w_qk       = (const float*)d_in[3];
    const float* ln_g       = (const float*)d_in[4];
    const float* ln_b       = (const float*)d_in[5];
    const float* in_proj_w  = (const float*)d_in[6];
    const float* out_proj_w = (const float*)d_in[7];
    const float* ln2_g      = (const float*)d_in[8];
    const float* ln2_b      = (const float*)d_in[9];
    const float* ff_w1      = (const float*)d_in[10];
    const float* ff_w2      = (const float*)d_in[11];
    const float* w_out      = (const float*)d_in[12];
    float* out = (float*)d_out;

    char* w = (char*)d_ws;
    unsigned short* epi_b  = (unsigned short*)(w);                // 4 MB bf16
    unsigned short* Qb     = (unsigned short*)(w + (4u  << 20));  // 4 MB bf16
    unsigned short* Kb     = (unsigned short*)(w + (8u  << 20));
    unsigned short* Vb     = (unsigned short*)(w + (12u << 20));
    unsigned short* q_b    = (unsigned short*)(w + (16u << 20));
    unsigned short* k_b    = (unsigned short*)(w + (20u << 20));
    unsigned short* kv_b   = (unsigned short*)(w + (24u << 20));
    unsigned short* ctx_b  = (unsigned short*)(w + (28u << 20));
    unsigned short* ffin_b = (unsigned short*)(w + (32u << 20));
    unsigned short* ffh_b  = (unsigned short*)(w + (36u << 20));  // 8 MB
    unsigned short* wqkv_b = (unsigned short*)(w + (44u << 20));
    unsigned short* wop_b  = (unsigned short*)(w + (45u << 20));
    unsigned short* wff1_b = (unsigned short*)(w + (46u << 20));
    unsigned short* wff2_b = (unsigned short*)(w + (47u << 20));

    // 1. gather + input proj + dual LN + weight conversion  [256 blk x 512]
    embed_conv_kernel<<<256, 512, 0, stream>>>(
        x_lf, x_hf, w_in, w_qk, ln_g, ln_b, epi_b, kv_b, q_b, k_b,
        in_proj_w, out_proj_w, ff_w1, ff_w2, wqkv_b, wop_b, wff1_b, wff2_b);
    // 2. QKV projection -> bf16 (bn,h,l,d)   [768 blocks, BK=64, gload_lds]
    gemm_mfma64<1, false><<<dim3(128, 2, 3), 256, 0, stream>>>(
        q_b, k_b, kv_b, wqkv_b, Qb, 256, 256);
    // 3. local-window attention (MFMA, 2 qv-rows/block) -> ctx bf16
    attn_mfma_kernel<<<1024, 256, 0, stream>>>(Qb, Kb, Vb, ctx_b);
    // 4. out_proj + residual(bf16) + LN2  [512 thr, BK=64]
    outproj_ln_kernel<<<256, 512, 0, stream>>>(ctx_b, wop_b, epi_b,
                                               ln2_g, ln2_b, ffin_b);
    // 5. FF1 + ReLU -> bf16 [8192,512]   [512 blocks, BK=64, gload_lds]
    gemm_mfma64<0, true><<<dim3(128, 4, 1), 256, 0, stream>>>(
        ffin_b, ffin_b, ffin_b, wff1_b, ffh_b, 256, 512);
    // 6. FF2 + residual(bf16) + final projection + transposed store
    ff2_final_kernel<<<256, 512, 0, stream>>>(ffh_b, wff2_b, epi_b, w_out, out);
}

// Round 19
// 64.240 us; speedup vs baseline: 1.7882x; 1.0244x over previous
//
#include <hip/hip_runtime.h>
#include <hip/hip_bf16.h>

// Problem constants: B=2,C=32,N=4,V=32,W=32,E=256,H=8,D=32,K_H=K_W=7
// L=1024, Bn=8, M=8192.  Internal row ordering: m = bn*1024 + l  (bn-major)
// Residual stream epi_b is bf16 (storage only; all arithmetic fp32).

typedef __attribute__((ext_vector_type(8))) short short8v;   // 8 bf16 (4 VGPR)
typedef __attribute__((ext_vector_type(4))) float f32x4;

__device__ __forceinline__ unsigned short f2bf(float x) {
    union { float f; unsigned u; } c; c.f = x;
    unsigned r = c.u + 0x7FFFu + ((c.u >> 16) & 1u);
    return (unsigned short)(r >> 16);
}
__device__ __forceinline__ float bf2f(short b) {
    union { unsigned u; float f; } c;
    c.u = ((unsigned)(unsigned short)b) << 16;
    return c.f;
}

// ---------------------------------------------------------------------------
// K1: 256 blocks x 512 threads.  32-row gather + input proj (MFMA) + dual LN.
// (unchanged, passing)
// ---------------------------------------------------------------------------
__global__ __launch_bounds__(512) void embed_conv_kernel(
    const float* __restrict__ x_lf, const float* __restrict__ x_hf,
    const float* __restrict__ w_in, const float* __restrict__ w_qk,
    const float* __restrict__ ln_g, const float* __restrict__ ln_b,
    unsigned short* __restrict__ epi_b, unsigned short* __restrict__ kv_b,
    unsigned short* __restrict__ q_b, unsigned short* __restrict__ k_b,
    const float* __restrict__ wqkv, const float* __restrict__ wop,
    const float* __restrict__ wff1, const float* __restrict__ wff2,
    unsigned short* __restrict__ o1, unsigned short* __restrict__ o2,
    unsigned short* __restrict__ o3, unsigned short* __restrict__ o4)
{
    __shared__ float xs[2][32][36];
    __shared__ float part[2][2][2][4][4][2];  // [p][rg][chh][g][r][{s,q}]

    int tid = threadIdx.x;
    int m0 = blockIdx.x * 32;
    int bn = m0 >> 10, l0 = m0 & 1023;
    int bb = bn >> 2, nn = bn & 3;

    {
        int t = tid >> 8, rem = tid & 255;
        int c = rem >> 3, i0 = (rem & 7) * 4;
        size_t base = (size_t)bb * 131072 + (size_t)c * 4096 + nn * 1024 + l0 + i0;
        const float* src = t ? x_hf : x_lf;
        *(float4*)&xs[t][c][i0] = *(const float4*)(src + base);
    }
    __syncthreads();

    int lane = tid & 63, wv = tid >> 6;
    int rA = lane & 15, k8r = lane >> 4, g = k8r, k0 = k8r * 8;
    int p = wv >> 2, rg = (wv >> 1) & 1, chh = wv & 1;
    const float* W = p ? w_qk : w_in;

    short8v afrag;
#pragma unroll
    for (int j = 0; j < 8; ++j)
        afrag[j] = (short)f2bf(xs[p][k0 + j][rg * 16 + rA]);

    f32x4 acc[8];
#pragma unroll
    for (int ct = 0; ct < 8; ++ct)
#pragma unroll
        for (int r = 0; r < 4; ++r) acc[ct][r] = 0.f;

#pragma unroll
    for (int ct = 0; ct < 8; ++ct) {
        const float* wp = W + ((chh * 8 + ct) * 16 + rA) * 32 + k0;
        float4 w0 = *(const float4*)wp;
        float4 w1 = *(const float4*)(wp + 4);
        short8v bfrag;
        bfrag[0] = (short)f2bf(w0.x); bfrag[1] = (short)f2bf(w0.y);
        bfrag[2] = (short)f2bf(w0.z); bfrag[3] = (short)f2bf(w0.w);
        bfrag[4] = (short)f2bf(w1.x); bfrag[5] = (short)f2bf(w1.y);
        bfrag[6] = (short)f2bf(w1.z); bfrag[7] = (short)f2bf(w1.w);
        acc[ct] = __builtin_amdgcn_mfma_f32_16x16x32_bf16(afrag, bfrag, acc[ct], 0, 0, 0);
    }

    float s[4] = {0.f, 0.f, 0.f, 0.f}, q[4] = {0.f, 0.f, 0.f, 0.f};
#pragma unroll
    for (int ct = 0; ct < 8; ++ct)
#pragma unroll
        for (int r = 0; r < 4; ++r) {
            float v = acc[ct][r];
            s[r] += v; q[r] += v * v;
        }
#pragma unroll
    for (int off = 8; off; off >>= 1)
#pragma unroll
        for (int r = 0; r < 4; ++r) {
            s[r] += __shfl_xor(s[r], off);
            q[r] += __shfl_xor(q[r], off);
        }
    if (rA == 0) {
#pragma unroll
        for (int r = 0; r < 4; ++r) {
            part[p][rg][chh][g][r][0] = s[r];
            part[p][rg][chh][g][r][1] = q[r];
        }
    }
    __syncthreads();
    float mu[4], rs[4];
#pragma unroll
    for (int r = 0; r < 4; ++r) {
        float S = part[p][rg][0][g][r][0] + part[p][rg][1][g][r][0];
        float Q = part[p][rg][0][g][r][1] + part[p][rg][1][g][r][1];
        mu[r] = S * (1.f / 256.f);
        rs[r] = rsqrtf(Q * (1.f / 256.f) - mu[r] * mu[r] + 1e-5f);
    }

#pragma unroll
    for (int ct = 0; ct < 8; ++ct) {
        int col = (chh * 8 + ct) * 16 + rA;
        float gg = ln_g[col], bv = ln_b[col];
#pragma unroll
        for (int r = 0; r < 4; ++r) {
            int row = m0 + rg * 16 + g * 4 + r;
            float v = acc[ct][r];
            float lnv = (v - mu[r]) * rs[r] * gg + bv;
            size_t o = (size_t)row * 256 + col;
            if (p == 0) {
                epi_b[o] = f2bf(v);
                q_b[o] = f2bf(lnv);
            } else {
                kv_b[o] = f2bf(v);
                k_b[o] = f2bf(lnv);
            }
        }
    }

    // ---- weight conversion tail: 131072 float4s = 1 per thread ----
    {
        int i4 = blockIdx.x * 512 + tid;
        const float* src; unsigned short* dst; int off;
        if (i4 < 49152)      { src = wqkv; dst = o1; off = i4 * 4; }
        else if (i4 < 65536) { src = wop;  dst = o2; off = (i4 - 49152) * 4; }
        else if (i4 < 98304) { src = wff1; dst = o3; off = (i4 - 65536) * 4; }
        else                 { src = wff2; dst = o4; off = (i4 - 98304) * 4; }
        float4 v = *(const float4*)(src + off);
        ushort4 u;
        u.x = f2bf(v.x); u.y = f2bf(v.y); u.z = f2bf(v.z); u.w = f2bf(v.w);
        *(ushort4*)(dst + off) = u;
    }
}

// ---------------------------------------------------------------------------
// K2: bf16 MFMA GEMM, 64x128 tile, 4 waves, BK=64, global_load_lds staging,
// linear pitch-64 LDS, both-sides XOR chunk swizzle.  (unchanged, passing)
// ---------------------------------------------------------------------------
template <int OUTMAP, bool RELU>
__global__ __launch_bounds__(256) void gemm_mfma64(
    const unsigned short* __restrict__ A0, const unsigned short* __restrict__ A1,
    const unsigned short* __restrict__ A2, const unsigned short* __restrict__ Wb,
    unsigned short* __restrict__ OUT, int K, int N)
{
    int z = blockIdx.z;
    const unsigned short* A = (z == 0) ? A0 : (z == 1) ? A1 : A2;
    const unsigned short* W = Wb + (size_t)z * 65536;

    __shared__ unsigned short As[64 * 64];
    __shared__ unsigned short Ws[128 * 64];

    int tid = threadIdx.x;
    int lane = tid & 63, wid = tid >> 6;
    int wm = wid >> 1, wn = wid & 1;
    int m0 = blockIdx.x * 64, n0 = blockIdx.y * 128;

    f32x4 acc[2][4];
#pragma unroll
    for (int i = 0; i < 2; ++i)
#pragma unroll
        for (int j = 0; j < 4; ++j)
#pragma unroll
            for (int r = 0; r < 4; ++r) acc[i][j][r] = 0.f;

    int rA = lane & 15, k8r = lane >> 4, g = lane >> 4;

    for (int kc = 0; kc < K; kc += 64) {
#pragma unroll
        for (int t = 0; t < 2; ++t) {
            int cb = (t * 4 + wid) * 64;
            int c = cb + lane;
            int row = c >> 3, k8p = (c & 7) ^ (row & 7);
            __builtin_amdgcn_global_load_lds(
                (const unsigned int*)(A + (size_t)(m0 + row) * K + kc + k8p * 8),
                (unsigned int*)&As[cb * 8], 16, 0, 0);
        }
#pragma unroll
        for (int t = 0; t < 4; ++t) {
            int cb = (t * 4 + wid) * 64;
            int c = cb + lane;
            int row = c >> 3, k8p = (c & 7) ^ (row & 7);
            __builtin_amdgcn_global_load_lds(
                (const unsigned int*)(W + (size_t)(n0 + row) * K + kc + k8p * 8),
                (unsigned int*)&Ws[cb * 8], 16, 0, 0);
        }
        __syncthreads();

        short8v a[2][2], b[2][4];
#pragma unroll
        for (int ks = 0; ks < 2; ++ks) {
#pragma unroll
            for (int mi = 0; mi < 2; ++mi) {
                int row = wm * 32 + mi * 16 + rA;
                int cx = (ks * 4 + k8r) ^ (row & 7);
                a[ks][mi] = *(const short8v*)&As[row * 64 + cx * 8];
            }
#pragma unroll
            for (int ni = 0; ni < 4; ++ni) {
                int row = wn * 64 + ni * 16 + rA;
                int cx = (ks * 4 + k8r) ^ (row & 7);
                b[ks][ni] = *(const short8v*)&Ws[row * 64 + cx * 8];
            }
        }
#pragma unroll
        for (int ks = 0; ks < 2; ++ks)
#pragma unroll
            for (int mi = 0; mi < 2; ++mi)
#pragma unroll
                for (int ni = 0; ni < 4; ++ni)
                    acc[mi][ni] = __builtin_amdgcn_mfma_f32_16x16x32_bf16(
                        a[ks][mi], b[ks][ni], acc[mi][ni], 0, 0, 0);
        __syncthreads();
    }

#pragma unroll
    for (int mi = 0; mi < 2; ++mi) {
#pragma unroll
        for (int ni = 0; ni < 4; ++ni) {
#pragma unroll
            for (int r = 0; r < 4; ++r) {
                int row = m0 + wm * 32 + mi * 16 + g * 4 + r;
                int col = n0 + wn * 64 + ni * 16 + rA;
                float v = acc[mi][ni][r];
                if (RELU) v = fmaxf(v, 0.f);
                if (OUTMAP == 0) {
                    OUT[(size_t)row * N + col] = f2bf(v);
                } else {
                    int l = row & 1023, bn = row >> 10;
                    int h = col >> 5, d = col & 31;
                    OUT[(size_t)z * 2097152 + ((bn * 8 + h) * 1024 + l) * 32 + d] = f2bf(v);
                }
            }
        }
    }
}

// ---------------------------------------------------------------------------
// K3: local-window attention, MFMA, 2 qv-rows per block.  (unchanged, passing)
// ---------------------------------------------------------------------------
__global__ __launch_bounds__(256) void attn_mfma_kernel(
    const unsigned short* __restrict__ Qb, const unsigned short* __restrict__ Kb,
    const unsigned short* __restrict__ Vb, unsigned short* __restrict__ ctx)
{
    int bh = blockIdx.x >> 4;       // bn*8 + h
    int qv0 = (blockIdx.x & 15) * 2;
    int tid = threadIdx.x, lane = tid & 63, mt = tid >> 6;
    int rA = lane & 15, k8r = lane >> 4, g = lane >> 4;

    __shared__ unsigned short KPs[64 * 264];   // Ks: [n<256][40] | Ps: [q<64][264]
    __shared__ unsigned short Vt[32 * 264];    // [d][n], pitch 264

    unsigned short* Ks = KPs;
    unsigned short* Ps = KPs;

    short8v qfrag;
    {
        int qq = mt * 16 + rA;
        int l = (qv0 + (qq >> 5)) * 32 + (qq & 31);
        qfrag = *(const short8v*)(Qb + ((size_t)bh * 1024 + l) * 32 + k8r * 8);
    }

#pragma unroll
    for (int it = 0; it < 4; ++it) {
        int idx = it * 256 + tid;
        int dv = idx >> 7, rem = idx & 127;
        int kw = rem >> 2, c8 = (rem & 3) * 8;
        int kvc = min(max(qv0 - 3 + dv, 0), 31);
        size_t base = ((size_t)bh * 1024 + kvc * 32 + kw) * 32 + c8;
        int n = dv * 32 + kw;
        *(short8v*)&Ks[n * 40 + c8] = *(const short8v*)(Kb + base);
        short8v v8 = *(const short8v*)(Vb + base);
#pragma unroll
        for (int j = 0; j < 8; ++j)
            Vt[(c8 + j) * 264 + n] = (unsigned short)v8[j];
    }
    __syncthreads();

    f32x4 sc[16];
#pragma unroll
    for (int ct = 0; ct < 16; ++ct)
#pragma unroll
        for (int r = 0; r < 4; ++r) sc[ct][r] = 0.f;
#pragma unroll
    for (int ct = 0; ct < 16; ++ct) {
        short8v b = *(const short8v*)&Ks[(ct * 16 + rA) * 40 + k8r * 8];
        sc[ct] = __builtin_amdgcn_mfma_f32_16x16x32_bf16(qfrag, b, sc[ct], 0, 0, 0);
    }
    __syncthreads();

    const float scale = 0.17677669529663687f;
    float mx[4] = {-1e30f, -1e30f, -1e30f, -1e30f};
#pragma unroll
    for (int ct = 0; ct < 16; ++ct) {
        int n = ct * 16 + rA;
        int dv = n >> 5, kw = n & 31;
        int kv = qv0 - 3 + dv;
        bool vok = (kv >= 0) && (kv < 32);
#pragma unroll
        for (int r = 0; r < 4; ++r) {
            int qq = mt * 16 + g * 4 + r;
            int v = qv0 + (qq >> 5), w = qq & 31;
            int djv = kv - v, djw = kw - w;
            bool ok = vok && (djv >= -3) && (djv <= 3) && (djw >= -3) && (djw <= 3);
            float s = ok ? sc[ct][r] * scale : -1e30f;
            sc[ct][r] = s;
            mx[r] = fmaxf(mx[r], s);
        }
    }
#pragma unroll
    for (int off = 8; off; off >>= 1)
#pragma unroll
        for (int r = 0; r < 4; ++r) mx[r] = fmaxf(mx[r], __shfl_xor(mx[r], off));

    float sm[4] = {0.f, 0.f, 0.f, 0.f};
#pragma unroll
    for (int ct = 0; ct < 16; ++ct)
#pragma unroll
        for (int r = 0; r < 4; ++r) {
            float e = __expf(sc[ct][r] - mx[r]);
            sc[ct][r] = e;
            sm[r] += e;
        }
#pragma unroll
    for (int off = 8; off; off >>= 1)
#pragma unroll
        for (int r = 0; r < 4; ++r) sm[r] += __shfl_xor(sm[r], off);
    float inv[4];
#pragma unroll
    for (int r = 0; r < 4; ++r) inv[r] = 1.f / sm[r];

#pragma unroll
    for (int ct = 0; ct < 16; ++ct) {
        int n = ct * 16 + rA;
#pragma unroll
        for (int r = 0; r < 4; ++r) {
            int q = mt * 16 + g * 4 + r;
            Ps[q * 264 + n] = f2bf(sc[ct][r]);
        }
    }
    __syncthreads();

    f32x4 o[2];
#pragma unroll
    for (int dt = 0; dt < 2; ++dt)
#pragma unroll
        for (int r = 0; r < 4; ++r) o[dt][r] = 0.f;
#pragma unroll
    for (int kb = 0; kb < 8; ++kb) {
        short8v pa = *(const short8v*)&Ps[(mt * 16 + rA) * 264 + kb * 32 + k8r * 8];
#pragma unroll
        for (int dt = 0; dt < 2; ++dt) {
            short8v vb = *(const short8v*)&Vt[(dt * 16 + rA) * 264 + kb * 32 + k8r * 8];
            o[dt] = __builtin_amdgcn_mfma_f32_16x16x32_bf16(pa, vb, o[dt], 0, 0, 0);
        }
    }

    {
        int bn = bh >> 3, h = bh & 7;
#pragma unroll
        for (int dt = 0; dt < 2; ++dt) {
            int d = dt * 16 + rA;
#pragma unroll
            for (int r = 0; r < 4; ++r) {
                int qq = mt * 16 + g * 4 + r;
                int l = (qv0 + (qq >> 5)) * 32 + (qq & 31);
                ctx[((size_t)bn * 1024 + l) * 256 + h * 32 + d] = f2bf(o[dt][r] * inv[r]);
            }
        }
    }
}

// ---------------------------------------------------------------------------
// K4: out_proj + residual(bf16) + LN2.  32-row tile, 512 threads / 8 waves,
// BK=64, global_load_lds staging, linear pitch-64 LDS, XOR chunk swizzle.
// ---------------------------------------------------------------------------
__global__ __launch_bounds__(512) void outproj_ln_kernel(
    const unsigned short* __restrict__ ctx, const unsigned short* __restrict__ Wop,
    unsigned short* __restrict__ epi_b, const float* __restrict__ g2,
    const float* __restrict__ b2, unsigned short* __restrict__ ffin)
{
    __shared__ unsigned short As[32 * 64];
    __shared__ unsigned short Ws[256 * 64];
    __shared__ float part[2][4][4][4][2];

    int tid = threadIdx.x, lane = tid & 63, wv = tid >> 6;
    int m0 = blockIdx.x * 32;
    int rA = lane & 15, k8r = lane >> 4, g = lane >> 4;
    int rg = wv & 1, ch = wv >> 1;

    f32x4 acc[4];
#pragma unroll
    for (int ct = 0; ct < 4; ++ct)
#pragma unroll
        for (int r = 0; r < 4; ++r) acc[ct][r] = 0.f;

    for (int kc = 0; kc < 256; kc += 64) {
        // As: 32 rows x 8 chunks = 256 chunks -> waves 0..3, 1 instr each
        if (wv < 4) {
            int cb = wv * 64;
            int c = cb + lane;
            int row = c >> 3, k8p = (c & 7) ^ (row & 7);
            __builtin_amdgcn_global_load_lds(
                (const unsigned int*)(ctx + (size_t)(m0 + row) * 256 + kc + k8p * 8),
                (unsigned int*)&As[cb * 8], 16, 0, 0);
        }
        // Ws: 256 rows x 8 chunks = 2048 chunks -> 4 per wave
#pragma unroll
        for (int t = 0; t < 4; ++t) {
            int cb = (t * 8 + wv) * 64;
            int c = cb + lane;
            int row = c >> 3, k8p = (c & 7) ^ (row & 7);
            __builtin_amdgcn_global_load_lds(
                (const unsigned int*)(Wop + (size_t)row * 256 + kc + k8p * 8),
                (unsigned int*)&Ws[cb * 8], 16, 0, 0);
        }
        __syncthreads();

        short8v a[2];
#pragma unroll
        for (int ks = 0; ks < 2; ++ks) {
            int row = rg * 16 + rA;
            int cx = (ks * 4 + k8r) ^ (row & 7);
            a[ks] = *(const short8v*)&As[row * 64 + cx * 8];
        }
#pragma unroll
        for (int ks = 0; ks < 2; ++ks)
#pragma unroll
            for (int ct = 0; ct < 4; ++ct) {
                int row = ch * 64 + ct * 16 + rA;
                int cx = (ks * 4 + k8r) ^ (row & 7);
                short8v b = *(const short8v*)&Ws[row * 64 + cx * 8];
                acc[ct] = __builtin_amdgcn_mfma_f32_16x16x32_bf16(a[ks], b, acc[ct], 0, 0, 0);
            }
        __syncthreads();
    }

    float s[4] = {0.f, 0.f, 0.f, 0.f}, q[4] = {0.f, 0.f, 0.f, 0.f};
#pragma unroll
    for (int ct = 0; ct < 4; ++ct) {
        int col = ch * 64 + ct * 16 + rA;
#pragma unroll
        for (int r = 0; r < 4; ++r) {
            int row = m0 + rg * 16 + g * 4 + r;
            float v = acc[ct][r] + bf2f(epi_b[(size_t)row * 256 + col]);
            acc[ct][r] = v;
            s[r] += v; q[r] += v * v;
        }
    }
#pragma unroll
    for (int off = 8; off; off >>= 1)
#pragma unroll
        for (int r = 0; r < 4; ++r) {
            s[r] += __shfl_xor(s[r], off);
            q[r] += __shfl_xor(q[r], off);
        }
    if (rA == 0) {
#pragma unroll
        for (int r = 0; r < 4; ++r) {
            part[rg][ch][g][r][0] = s[r];
            part[rg][ch][g][r][1] = q[r];
        }
    }
    __syncthreads();
    float mu[4], rs[4];
#pragma unroll
    for (int r = 0; r < 4; ++r) {
        float S = part[rg][0][g][r][0] + part[rg][1][g][r][0]
                + part[rg][2][g][r][0] + part[rg][3][g][r][0];
        float Q = part[rg][0][g][r][1] + part[rg][1][g][r][1]
                + part[rg][2][g][r][1] + part[rg][3][g][r][1];
        mu[r] = S * (1.f / 256.f);
        rs[r] = rsqrtf(Q * (1.f / 256.f) - mu[r] * mu[r] + 1e-5f);
    }
#pragma unroll
    for (int ct = 0; ct < 4; ++ct) {
        int col = ch * 64 + ct * 16 + rA;
        float gg = g2[col], bv = b2[col];
#pragma unroll
        for (int r = 0; r < 4; ++r) {
            int row = m0 + rg * 16 + g * 4 + r;
            size_t o = (size_t)row * 256 + col;
            epi_b[o] = f2bf(acc[ct][r]);
            ffin[o] = f2bf((acc[ct][r] - mu[r]) * rs[r] * gg + bv);
        }
    }
}

// ---------------------------------------------------------------------------
// K6: FF2 + residual(bf16) + final E->32 projection + transposed store.
// 32-row tile, 512 threads / 8 waves, BK=64, global_load_lds staging.
// ---------------------------------------------------------------------------
__global__ __launch_bounds__(512) void ff2_final_kernel(
    const unsigned short* __restrict__ ffh, const unsigned short* __restrict__ W2,
    const unsigned short* __restrict__ epi_b, const float* __restrict__ w_out,
    float* __restrict__ out)
{
    __shared__ unsigned short As[32 * 64];
    __shared__ unsigned short Ws[256 * 64];
    __shared__ unsigned short Ts[32 * 264];

    int tid = threadIdx.x, lane = tid & 63, wv = tid >> 6;
    int m0 = blockIdx.x * 32;
    int rA = lane & 15, k8r = lane >> 4, g = lane >> 4;
    int rg = wv & 1, ch = wv >> 1;

    f32x4 acc[4];
#pragma unroll
    for (int ct = 0; ct < 4; ++ct)
#pragma unroll
        for (int r = 0; r < 4; ++r) acc[ct][r] = 0.f;

    for (int kc = 0; kc < 512; kc += 64) {
        if (wv < 4) {
            int cb = wv * 64;
            int c = cb + lane;
            int row = c >> 3, k8p = (c & 7) ^ (row & 7);
            __builtin_amdgcn_global_load_lds(
                (const unsigned int*)(ffh + (size_t)(m0 + row) * 512 + kc + k8p * 8),
                (unsigned int*)&As[cb * 8], 16, 0, 0);
        }
#pragma unroll
        for (int t = 0; t < 4; ++t) {
            int cb = (t * 8 + wv) * 64;
            int c = cb + lane;
            int row = c >> 3, k8p = (c & 7) ^ (row & 7);
            __builtin_amdgcn_global_load_lds(
                (const unsigned int*)(W2 + (size_t)row * 512 + kc + k8p * 8),
                (unsigned int*)&Ws[cb * 8], 16, 0, 0);
        }
        __syncthreads();

        short8v a[2];
#pragma unroll
        for (int ks = 0; ks < 2; ++ks) {
            int row = rg * 16 + rA;
            int cx = (ks * 4 + k8r) ^ (row & 7);
            a[ks] = *(const short8v*)&As[row * 64 + cx * 8];
        }
#pragma unroll
        for (int ks = 0; ks < 2; ++ks)
#pragma unroll
            for (int ct = 0; ct < 4; ++ct) {
                int row = ch * 64 + ct * 16 + rA;
                int cx = (ks * 4 + k8r) ^ (row & 7);
                short8v b = *(const short8v*)&Ws[row * 64 + cx * 8];
                acc[ct] = __builtin_amdgcn_mfma_f32_16x16x32_bf16(a[ks], b, acc[ct], 0, 0, 0);
            }
        __syncthreads();
    }

#pragma unroll
    for (int ct = 0; ct < 4; ++ct) {
        int col = ch * 64 + ct * 16 + rA;
#pragma unroll
        for (int r = 0; r < 4; ++r) {
            int lrow = rg * 16 + g * 4 + r;
            float v = acc[ct][r] + bf2f(epi_b[(size_t)(m0 + lrow) * 256 + col]);
            Ts[lrow * 264 + col] = f2bf(v);
        }
    }
    __syncthreads();

    int bn = m0 >> 10, l0 = m0 & 1023;
    int bb = bn >> 2, nn = bn & 3;

    if (wv < 4) {
        int rw = wv & 1, cw = wv >> 1;
        f32x4 a2;
#pragma unroll
        for (int r = 0; r < 4; ++r) a2[r] = 0.f;
#pragma unroll
        for (int ks = 0; ks < 8; ++ks) {
            short8v af = *(const short8v*)&Ts[(rw * 16 + rA) * 264 + ks * 32 + k8r * 8];
            const float* wp = w_out + (cw * 16 + rA) * 256 + ks * 32 + k8r * 8;
            float4 w0 = *(const float4*)wp;
            float4 w1 = *(const float4*)(wp + 4);
            short8v bf;
            bf[0] = (short)f2bf(w0.x); bf[1] = (short)f2bf(w0.y);
            bf[2] = (short)f2bf(w0.z); bf[3] = (short)f2bf(w0.w);
            bf[4] = (short)f2bf(w1.x); bf[5] = (short)f2bf(w1.y);
            bf[6] = (short)f2bf(w1.z); bf[7] = (short)f2bf(w1.w);
            a2 = __builtin_amdgcn_mfma_f32_16x16x32_bf16(af, bf, a2, 0, 0, 0);
        }
        int c = cw * 16 + rA;
        int l = l0 + rw * 16 + g * 4;
        float4 st; st.x = a2[0]; st.y = a2[1]; st.z = a2[2]; st.w = a2[3];
        *(float4*)(out + ((size_t)(bb * 32 + c) * 4 + nn) * 1024 + l) = st;
    }
}

// ---------------------------------------------------------------------------
extern "C" void kernel_launch(void* const* d_in, const int* in_sizes, int n_in,
                              void* d_out, int out_size, void* d_ws, size_t ws_size,
                              hipStream_t stream) {
    const float* x_lf       = (const float*)d_in[0];
    const float* x_hf       = (const float*)d_in[1];
    const float* w_in       = (const float*)d_in[2];
    const float* w_qk       = (const float*)d_in[3];
    const float* ln_g       = (const float*)d_in[4];
    const float* ln_b       = (const float*)d_in[5];
    const float* in_proj_w  = (const float*)d_in[6];
    const float* out_proj_w = (const float*)d_in[7];
    const float* ln2_g      = (const float*)d_in[8];
    const float* ln2_b      = (const float*)d_in[9];
    const float* ff_w1      = (const float*)d_in[10];
    const float* ff_w2      = (const float*)d_in[11];
    const float* w_out      = (const float*)d_in[12];
    float* out = (float*)d_out;

    char* w = (char*)d_ws;
    unsigned short* epi_b  = (unsigned short*)(w);                // 4 MB bf16
    unsigned short* Qb     = (unsigned short*)(w + (4u  << 20));  // 4 MB bf16
    unsigned short* Kb     = (unsigned short*)(w + (8u  << 20));
    unsigned short* Vb     = (unsigned short*)(w + (12u << 20));
    unsigned short* q_b    = (unsigned short*)(w + (16u << 20));
    unsigned short* k_b    = (unsigned short*)(w + (20u << 20));
    unsigned short* kv_b   = (unsigned short*)(w + (24u << 20));
    unsigned short* ctx_b  = (unsigned short*)(w + (28u << 20));
    unsigned short* ffin_b = (unsigned short*)(w + (32u << 20));
    unsigned short* ffh_b  = (unsigned short*)(w + (36u << 20));  // 8 MB
    unsigned short* wqkv_b = (unsigned short*)(w + (44u << 20));
    unsigned short* wop_b  = (unsigned short*)(w + (45u << 20));
    unsigned short* wff1_b = (unsigned short*)(w + (46u << 20));
    unsigned short* wff2_b = (unsigned short*)(w + (47u << 20));

    // 1. gather + input proj + dual LN + weight conversion  [256 blk x 512]
    embed_conv_kernel<<<256, 512, 0, stream>>>(
        x_lf, x_hf, w_in, w_qk, ln_g, ln_b, epi_b, kv_b, q_b, k_b,
        in_proj_w, out_proj_w, ff_w1, ff_w2, wqkv_b, wop_b, wff1_b, wff2_b);
    // 2. QKV projection -> bf16 (bn,h,l,d)   [768 blocks, gload_lds]
    gemm_mfma64<1, false><<<dim3(128, 2, 3), 256, 0, stream>>>(
        q_b, k_b, kv_b, wqkv_b, Qb, 256, 256);
    // 3. local-window attention (MFMA, 2 qv-rows/block) -> ctx bf16
    attn_mfma_kernel<<<1024, 256, 0, stream>>>(Qb, Kb, Vb, ctx_b);
    // 4. out_proj + residual(bf16) + LN2  [512 thr, gload_lds]
    outproj_ln_kernel<<<256, 512, 0, stream>>>(ctx_b, wop_b, epi_b,
                                               ln2_g, ln2_b, ffin_b);
    // 5. FF1 + ReLU -> bf16 [8192,512]   [512 blocks, gload_lds]
    gemm_mfma64<0, true><<<dim3(128, 4, 1), 256, 0, stream>>>(
        ffin_b, ffin_b, ffin_b, wff1_b, ffh_b, 256, 512);
    // 6. FF2 + residual(bf16) + final projection + transposed store
    ff2_final_kernel<<<256, 512, 0, stream>>>(ffh_b, wff2_b, epi_b, w_out, out);
}